// Round 1
// baseline (2147.884 us; speedup 1.0000x reference)
//
#include <hip/hip_runtime.h>
#include <math.h>

// ---------------- problem constants ----------------
#define BATCH 2048
#define HID 512
#define G4 2048            // 4*H
#define TPTS 90
#define NSEG 89
#define NSUB 10
#define NT_GRID 1781       // 20*NSEG + 1 half-step time points

__device__ __constant__ const float kR_I  = 0.6931471805599453f / 5.0f;
__device__ __constant__ const float kR_D  = 0.6931471805599453f / 2.0f;
__device__ __constant__ const float kR_RI = 0.6931471805599453f / 10.0f;
__device__ __constant__ const float kR_RH = 0.6931471805599453f / 15.0f;
__device__ __constant__ const float kR_RV = 0.6931471805599453f / 10.0f;

__device__ __forceinline__ float sigmoidf_(float x) { return 1.0f / (1.0f + expf(-x)); }

// ---------------- prep: pad K=30 operands to K=32, x = mi[:, :30]/pop ----------------
__global__ void prep_pad(const float* __restrict__ mi, const float* __restrict__ pop,
                         const float* __restrict__ Wih0, const float* __restrict__ mW1,
                         float* __restrict__ x0p, float* __restrict__ xmp,
                         float* __restrict__ Wp0, float* __restrict__ Wpm)
{
    int i = blockIdx.x * 256 + threadIdx.x;     // < 2048*32
    int r = i >> 5, c = i & 31;
    bool v = (c < 30);
    x0p[i] = v ? mi[r * 60 + c] / pop[r] : 0.0f;
    xmp[i] = v ? mi[r * 60 + 30 + c] : 0.0f;
    Wp0[i] = v ? Wih0[r * 30 + c] : 0.0f;
    if (r < 512) Wpm[i] = v ? mW1[r * 30 + c] : 0.0f;
}

// ---------------- fp32 tiled GEMM-NT: C[m][n] = sum_k A[m][k]*W[n][k] (+bias, act) ----------------
// Dual operand: C = A1*W1^T + A2*W2^T + b1 + b2.  128x128 tile, BK=8, 256 thr, 8x8 microtile.
// Requires: M=2048, K mult of 8, lda/ldw mult of 4; N arbitrary (guarded).
// ACT: 0=none, 1=relu, 2=tanh
template<int ACT>
__global__ __launch_bounds__(256)
void gemm_dual(const float* __restrict__ A1, int lda1,
               const float* __restrict__ W1, int ldw1, int K1,
               const float* __restrict__ A2, int lda2,
               const float* __restrict__ W2, int ldw2, int K2,
               const float* __restrict__ b1p, const float* __restrict__ b2p,
               float* __restrict__ Cp, int ldc, int N)
{
    __shared__ float As[8][128];
    __shared__ float Ws[8][128];
    const int tid  = threadIdx.x;
    const int m0   = blockIdx.y * 128;
    const int n0   = blockIdx.x * 128;
    const int tm   = tid >> 4;          // 0..15
    const int tn   = tid & 15;          // 0..15
    const int lrow = tid >> 1;          // 0..127
    const int lkh  = (tid & 1) << 2;    // 0 or 4

    float acc[8][8];
    #pragma unroll
    for (int i = 0; i < 8; ++i)
        #pragma unroll
        for (int j = 0; j < 8; ++j) acc[i][j] = 0.0f;

    for (int pass = 0; pass < 2; ++pass) {
        const float* A = pass ? A2 : A1;
        const float* W = pass ? W2 : W1;
        const int lda = pass ? lda2 : lda1;
        const int ldw = pass ? ldw2 : ldw1;
        const int K   = pass ? K2   : K1;
        if (K == 0) continue;
        for (int kt = 0; kt < K; kt += 8) {
            float4 av = *(const float4*)(A + (size_t)(m0 + lrow) * lda + kt + lkh);
            float4 wv = make_float4(0.0f, 0.0f, 0.0f, 0.0f);
            int wrow = n0 + lrow;
            if (wrow < N) wv = *(const float4*)(W + (size_t)wrow * ldw + kt + lkh);
            __syncthreads();
            As[lkh + 0][lrow] = av.x; As[lkh + 1][lrow] = av.y;
            As[lkh + 2][lrow] = av.z; As[lkh + 3][lrow] = av.w;
            Ws[lkh + 0][lrow] = wv.x; Ws[lkh + 1][lrow] = wv.y;
            Ws[lkh + 2][lrow] = wv.z; Ws[lkh + 3][lrow] = wv.w;
            __syncthreads();
            #pragma unroll
            for (int kk = 0; kk < 8; ++kk) {
                float af[8], wf[8];
                #pragma unroll
                for (int i = 0; i < 4; ++i) {
                    af[i]     = As[kk][tm * 8 + i];
                    af[i + 4] = As[kk][tm * 8 + 4 + i];
                    wf[i]     = Ws[kk][tn * 4 + i];
                    wf[i + 4] = Ws[kk][64 + tn * 4 + i];
                }
                #pragma unroll
                for (int i = 0; i < 8; ++i)
                    #pragma unroll
                    for (int j = 0; j < 8; ++j)
                        acc[i][j] += af[i] * wf[j];
            }
        }
    }

    #pragma unroll
    for (int j = 0; j < 8; ++j) {
        int col = n0 + ((j < 4) ? (tn * 4 + j) : (64 + tn * 4 + (j - 4)));
        if (col >= N) continue;
        float bias = b1p[col] + (b2p ? b2p[col] : 0.0f);
        #pragma unroll
        for (int i = 0; i < 8; ++i) {
            int rrow = m0 + tm * 8 + i;
            float v = acc[i][j] + bias;
            if (ACT == 1) v = fmaxf(v, 0.0f);
            else if (ACT == 2) v = tanhf(v);
            Cp[(size_t)rrow * ldc + col] = v;
        }
    }
}

// ---------------- LSTM gate nonlinearity ----------------
__global__ void lstm_gates(const float* __restrict__ G_, const float* __restrict__ c0l,
                           float* __restrict__ xout, int xld, float* __restrict__ ts)
{
    int i = blockIdx.x * 256 + threadIdx.x;     // < 2048*512
    int m = i >> 9, h = i & 511;
    const float* g = G_ + (size_t)m * 2048 + h;
    float gi = g[0], gf = g[512], gg = g[1024], go = g[1536];
    float c = sigmoidf_(gf) * c0l[i] + sigmoidf_(gi) * tanhf(gg);
    float x = sigmoidf_(go) * tanhf(c);
    xout[(size_t)m * xld + h] = x;
    if (ts) ts[i] = x;
}

// ---------------- dnn = sigmoid(raw*ss) * range ----------------
__global__ void dnn_kernel(const float* __restrict__ raw, const int* __restrict__ ssp,
                           const float* __restrict__ rng, float* __restrict__ dnn)
{
    int i = blockIdx.x * 256 + threadIdx.x;
    if (i >= 2048 * 23) return;
    int c = i % 23;
    int v = *ssp;
    // sigmoid_scale is a python int (1); defend against a float-encoded 1.0 as well
    float ss = (v > 100000 || v < 0) ? __int_as_float(v) : (float)v;
    dnn[i] = sigmoidf_(raw[i] * ss) * rng[c];
}

// ---------------- precompute ag(t)=alpha*gam(t), pdt(t) on half-step grid ----------------
__global__ void gampdt_kernel(const float* __restrict__ dnn,
                              float* __restrict__ agp, float* __restrict__ pdp)
{
    int idx = blockIdx.x * 256 + threadIdx.x;
    if (idx >= NT_GRID * 2048) return;
    int e = idx & 2047;
    int k = idx >> 11;
    const float* p = dnn + e * 23 + 11;
    float alpha = p[0], days = p[1], r_s = p[2], p_dth = p[4], r_dthdecay = p[5];
    float jump = p[8], t_jump = p[9], stdn = p[10];
    float t = 0.05f * (float)k;
    float dtj = t - t_jump;
    float g = 0.6366197723675814f * atanf((days - t) * (r_s * 0.05f)) + 1.0f
            + jump * expf(-(dtj * dtj) / (2.0f * stdn * stdn));
    float pdt = 0.6366197723675814f * (p_dth - 0.001f) * (atanf(-t * (r_dthdecay * 0.05f)) + 1.5707963267948966f)
              + 0.001f;
    agp[idx] = alpha * g;
    pdp[idx] = pdt;
}

// ---------------- ODE ----------------
__device__ __forceinline__ void deriv16(const float* y, float ag, float pd,
                                        float invN, float r_dth, float* d)
{
    float inf = ag * y[0] * y[2] * invN;
    float det = kR_D * y[2];
    float t1  = kR_I * y[1];
    float omp = 1.0f - pd;
    float dq  = det * omp;
    float dp  = det * pd;
    float dq003 = dq * 0.03f;
    float dp003 = dp * 0.03f;
    d[0]  = -inf;
    d[1]  = inf - t1;
    d[2]  = t1 - det;
    d[3]  = dq * 0.8f  - kR_RI * y[3];
    d[4]  = dq003      - kR_RH * y[4];
    d[5]  = dq * 0.17f - kR_RI * y[5];
    d[6]  = dp * 0.8f  - r_dth * y[6];
    d[7]  = dp003      - r_dth * y[7];
    d[8]  = dp * 0.17f - r_dth * y[8];
    d[9]  = kR_RI * (y[3] + y[5]) + kR_RH * y[4];
    d[10] = r_dth * ((y[6] + y[7]) + y[8]);
    d[11] = det * 0.03f;
    d[12] = 0.25f * dq003 - kR_RV * y[12];
    d[13] = 0.25f * dp003 - r_dth * y[13];
    d[14] = r_dth * (y[7] + y[8]);
    d[15] = det * 0.2f;
}

__device__ __forceinline__ void gampdt_eval(float t, float alpha, float days, float rs20,
                                            float jump, float t_jump, float inv2s2,
                                            float pconst, float rdd20, float* ag, float* pd)
{
    float dtj = t - t_jump;
    float g = 0.6366197723675814f * atanf((days - t) * rs20) + 1.0f + jump * expf(-(dtj * dtj) * inv2s2);
    *ag = alpha * g;
    *pd = pconst * (atanf(-t * rdd20) + 1.5707963267948966f) + 0.001f;
}

template<bool PRE>
__global__ __launch_bounds__(64)
void ode_kernel(const float* __restrict__ dnn, const float* __restrict__ pop,
                const float* __restrict__ ccn, const float* __restrict__ mort,
                const float* __restrict__ agp, const float* __restrict__ pdp,
                float* __restrict__ sol)
{
    int e = blockIdx.x * 64 + threadIdx.x;      // 0..2047
    const float* p = dnn + e * 23 + 11;
    float alpha = p[0], days = p[1], r_s = p[2], r_dth = p[3], p_dth = p[4];
    float r_dthdecay = p[5], k1p = p[6], k2p = p[7], jump = p[8], t_jump = p[9], stdn = p[10];

    float N = pop[e];
    float invN = 1.0f / N;
    float PopI = ccn[e];
    float PopD = floorf(mort[e] * PopI);
    float R0v  = (PopI - PopD > 5.0f * PopD) ? 5.0f * PopD : 0.0f;
    float PopCI = PopI - PopD - R0v;
    float DP = PopCI / 0.2f;

    float y[16];
    y[0]  = N - DP * (k1p + k2p) - R0v / 0.2f - PopD / 0.2f;
    y[1]  = DP * k1p;
    y[2]  = DP * k2p;
    y[3]  = (DP - PopCI) * (1.0f - p_dth);
    y[4]  = PopCI * 0.15f * (1.0f - p_dth);
    y[5]  = PopCI * 0.85f * (1.0f - p_dth);
    y[6]  = (DP - PopCI) * p_dth;
    y[7]  = PopCI * 0.15f * p_dth;
    y[8]  = PopCI * 0.85f * p_dth;
    y[9]  = R0v / 0.2f;
    y[10] = PopD / 0.2f;
    y[11] = PopCI * 0.15f;
    y[12] = PopCI * 0.15f * 0.25f * (1.0f - p_dth);
    y[13] = PopCI * 0.15f * 0.25f * p_dth;
    y[14] = PopD;
    y[15] = PopI;

    {
        float* sp = sol + (size_t)e * (TPTS * 16);
        #pragma unroll
        for (int i = 0; i < 16; ++i) sp[i] = y[i];
    }

    // per-thread constants for inline gam/pdt path
    float rs20   = r_s * 0.05f;
    float rdd20  = r_dthdecay * 0.05f;
    float inv2s2 = 1.0f / (2.0f * stdn * stdn);
    float pconst = 0.6366197723675814f * (p_dth - 0.001f);

    float ag0, pd0;
    if (PRE) { ag0 = agp[e]; pd0 = pdp[e]; }
    else     { gampdt_eval(0.0f, alpha, days, rs20, jump, t_jump, inv2s2, pconst, rdd20, &ag0, &pd0); }

    for (int s = 0; s < NSEG; ++s) {
        float t0 = (float)s;
        for (int j = 0; j < NSUB; ++j) {
            float agh, pdh, ag1, pd1;
            if (PRE) {
                int k = s * 20 + j * 2;
                agh = agp[(size_t)(k + 1) * 2048 + e]; pdh = pdp[(size_t)(k + 1) * 2048 + e];
                ag1 = agp[(size_t)(k + 2) * 2048 + e]; pd1 = pdp[(size_t)(k + 2) * 2048 + e];
            } else {
                float t = t0 + (float)j * 0.1f;
                gampdt_eval(t + 0.05f, alpha, days, rs20, jump, t_jump, inv2s2, pconst, rdd20, &agh, &pdh);
                gampdt_eval(t + 0.1f,  alpha, days, rs20, jump, t_jump, inv2s2, pconst, rdd20, &ag1, &pd1);
            }
            float d[16], acc[16], yt[16];
            deriv16(y, ag0, pd0, invN, r_dth, d);
            #pragma unroll
            for (int i = 0; i < 16; ++i) { acc[i] = d[i]; yt[i] = y[i] + 0.05f * d[i]; }
            deriv16(yt, agh, pdh, invN, r_dth, d);
            #pragma unroll
            for (int i = 0; i < 16; ++i) { acc[i] += 2.0f * d[i]; yt[i] = y[i] + 0.05f * d[i]; }
            deriv16(yt, agh, pdh, invN, r_dth, d);
            #pragma unroll
            for (int i = 0; i < 16; ++i) { acc[i] += 2.0f * d[i]; yt[i] = y[i] + 0.1f * d[i]; }
            deriv16(yt, ag1, pd1, invN, r_dth, d);
            #pragma unroll
            for (int i = 0; i < 16; ++i) y[i] += 0.016666668f * (acc[i] + d[i]);
            ag0 = ag1; pd0 = pd1;
        }
        float* sp = sol + (size_t)e * (TPTS * 16) + (size_t)(s + 1) * 16;
        #pragma unroll
        for (int i = 0; i < 16; ++i) sp[i] = y[i];
    }
}

// ---------------- host launch ----------------
extern "C" void kernel_launch(void* const* d_in, const int* in_sizes, int n_in,
                              void* d_out, int out_size, void* d_ws, size_t ws_size,
                              hipStream_t stream)
{
    const float* mi   = (const float*)d_in[0];
    const float* pop  = (const float*)d_in[1];
    const float* ccn  = (const float*)d_in[2];
    const float* mort = (const float*)d_in[3];
    const float* h0   = (const float*)d_in[4];
    const float* c0   = (const float*)d_in[5];
    const float* Wih0 = (const float*)d_in[6];
    const float* WihR = (const float*)d_in[7];
    const float* Whh  = (const float*)d_in[8];
    const float* bih  = (const float*)d_in[9];
    const float* bhh  = (const float*)d_in[10];
    const float* mW1  = (const float*)d_in[11];
    const float* mb1  = (const float*)d_in[12];
    const float* mW2  = (const float*)d_in[13];
    const float* mb2  = (const float*)d_in[14];
    const float* rW1  = (const float*)d_in[15];
    const float* rb1  = (const float*)d_in[16];
    const float* rW2  = (const float*)d_in[17];
    const float* rb2  = (const float*)d_in[18];
    const float* rng  = (const float*)d_in[19];
    const int*   ssp  = (const int*)d_in[20];

    float* out   = (float*)d_out;
    float* sol_o = out;                                   // 2048*90*16
    float* dnn_o = out + 2949120;                         // 2048*23
    float* ts_o  = out + 2949120 + 47104;                 // 2048*512
    float* raw_o = out + 2949120 + 47104 + 1048576;       // 2048*23

    float* ws  = (float*)d_ws;
    float* G   = ws;                    // 4,194,304 floats (also hosts m1, then z2)
    float* Z   = ws + 4194304;          // 2,097,152
    float* X0  = ws + 6291456;          // 1,048,576
    float* X1  = ws + 7340032;          // 1,048,576
    float* x0p = ws + 8388608;          // 65,536
    float* xmp = ws + 8454144;          // 65,536
    float* Wp0 = ws + 8519680;          // 65,536
    float* Wpm = ws + 8585216;          // 16,384   (end 8,601,600)
    float* AGP = ws + 8601600;          // 3,647,488
    float* PDP = ws + 12249088;         // 3,647,488 (end 15,896,576 floats = 63.6 MB)
    bool usePre = ws_size >= (size_t)15896576 * sizeof(float);

    prep_pad<<<256, 256, 0, stream>>>(mi, pop, Wih0, mW1, x0p, xmp, Wp0, Wpm);

    // meta MLP (uses G as scratch for m1, before LSTM needs G)
    gemm_dual<1><<<dim3(4, 16), 256, 0, stream>>>(xmp, 32, Wpm, 32, 32,
                                                  nullptr, 0, nullptr, 0, 0,
                                                  mb1, nullptr, G, 512, 512);
    gemm_dual<1><<<dim3(4, 16), 256, 0, stream>>>(G, 512, mW2, 512, 512,
                                                  nullptr, 0, nullptr, 0, 0,
                                                  mb2, nullptr, Z + 512, 1024, 512);

    // 5-layer LSTM cell stack
    for (int l = 0; l < 5; ++l) {
        const float* A1   = (l == 0) ? x0p : ((l & 1) ? X1 : X0);
        int          K1   = (l == 0) ? 32 : 512;
        const float* W1   = (l == 0) ? Wp0 : (WihR + (size_t)(l - 1) * 1048576);
        gemm_dual<0><<<dim3(16, 16), 256, 0, stream>>>(
            A1, K1, W1, K1, K1,
            h0 + (size_t)l * 1048576, 512, Whh + (size_t)l * 1048576, 512, 512,
            bih + l * 2048, bhh + l * 2048, G, 2048, 2048);
        float* xo  = (l == 4) ? Z : ((l & 1) ? X0 : X1);
        int    xol = (l == 4) ? 1024 : 512;
        lstm_gates<<<4096, 256, 0, stream>>>(G, c0 + (size_t)l * 1048576, xo, xol,
                                             (l == 4) ? ts_o : nullptr);
    }

    // readout
    gemm_dual<2><<<dim3(8, 16), 256, 0, stream>>>(Z, 1024, rW1, 1024, 1024,
                                                  nullptr, 0, nullptr, 0, 0,
                                                  rb1, nullptr, G, 1024, 1024);
    gemm_dual<0><<<dim3(1, 16), 256, 0, stream>>>(G, 1024, rW2, 1024, 1024,
                                                  nullptr, 0, nullptr, 0, 0,
                                                  rb2, nullptr, raw_o, 23, 23);
    dnn_kernel<<<184, 256, 0, stream>>>(raw_o, ssp, rng, dnn_o);

    // ODE
    if (usePre) {
        gampdt_kernel<<<(NT_GRID * 2048 + 255) / 256, 256, 0, stream>>>(dnn_o, AGP, PDP);
        ode_kernel<true><<<32, 64, 0, stream>>>(dnn_o, pop, ccn, mort, AGP, PDP, sol_o);
    } else {
        ode_kernel<false><<<32, 64, 0, stream>>>(dnn_o, pop, ccn, mort, nullptr, nullptr, sol_o);
    }
    (void)in_sizes; (void)n_in; (void)out_size;
}

// Round 2
// 1493.566 us; speedup vs baseline: 1.4381x; 1.4381x over previous
//
#include <hip/hip_runtime.h>
#include <math.h>

// ---------------- problem constants ----------------
#define BATCH 2048
#define HID 512
#define TPTS 90
#define NSEG 89
#define NSUB 10
#define NSTEPS 890          // NSEG*NSUB global substeps

__device__ __constant__ const float kR_I  = 0.6931471805599453f / 5.0f;
__device__ __constant__ const float kR_D  = 0.6931471805599453f / 2.0f;
__device__ __constant__ const float kR_RI = 0.6931471805599453f / 10.0f;
__device__ __constant__ const float kR_RH = 0.6931471805599453f / 15.0f;
__device__ __constant__ const float kR_RV = 0.6931471805599453f / 10.0f;

__device__ __forceinline__ float sigmoidf_(float x) { return 1.0f / (1.0f + expf(-x)); }

// ---------------- prep: pad K=30 operands to K=32, x = mi[:, :30]/pop ----------------
__global__ void prep_pad(const float* __restrict__ mi, const float* __restrict__ pop,
                         const float* __restrict__ Wih0, const float* __restrict__ mW1,
                         float* __restrict__ x0p, float* __restrict__ xmp,
                         float* __restrict__ Wp0, float* __restrict__ Wpm)
{
    int i = blockIdx.x * 256 + threadIdx.x;     // < 2048*32
    int r = i >> 5, c = i & 31;
    bool v = (c < 30);
    x0p[i] = v ? mi[r * 60 + c] / pop[r] : 0.0f;
    xmp[i] = v ? mi[r * 60 + 30 + c] : 0.0f;
    Wp0[i] = v ? Wih0[r * 30 + c] : 0.0f;
    if (r < 512) Wpm[i] = v ? mW1[r * 30 + c] : 0.0f;
}

// ---------------- fp32 tiled GEMM-NT with register-prefetch pipelining ----------------
// C = A1*W1^T + A2*W2^T + b1 + b2 over concatenated K.  128x128 tile, BK=8,
// 256 thr, 8x8 microtile.  M=2048 assumed; N guarded.  ACT: 0=none,1=relu,2=tanh
template<int ACT>
__global__ __launch_bounds__(256)
void gemm_dual(const float* __restrict__ A1, int lda1,
               const float* __restrict__ W1, int ldw1, int K1,
               const float* __restrict__ A2, int lda2,
               const float* __restrict__ W2, int ldw2, int K2,
               const float* __restrict__ b1p, const float* __restrict__ b2p,
               float* __restrict__ Cp, int ldc, int N)
{
    __shared__ float As[8][128];
    __shared__ float Ws[8][128];
    const int tid  = threadIdx.x;
    const int m0   = blockIdx.y * 128;
    const int n0   = blockIdx.x * 128;
    const int tm   = tid >> 4;          // 0..15
    const int tn   = tid & 15;          // 0..15
    const int lrow = tid >> 1;          // 0..127
    const int lkh  = (tid & 1) << 2;    // 0 or 4
    const int wrow = n0 + lrow;
    const int Ktot = K1 + K2;

    float acc[8][8];
    #pragma unroll
    for (int i = 0; i < 8; ++i)
        #pragma unroll
        for (int j = 0; j < 8; ++j) acc[i][j] = 0.0f;

    // initial tile load (kt = 0, always from operand 1)
    float4 av = *(const float4*)(A1 + (size_t)(m0 + lrow) * lda1 + lkh);
    float4 wv = make_float4(0.0f, 0.0f, 0.0f, 0.0f);
    if (wrow < N) wv = *(const float4*)(W1 + (size_t)wrow * ldw1 + lkh);

    for (int kt = 0; kt < Ktot; kt += 8) {
        __syncthreads();                 // previous compute done reading LDS
        As[lkh + 0][lrow] = av.x; As[lkh + 1][lrow] = av.y;
        As[lkh + 2][lrow] = av.z; As[lkh + 3][lrow] = av.w;
        Ws[lkh + 0][lrow] = wv.x; Ws[lkh + 1][lrow] = wv.y;
        Ws[lkh + 2][lrow] = wv.z; Ws[lkh + 3][lrow] = wv.w;
        __syncthreads();

        // prefetch next k-tile into registers; overlaps with compute below
        int kn = kt + 8;
        float4 avn = make_float4(0.0f, 0.0f, 0.0f, 0.0f);
        float4 wvn = avn;
        if (kn < Ktot) {
            if (kn < K1) {
                avn = *(const float4*)(A1 + (size_t)(m0 + lrow) * lda1 + kn + lkh);
                if (wrow < N) wvn = *(const float4*)(W1 + (size_t)wrow * ldw1 + kn + lkh);
            } else {
                int k2 = kn - K1;
                avn = *(const float4*)(A2 + (size_t)(m0 + lrow) * lda2 + k2 + lkh);
                if (wrow < N) wvn = *(const float4*)(W2 + (size_t)wrow * ldw2 + k2 + lkh);
            }
        }

        #pragma unroll
        for (int kk = 0; kk < 8; ++kk) {
            float af[8], wf[8];
            #pragma unroll
            for (int i = 0; i < 4; ++i) {
                af[i]     = As[kk][tm * 8 + i];
                af[i + 4] = As[kk][tm * 8 + 4 + i];
                wf[i]     = Ws[kk][tn * 4 + i];
                wf[i + 4] = Ws[kk][64 + tn * 4 + i];
            }
            #pragma unroll
            for (int i = 0; i < 8; ++i)
                #pragma unroll
                for (int j = 0; j < 8; ++j)
                    acc[i][j] += af[i] * wf[j];
        }
        av = avn; wv = wvn;
    }

    #pragma unroll
    for (int j = 0; j < 8; ++j) {
        int col = n0 + ((j < 4) ? (tn * 4 + j) : (64 + tn * 4 + (j - 4)));
        if (col >= N) continue;
        float bias = b1p[col] + (b2p ? b2p[col] : 0.0f);
        #pragma unroll
        for (int i = 0; i < 8; ++i) {
            int rrow = m0 + tm * 8 + i;
            float v = acc[i][j] + bias;
            if (ACT == 1) v = fmaxf(v, 0.0f);
            else if (ACT == 2) v = tanhf(v);
            Cp[(size_t)rrow * ldc + col] = v;
        }
    }
}

// ---------------- LSTM gate nonlinearity ----------------
__global__ void lstm_gates(const float* __restrict__ G_, const float* __restrict__ c0l,
                           float* __restrict__ xout, int xld, float* __restrict__ ts)
{
    int i = blockIdx.x * 256 + threadIdx.x;     // < 2048*512
    int m = i >> 9, h = i & 511;
    const float* g = G_ + (size_t)m * 2048 + h;
    float gi = g[0], gf = g[512], gg = g[1024], go = g[1536];
    float c = sigmoidf_(gf) * c0l[i] + sigmoidf_(gi) * tanhf(gg);
    float x = sigmoidf_(go) * tanhf(c);
    xout[(size_t)m * xld + h] = x;
    if (ts) ts[i] = x;
}

// ---------------- dnn = sigmoid(raw*ss) * range ----------------
__global__ void dnn_kernel(const float* __restrict__ raw, const int* __restrict__ ssp,
                           const float* __restrict__ rng, float* __restrict__ dnn)
{
    int i = blockIdx.x * 256 + threadIdx.x;
    if (i >= 2048 * 23) return;
    int c = i % 23;
    int v = *ssp;
    float ss = (v > 100000 || v < 0) ? __int_as_float(v) : (float)v;
    dnn[i] = sigmoidf_(raw[i] * ss) * rng[c];
}

// ---------------- gam/pdt evaluation ----------------
__device__ __forceinline__ void gampdt_eval(float t, float alpha, float days, float rs20,
                                            float jump, float t_jump, float inv2s2,
                                            float pconst, float rdd20, float* ag, float* pd)
{
    float dtj = t - t_jump;
    float g = 0.6366197723675814f * atanf((days - t) * rs20) + 1.0f + jump * expf(-(dtj * dtj) * inv2s2);
    *ag = alpha * g;
    *pd = pconst * (atanf(-t * rdd20) + 1.5707963267948966f) + 0.001f;
}

// pack (ag_half, pd_half, ag_end, pd_end) per (substep k, chain e) as float4
__global__ void gampdt4_kernel(const float* __restrict__ dnn, float4* __restrict__ ag4)
{
    int idx = blockIdx.x * 256 + threadIdx.x;
    if (idx >= NSTEPS * 2048) return;
    int e = idx & 2047;
    int k = idx >> 11;
    int s = k / 10, j = k - s * 10;
    const float* p = dnn + e * 23 + 11;
    float alpha = p[0], days = p[1], r_s = p[2], p_dth = p[4], r_dthdecay = p[5];
    float jump = p[8], t_jump = p[9], stdn = p[10];
    float rs20   = r_s * 0.05f;
    float rdd20  = r_dthdecay * 0.05f;
    float inv2s2 = 1.0f / (2.0f * stdn * stdn);
    float pconst = 0.6366197723675814f * (p_dth - 0.001f);
    float t = (float)s + (float)j * 0.1f;
    float agh, pdh, ag1, pd1;
    gampdt_eval(t + 0.05f, alpha, days, rs20, jump, t_jump, inv2s2, pconst, rdd20, &agh, &pdh);
    gampdt_eval(t + 0.1f,  alpha, days, rs20, jump, t_jump, inv2s2, pconst, rdd20, &ag1, &pd1);
    ag4[idx] = make_float4(agh, pdh, ag1, pd1);
}

// ---------------- ODE ----------------
__device__ __forceinline__ void deriv16(const float* y, float ag, float pd,
                                        float invN, float r_dth, float* d)
{
    float inf = ag * y[0] * y[2] * invN;
    float det = kR_D * y[2];
    float t1  = kR_I * y[1];
    float omp = 1.0f - pd;
    float dq  = det * omp;
    float dp  = det * pd;
    float dq003 = dq * 0.03f;
    float dp003 = dp * 0.03f;
    d[0]  = -inf;
    d[1]  = inf - t1;
    d[2]  = t1 - det;
    d[3]  = dq * 0.8f  - kR_RI * y[3];
    d[4]  = dq003      - kR_RH * y[4];
    d[5]  = dq * 0.17f - kR_RI * y[5];
    d[6]  = dp * 0.8f  - r_dth * y[6];
    d[7]  = dp003      - r_dth * y[7];
    d[8]  = dp * 0.17f - r_dth * y[8];
    d[9]  = kR_RI * (y[3] + y[5]) + kR_RH * y[4];
    d[10] = r_dth * ((y[6] + y[7]) + y[8]);
    d[11] = det * 0.03f;
    d[12] = 0.25f * dq003 - kR_RV * y[12];
    d[13] = 0.25f * dp003 - r_dth * y[13];
    d[14] = r_dth * (y[7] + y[8]);
    d[15] = det * 0.2f;
}

template<bool PRE>
__global__ __launch_bounds__(64)
void ode_kernel(const float* __restrict__ dnn, const float* __restrict__ pop,
                const float* __restrict__ ccn, const float* __restrict__ mort,
                const float4* __restrict__ ag4, float* __restrict__ sol)
{
    int e = blockIdx.x * 64 + threadIdx.x;      // 0..2047
    const float* p = dnn + e * 23 + 11;
    float alpha = p[0], days = p[1], r_s = p[2], r_dth = p[3], p_dth = p[4];
    float r_dthdecay = p[5], k1p = p[6], k2p = p[7], jump = p[8], t_jump = p[9], stdn = p[10];

    float N = pop[e];
    float invN = 1.0f / N;
    float PopI = ccn[e];
    float PopD = floorf(mort[e] * PopI);
    float R0v  = (PopI - PopD > 5.0f * PopD) ? 5.0f * PopD : 0.0f;
    float PopCI = PopI - PopD - R0v;
    float DP = PopCI / 0.2f;

    float y[16];
    y[0]  = N - DP * (k1p + k2p) - R0v / 0.2f - PopD / 0.2f;
    y[1]  = DP * k1p;
    y[2]  = DP * k2p;
    y[3]  = (DP - PopCI) * (1.0f - p_dth);
    y[4]  = PopCI * 0.15f * (1.0f - p_dth);
    y[5]  = PopCI * 0.85f * (1.0f - p_dth);
    y[6]  = (DP - PopCI) * p_dth;
    y[7]  = PopCI * 0.15f * p_dth;
    y[8]  = PopCI * 0.85f * p_dth;
    y[9]  = R0v / 0.2f;
    y[10] = PopD / 0.2f;
    y[11] = PopCI * 0.15f;
    y[12] = PopCI * 0.15f * 0.25f * (1.0f - p_dth);
    y[13] = PopCI * 0.15f * 0.25f * p_dth;
    y[14] = PopD;
    y[15] = PopI;

    {
        float* sp = sol + (size_t)e * (TPTS * 16);
        #pragma unroll
        for (int i = 0; i < 16; ++i) sp[i] = y[i];
    }

    float rs20   = r_s * 0.05f;
    float rdd20  = r_dthdecay * 0.05f;
    float inv2s2 = 1.0f / (2.0f * stdn * stdn);
    float pconst = 0.6366197723675814f * (p_dth - 0.001f);

    float ag0, pd0;
    gampdt_eval(0.0f, alpha, days, rs20, jump, t_jump, inv2s2, pconst, rdd20, &ag0, &pd0);

    // 2-deep register prefetch of the packed (agh,pdh,ag1,pd1) stream
    float4 c0v, c1v;
    if (PRE) {
        c0v = ag4[e];
        c1v = ag4[2048 + e];
    }

    for (int s = 0; s < NSEG; ++s) {
        float t0 = (float)s;
        for (int j = 0; j < NSUB; ++j) {
            float agh, pdh, ag1, pd1;
            if (PRE) {
                agh = c0v.x; pdh = c0v.y; ag1 = c0v.z; pd1 = c0v.w;
                int k2 = s * 10 + j + 2;
                c0v = c1v;
                if (k2 < NSTEPS) c1v = ag4[(size_t)k2 * 2048 + e];
            } else {
                float t = t0 + (float)j * 0.1f;
                gampdt_eval(t + 0.05f, alpha, days, rs20, jump, t_jump, inv2s2, pconst, rdd20, &agh, &pdh);
                gampdt_eval(t + 0.1f,  alpha, days, rs20, jump, t_jump, inv2s2, pconst, rdd20, &ag1, &pd1);
            }
            float d[16], acc[16], yt[16];
            deriv16(y, ag0, pd0, invN, r_dth, d);
            #pragma unroll
            for (int i = 0; i < 16; ++i) { acc[i] = d[i]; yt[i] = y[i] + 0.05f * d[i]; }
            deriv16(yt, agh, pdh, invN, r_dth, d);
            #pragma unroll
            for (int i = 0; i < 16; ++i) { acc[i] += 2.0f * d[i]; yt[i] = y[i] + 0.05f * d[i]; }
            deriv16(yt, agh, pdh, invN, r_dth, d);
            #pragma unroll
            for (int i = 0; i < 16; ++i) { acc[i] += 2.0f * d[i]; yt[i] = y[i] + 0.1f * d[i]; }
            deriv16(yt, ag1, pd1, invN, r_dth, d);
            #pragma unroll
            for (int i = 0; i < 16; ++i) y[i] += 0.016666668f * (acc[i] + d[i]);
            ag0 = ag1; pd0 = pd1;
        }
        float* sp = sol + (size_t)e * (TPTS * 16) + (size_t)(s + 1) * 16;
        #pragma unroll
        for (int i = 0; i < 16; ++i) sp[i] = y[i];
    }
}

// ---------------- host launch ----------------
extern "C" void kernel_launch(void* const* d_in, const int* in_sizes, int n_in,
                              void* d_out, int out_size, void* d_ws, size_t ws_size,
                              hipStream_t stream)
{
    const float* mi   = (const float*)d_in[0];
    const float* pop  = (const float*)d_in[1];
    const float* ccn  = (const float*)d_in[2];
    const float* mort = (const float*)d_in[3];
    const float* h0   = (const float*)d_in[4];
    const float* c0   = (const float*)d_in[5];
    const float* Wih0 = (const float*)d_in[6];
    const float* WihR = (const float*)d_in[7];
    const float* Whh  = (const float*)d_in[8];
    const float* bih  = (const float*)d_in[9];
    const float* bhh  = (const float*)d_in[10];
    const float* mW1  = (const float*)d_in[11];
    const float* mb1  = (const float*)d_in[12];
    const float* mW2  = (const float*)d_in[13];
    const float* mb2  = (const float*)d_in[14];
    const float* rW1  = (const float*)d_in[15];
    const float* rb1  = (const float*)d_in[16];
    const float* rW2  = (const float*)d_in[17];
    const float* rb2  = (const float*)d_in[18];
    const float* rng  = (const float*)d_in[19];
    const int*   ssp  = (const int*)d_in[20];

    float* out   = (float*)d_out;
    float* sol_o = out;                                   // 2048*90*16
    float* dnn_o = out + 2949120;                         // 2048*23
    float* ts_o  = out + 2949120 + 47104;                 // 2048*512
    float* raw_o = out + 2949120 + 47104 + 1048576;       // 2048*23

    float* ws  = (float*)d_ws;
    float* G   = ws;                    // 4,194,304 floats (also m1, then z2)
    float* Z   = ws + 4194304;          // 2,097,152
    float* X0  = ws + 6291456;          // 1,048,576
    float* X1  = ws + 7340032;          // 1,048,576
    float* x0p = ws + 8388608;          // 65,536
    float* xmp = ws + 8454144;          // 65,536
    float* Wp0 = ws + 8519680;          // 65,536
    float* Wpm = ws + 8585216;          // 16,384   (end 8,601,600)
    float4* AG4 = (float4*)(ws + 8601600);   // 890*2048 float4 = 7,290,880 floats
    bool usePre = ws_size >= (size_t)(8601600 + 7290880) * sizeof(float);

    prep_pad<<<256, 256, 0, stream>>>(mi, pop, Wih0, mW1, x0p, xmp, Wp0, Wpm);

    // meta MLP (G is free scratch until the LSTM loop)
    gemm_dual<1><<<dim3(4, 16), 256, 0, stream>>>(xmp, 32, Wpm, 32, 32,
                                                  nullptr, 0, nullptr, 0, 0,
                                                  mb1, nullptr, G, 512, 512);
    gemm_dual<1><<<dim3(4, 16), 256, 0, stream>>>(G, 512, mW2, 512, 512,
                                                  nullptr, 0, nullptr, 0, 0,
                                                  mb2, nullptr, Z + 512, 1024, 512);

    // 5-layer LSTM cell stack
    for (int l = 0; l < 5; ++l) {
        const float* A1   = (l == 0) ? x0p : ((l & 1) ? X1 : X0);
        int          K1   = (l == 0) ? 32 : 512;
        const float* W1   = (l == 0) ? Wp0 : (WihR + (size_t)(l - 1) * 1048576);
        gemm_dual<0><<<dim3(16, 16), 256, 0, stream>>>(
            A1, K1, W1, K1, K1,
            h0 + (size_t)l * 1048576, 512, Whh + (size_t)l * 1048576, 512, 512,
            bih + l * 2048, bhh + l * 2048, G, 2048, 2048);
        float* xo  = (l == 4) ? Z : ((l & 1) ? X0 : X1);
        int    xol = (l == 4) ? 1024 : 512;
        lstm_gates<<<4096, 256, 0, stream>>>(G, c0 + (size_t)l * 1048576, xo, xol,
                                             (l == 4) ? ts_o : nullptr);
    }

    // readout
    gemm_dual<2><<<dim3(8, 16), 256, 0, stream>>>(Z, 1024, rW1, 1024, 1024,
                                                  nullptr, 0, nullptr, 0, 0,
                                                  rb1, nullptr, G, 1024, 1024);
    gemm_dual<0><<<dim3(1, 16), 256, 0, stream>>>(G, 1024, rW2, 1024, 1024,
                                                  nullptr, 0, nullptr, 0, 0,
                                                  rb2, nullptr, raw_o, 23, 23);
    dnn_kernel<<<184, 256, 0, stream>>>(raw_o, ssp, rng, dnn_o);

    // ODE
    if (usePre) {
        gampdt4_kernel<<<(NSTEPS * 2048 + 255) / 256, 256, 0, stream>>>(dnn_o, AG4);
        ode_kernel<true><<<32, 64, 0, stream>>>(dnn_o, pop, ccn, mort, AG4, sol_o);
    } else {
        ode_kernel<false><<<32, 64, 0, stream>>>(dnn_o, pop, ccn, mort, nullptr, sol_o);
    }
    (void)in_sizes; (void)n_in; (void)out_size;
}

// Round 3
// 1211.506 us; speedup vs baseline: 1.7729x; 1.2328x over previous
//
#include <hip/hip_runtime.h>
#include <hip/hip_bf16.h>
#include <math.h>

// ---------------- problem constants ----------------
#define BATCH 2048
#define HID 512
#define TPTS 90
#define NSEG 89
#define NSUB 10
#define NSTEPS 890          // NSEG*NSUB global substeps

__device__ __constant__ const float kR_I  = 0.6931471805599453f / 5.0f;
__device__ __constant__ const float kR_D  = 0.6931471805599453f / 2.0f;
__device__ __constant__ const float kR_RI = 0.6931471805599453f / 10.0f;
__device__ __constant__ const float kR_RH = 0.6931471805599453f / 15.0f;
__device__ __constant__ const float kR_RV = 0.6931471805599453f / 10.0f;

typedef __attribute__((ext_vector_type(8))) short short8;
typedef __attribute__((ext_vector_type(4))) float float4v;

__device__ __forceinline__ float sigmoidf_(float x) { return 1.0f / (1.0f + expf(-x)); }

// ---------------- prep: pad K=30 operands to K=32, x = mi[:, :30]/pop ----------------
__global__ void prep_pad(const float* __restrict__ mi, const float* __restrict__ pop,
                         const float* __restrict__ Wih0, const float* __restrict__ mW1,
                         float* __restrict__ x0p, float* __restrict__ xmp,
                         float* __restrict__ Wp0, float* __restrict__ Wpm)
{
    int i = blockIdx.x * 256 + threadIdx.x;     // < 2048*32
    int r = i >> 5, c = i & 31;
    bool v = (c < 30);
    x0p[i] = v ? mi[r * 60 + c] / pop[r] : 0.0f;
    xmp[i] = v ? mi[r * 60 + 30 + c] : 0.0f;
    Wp0[i] = v ? Wih0[r * 30 + c] : 0.0f;
    if (r < 512) Wpm[i] = v ? mW1[r * 30 + c] : 0.0f;
}

// ---------------- hi/lo bf16 split + K-concat packing ----------------
// A-mode (WMODE=false): segments [hi | hi | lo]
// W-mode (WMODE=true):  segments [hi | lo | hi]
// Dual-source: cols [0,K1) from s1, [K1,K1+K2) from s2; dst row stride 3*(K1+K2).
template<bool WMODE>
__global__ void pack_split(const float* __restrict__ s1, int ld1, int K1,
                           const float* __restrict__ s2, int ld2, int K2,
                           __hip_bfloat16* __restrict__ dst, int rows)
{
    int idx = blockIdx.x * 256 + threadIdx.x;
    int Ks = K1 + K2;
    if (idx >= rows * Ks) return;
    int r = idx / Ks, k = idx - r * Ks;
    float x; int base, seg, kk;
    if (k < K1) { x = s1[(size_t)r * ld1 + k]; base = 0; seg = K1; kk = k; }
    else        { kk = k - K1; x = s2[(size_t)r * ld2 + kk]; base = 3 * K1; seg = K2; }
    __hip_bfloat16 hi = __float2bfloat16(x);
    __hip_bfloat16 lo = __float2bfloat16(x - __bfloat162float(hi));
    __hip_bfloat16* d = dst + (size_t)r * (3 * Ks) + base;
    d[kk]           = hi;
    d[seg + kk]     = WMODE ? lo : hi;
    d[2 * seg + kk] = WMODE ? hi : lo;
}

// ---------------- bf16 MFMA GEMM-NT: C[m][n] = sum_k Ah[m][k]*Wh[n][k] (+bias,+act) ----
// M=2048 fixed; N multiple of 128; K3 multiple of 32.  128x128 tile, BK=32,
// 256 thr = 4 waves, each wave a 64x64 quadrant via 4x4 mfma_f32_16x16x32_bf16.
// ACT: 0=none, 1=relu, 2=tanh
template<int ACT>
__global__ __launch_bounds__(256)
void gemm_mfma(const __hip_bfloat16* __restrict__ Ah,
               const __hip_bfloat16* __restrict__ Wh, int K3,
               const float* __restrict__ b1, const float* __restrict__ b2,
               float* __restrict__ Cp, int ldc, int N)
{
    __shared__ __hip_bfloat16 As[128 * 32];
    __shared__ __hip_bfloat16 Ws[128 * 32];
    const int tid  = threadIdx.x;
    const int m0   = blockIdx.y * 128;
    const int n0   = blockIdx.x * 128;
    const int lane = tid & 63, wv = tid >> 6;
    const int mw   = (wv >> 1) * 64, nw = (wv & 1) * 64;
    const int l15  = lane & 15, quad = lane >> 4;
    const int sr   = tid >> 2;          // staging row 0..63
    const int sc   = (tid & 3) * 8;     // staging col {0,8,16,24}

    float4v acc[4][4];
    #pragma unroll
    for (int i = 0; i < 4; ++i)
        #pragma unroll
        for (int j = 0; j < 4; ++j)
            acc[i][j] = (float4v){0.0f, 0.0f, 0.0f, 0.0f};

    for (int kt = 0; kt < K3; kt += 32) {
        short8 a0 = *(const short8*)(Ah + (size_t)(m0 + sr)      * K3 + kt + sc);
        short8 a1 = *(const short8*)(Ah + (size_t)(m0 + sr + 64) * K3 + kt + sc);
        short8 w0 = *(const short8*)(Wh + (size_t)(n0 + sr)      * K3 + kt + sc);
        short8 w1 = *(const short8*)(Wh + (size_t)(n0 + sr + 64) * K3 + kt + sc);
        __syncthreads();                 // previous iter's LDS reads done
        *(short8*)(As + sr * 32 + sc)        = a0;
        *(short8*)(As + (sr + 64) * 32 + sc) = a1;
        *(short8*)(Ws + sr * 32 + sc)        = w0;
        *(short8*)(Ws + (sr + 64) * 32 + sc) = w1;
        __syncthreads();
        short8 af[4], bf[4];
        #pragma unroll
        for (int t = 0; t < 4; ++t) {
            af[t] = *(const short8*)(As + (mw + t * 16 + l15) * 32 + quad * 8);
            bf[t] = *(const short8*)(Ws + (nw + t * 16 + l15) * 32 + quad * 8);
        }
        #pragma unroll
        for (int i = 0; i < 4; ++i)
            #pragma unroll
            for (int j = 0; j < 4; ++j)
                acc[i][j] = __builtin_amdgcn_mfma_f32_16x16x32_bf16(af[i], bf[j], acc[i][j], 0, 0, 0);
    }

    // epilogue: C/D layout col = lane&15, row = quad*4 + reg
    #pragma unroll
    for (int j = 0; j < 4; ++j) {
        int col = n0 + nw + j * 16 + l15;
        float bias = b1[col] + (b2 ? b2[col] : 0.0f);
        #pragma unroll
        for (int i = 0; i < 4; ++i) {
            #pragma unroll
            for (int r = 0; r < 4; ++r) {
                int row = m0 + mw + i * 16 + quad * 4 + r;
                float v = acc[i][j][r] + bias;
                if (ACT == 1)      v = fmaxf(v, 0.0f);
                else if (ACT == 2) v = tanhf(v);
                Cp[(size_t)row * ldc + col] = v;
            }
        }
    }
}

// ---------------- fp32 tiled GEMM-NT (kept for small GEMMs + fallback) ----------------
template<int ACT>
__global__ __launch_bounds__(256)
void gemm_dual(const float* __restrict__ A1, int lda1,
               const float* __restrict__ W1, int ldw1, int K1,
               const float* __restrict__ A2, int lda2,
               const float* __restrict__ W2, int ldw2, int K2,
               const float* __restrict__ b1p, const float* __restrict__ b2p,
               float* __restrict__ Cp, int ldc, int N)
{
    __shared__ float As[8][128];
    __shared__ float Ws[8][128];
    const int tid  = threadIdx.x;
    const int m0   = blockIdx.y * 128;
    const int n0   = blockIdx.x * 128;
    const int tm   = tid >> 4;
    const int tn   = tid & 15;
    const int lrow = tid >> 1;
    const int lkh  = (tid & 1) << 2;
    const int wrow = n0 + lrow;
    const int Ktot = K1 + K2;

    float acc[8][8];
    #pragma unroll
    for (int i = 0; i < 8; ++i)
        #pragma unroll
        for (int j = 0; j < 8; ++j) acc[i][j] = 0.0f;

    float4 av = *(const float4*)(A1 + (size_t)(m0 + lrow) * lda1 + lkh);
    float4 wv = make_float4(0.0f, 0.0f, 0.0f, 0.0f);
    if (wrow < N) wv = *(const float4*)(W1 + (size_t)wrow * ldw1 + lkh);

    for (int kt = 0; kt < Ktot; kt += 8) {
        __syncthreads();
        As[lkh + 0][lrow] = av.x; As[lkh + 1][lrow] = av.y;
        As[lkh + 2][lrow] = av.z; As[lkh + 3][lrow] = av.w;
        Ws[lkh + 0][lrow] = wv.x; Ws[lkh + 1][lrow] = wv.y;
        Ws[lkh + 2][lrow] = wv.z; Ws[lkh + 3][lrow] = wv.w;
        __syncthreads();

        int kn = kt + 8;
        float4 avn = make_float4(0.0f, 0.0f, 0.0f, 0.0f);
        float4 wvn = avn;
        if (kn < Ktot) {
            if (kn < K1) {
                avn = *(const float4*)(A1 + (size_t)(m0 + lrow) * lda1 + kn + lkh);
                if (wrow < N) wvn = *(const float4*)(W1 + (size_t)wrow * ldw1 + kn + lkh);
            } else {
                int k2 = kn - K1;
                avn = *(const float4*)(A2 + (size_t)(m0 + lrow) * lda2 + k2 + lkh);
                if (wrow < N) wvn = *(const float4*)(W2 + (size_t)wrow * ldw2 + k2 + lkh);
            }
        }

        #pragma unroll
        for (int kk = 0; kk < 8; ++kk) {
            float af[8], wf[8];
            #pragma unroll
            for (int i = 0; i < 4; ++i) {
                af[i]     = As[kk][tm * 8 + i];
                af[i + 4] = As[kk][tm * 8 + 4 + i];
                wf[i]     = Ws[kk][tn * 4 + i];
                wf[i + 4] = Ws[kk][64 + tn * 4 + i];
            }
            #pragma unroll
            for (int i = 0; i < 8; ++i)
                #pragma unroll
                for (int j = 0; j < 8; ++j)
                    acc[i][j] += af[i] * wf[j];
        }
        av = avn; wv = wvn;
    }

    #pragma unroll
    for (int j = 0; j < 8; ++j) {
        int col = n0 + ((j < 4) ? (tn * 4 + j) : (64 + tn * 4 + (j - 4)));
        if (col >= N) continue;
        float bias = b1p[col] + (b2p ? b2p[col] : 0.0f);
        #pragma unroll
        for (int i = 0; i < 8; ++i) {
            int rrow = m0 + tm * 8 + i;
            float v = acc[i][j] + bias;
            if (ACT == 1) v = fmaxf(v, 0.0f);
            else if (ACT == 2) v = tanhf(v);
            Cp[(size_t)rrow * ldc + col] = v;
        }
    }
}

// ---------------- LSTM gate nonlinearity ----------------
__global__ void lstm_gates(const float* __restrict__ G_, const float* __restrict__ c0l,
                           float* __restrict__ xout, int xld, float* __restrict__ ts)
{
    int i = blockIdx.x * 256 + threadIdx.x;     // < 2048*512
    int m = i >> 9, h = i & 511;
    const float* g = G_ + (size_t)m * 2048 + h;
    float gi = g[0], gf = g[512], gg = g[1024], go = g[1536];
    float c = sigmoidf_(gf) * c0l[i] + sigmoidf_(gi) * tanhf(gg);
    float x = sigmoidf_(go) * tanhf(c);
    xout[(size_t)m * xld + h] = x;
    if (ts) ts[i] = x;
}

// ---------------- dnn = sigmoid(raw*ss) * range ----------------
__global__ void dnn_kernel(const float* __restrict__ raw, const int* __restrict__ ssp,
                           const float* __restrict__ rng, float* __restrict__ dnn)
{
    int i = blockIdx.x * 256 + threadIdx.x;
    if (i >= 2048 * 23) return;
    int c = i % 23;
    int v = *ssp;
    float ss = (v > 100000 || v < 0) ? __int_as_float(v) : (float)v;
    dnn[i] = sigmoidf_(raw[i] * ss) * rng[c];
}

// ---------------- gam/pdt evaluation ----------------
__device__ __forceinline__ void gampdt_eval(float t, float alpha, float days, float rs20,
                                            float jump, float t_jump, float inv2s2,
                                            float pconst, float rdd20, float* ag, float* pd)
{
    float dtj = t - t_jump;
    float g = 0.6366197723675814f * atanf((days - t) * rs20) + 1.0f + jump * expf(-(dtj * dtj) * inv2s2);
    *ag = alpha * g;
    *pd = pconst * (atanf(-t * rdd20) + 1.5707963267948966f) + 0.001f;
}

// pack (ag_half, pd_half, ag_end, pd_end) per (substep k, chain e) as float4
__global__ void gampdt4_kernel(const float* __restrict__ dnn, float4* __restrict__ ag4)
{
    int idx = blockIdx.x * 256 + threadIdx.x;
    if (idx >= NSTEPS * 2048) return;
    int e = idx & 2047;
    int k = idx >> 11;
    int s = k / 10, j = k - s * 10;
    const float* p = dnn + e * 23 + 11;
    float alpha = p[0], days = p[1], r_s = p[2], p_dth = p[4], r_dthdecay = p[5];
    float jump = p[8], t_jump = p[9], stdn = p[10];
    float rs20   = r_s * 0.05f;
    float rdd20  = r_dthdecay * 0.05f;
    float inv2s2 = 1.0f / (2.0f * stdn * stdn);
    float pconst = 0.6366197723675814f * (p_dth - 0.001f);
    float t = (float)s + (float)j * 0.1f;
    float agh, pdh, ag1, pd1;
    gampdt_eval(t + 0.05f, alpha, days, rs20, jump, t_jump, inv2s2, pconst, rdd20, &agh, &pdh);
    gampdt_eval(t + 0.1f,  alpha, days, rs20, jump, t_jump, inv2s2, pconst, rdd20, &ag1, &pd1);
    ag4[idx] = make_float4(agh, pdh, ag1, pd1);
}

// ---------------- ODE ----------------
__device__ __forceinline__ void deriv16(const float* y, float ag, float pd,
                                        float invN, float r_dth, float* d)
{
    float inf = ag * y[0] * y[2] * invN;
    float det = kR_D * y[2];
    float t1  = kR_I * y[1];
    float omp = 1.0f - pd;
    float dq  = det * omp;
    float dp  = det * pd;
    float dq003 = dq * 0.03f;
    float dp003 = dp * 0.03f;
    d[0]  = -inf;
    d[1]  = inf - t1;
    d[2]  = t1 - det;
    d[3]  = dq * 0.8f  - kR_RI * y[3];
    d[4]  = dq003      - kR_RH * y[4];
    d[5]  = dq * 0.17f - kR_RI * y[5];
    d[6]  = dp * 0.8f  - r_dth * y[6];
    d[7]  = dp003      - r_dth * y[7];
    d[8]  = dp * 0.17f - r_dth * y[8];
    d[9]  = kR_RI * (y[3] + y[5]) + kR_RH * y[4];
    d[10] = r_dth * ((y[6] + y[7]) + y[8]);
    d[11] = det * 0.03f;
    d[12] = 0.25f * dq003 - kR_RV * y[12];
    d[13] = 0.25f * dp003 - r_dth * y[13];
    d[14] = r_dth * (y[7] + y[8]);
    d[15] = det * 0.2f;
}

template<bool PRE>
__global__ __launch_bounds__(64)
void ode_kernel(const float* __restrict__ dnn, const float* __restrict__ pop,
                const float* __restrict__ ccn, const float* __restrict__ mort,
                const float4* __restrict__ ag4, float* __restrict__ sol)
{
    int e = blockIdx.x * 64 + threadIdx.x;      // 0..2047
    const float* p = dnn + e * 23 + 11;
    float alpha = p[0], days = p[1], r_s = p[2], r_dth = p[3], p_dth = p[4];
    float r_dthdecay = p[5], k1p = p[6], k2p = p[7], jump = p[8], t_jump = p[9], stdn = p[10];

    float N = pop[e];
    float invN = 1.0f / N;
    float PopI = ccn[e];
    float PopD = floorf(mort[e] * PopI);
    float R0v  = (PopI - PopD > 5.0f * PopD) ? 5.0f * PopD : 0.0f;
    float PopCI = PopI - PopD - R0v;
    float DP = PopCI / 0.2f;

    float y[16];
    y[0]  = N - DP * (k1p + k2p) - R0v / 0.2f - PopD / 0.2f;
    y[1]  = DP * k1p;
    y[2]  = DP * k2p;
    y[3]  = (DP - PopCI) * (1.0f - p_dth);
    y[4]  = PopCI * 0.15f * (1.0f - p_dth);
    y[5]  = PopCI * 0.85f * (1.0f - p_dth);
    y[6]  = (DP - PopCI) * p_dth;
    y[7]  = PopCI * 0.15f * p_dth;
    y[8]  = PopCI * 0.85f * p_dth;
    y[9]  = R0v / 0.2f;
    y[10] = PopD / 0.2f;
    y[11] = PopCI * 0.15f;
    y[12] = PopCI * 0.15f * 0.25f * (1.0f - p_dth);
    y[13] = PopCI * 0.15f * 0.25f * p_dth;
    y[14] = PopD;
    y[15] = PopI;

    {
        float* sp = sol + (size_t)e * (TPTS * 16);
        #pragma unroll
        for (int i = 0; i < 16; ++i) sp[i] = y[i];
    }

    float rs20   = r_s * 0.05f;
    float rdd20  = r_dthdecay * 0.05f;
    float inv2s2 = 1.0f / (2.0f * stdn * stdn);
    float pconst = 0.6366197723675814f * (p_dth - 0.001f);

    float ag0, pd0;
    gampdt_eval(0.0f, alpha, days, rs20, jump, t_jump, inv2s2, pconst, rdd20, &ag0, &pd0);

    float4 c0v, c1v;
    if (PRE) {
        c0v = ag4[e];
        c1v = ag4[2048 + e];
    }

    for (int s = 0; s < NSEG; ++s) {
        float t0 = (float)s;
        for (int j = 0; j < NSUB; ++j) {
            float agh, pdh, ag1, pd1;
            if (PRE) {
                agh = c0v.x; pdh = c0v.y; ag1 = c0v.z; pd1 = c0v.w;
                int k2 = s * 10 + j + 2;
                c0v = c1v;
                if (k2 < NSTEPS) c1v = ag4[(size_t)k2 * 2048 + e];
            } else {
                float t = t0 + (float)j * 0.1f;
                gampdt_eval(t + 0.05f, alpha, days, rs20, jump, t_jump, inv2s2, pconst, rdd20, &agh, &pdh);
                gampdt_eval(t + 0.1f,  alpha, days, rs20, jump, t_jump, inv2s2, pconst, rdd20, &ag1, &pd1);
            }
            float d[16], acc[16], yt[16];
            deriv16(y, ag0, pd0, invN, r_dth, d);
            #pragma unroll
            for (int i = 0; i < 16; ++i) { acc[i] = d[i]; yt[i] = y[i] + 0.05f * d[i]; }
            deriv16(yt, agh, pdh, invN, r_dth, d);
            #pragma unroll
            for (int i = 0; i < 16; ++i) { acc[i] += 2.0f * d[i]; yt[i] = y[i] + 0.05f * d[i]; }
            deriv16(yt, agh, pdh, invN, r_dth, d);
            #pragma unroll
            for (int i = 0; i < 16; ++i) { acc[i] += 2.0f * d[i]; yt[i] = y[i] + 0.1f * d[i]; }
            deriv16(yt, ag1, pd1, invN, r_dth, d);
            #pragma unroll
            for (int i = 0; i < 16; ++i) y[i] += 0.016666668f * (acc[i] + d[i]);
            ag0 = ag1; pd0 = pd1;
        }
        float* sp = sol + (size_t)e * (TPTS * 16) + (size_t)(s + 1) * 16;
        #pragma unroll
        for (int i = 0; i < 16; ++i) sp[i] = y[i];
    }
}

// ---------------- host launch ----------------
extern "C" void kernel_launch(void* const* d_in, const int* in_sizes, int n_in,
                              void* d_out, int out_size, void* d_ws, size_t ws_size,
                              hipStream_t stream)
{
    const float* mi   = (const float*)d_in[0];
    const float* pop  = (const float*)d_in[1];
    const float* ccn  = (const float*)d_in[2];
    const float* mort = (const float*)d_in[3];
    const float* h0   = (const float*)d_in[4];
    const float* c0   = (const float*)d_in[5];
    const float* Wih0 = (const float*)d_in[6];
    const float* WihR = (const float*)d_in[7];
    const float* Whh  = (const float*)d_in[8];
    const float* bih  = (const float*)d_in[9];
    const float* bhh  = (const float*)d_in[10];
    const float* mW1  = (const float*)d_in[11];
    const float* mb1  = (const float*)d_in[12];
    const float* mW2  = (const float*)d_in[13];
    const float* mb2  = (const float*)d_in[14];
    const float* rW1  = (const float*)d_in[15];
    const float* rb1  = (const float*)d_in[16];
    const float* rW2  = (const float*)d_in[17];
    const float* rb2  = (const float*)d_in[18];
    const float* rng  = (const float*)d_in[19];
    const int*   ssp  = (const int*)d_in[20];

    float* out   = (float*)d_out;
    float* sol_o = out;                                   // 2048*90*16
    float* dnn_o = out + 2949120;                         // 2048*23
    float* ts_o  = out + 2949120 + 47104;                 // 2048*512
    float* raw_o = out + 2949120 + 47104 + 1048576;       // 2048*23

    float* ws  = (float*)d_ws;
    float* G   = ws;                    // 4,194,304 floats (m1 scratch, gates, ro1 out)
    float* Z   = ws + 4194304;          // 2,097,152  (concat [ts | m], ld 1024)
    float* X0  = ws + 6291456;          // 1,048,576
    float* X1  = ws + 7340032;          // 1,048,576
    float* x0p = ws + 8388608;          // 65,536
    float* xmp = ws + 8454144;          // 65,536
    float* Wp0 = ws + 8519680;          // 65,536
    float* Wpm = ws + 8585216;          // 16,384   (end 8,601,600)
    // pack region (reused), aliased later by AG4:
    __hip_bfloat16* Ab = (__hip_bfloat16*)(ws + 8601600);            // 6,291,456 bf16
    __hip_bfloat16* Wb = (__hip_bfloat16*)(ws + 8601600 + 3145728);  // 6,291,456 bf16 (end 14,893,056 fl)
    float4* AG4 = (float4*)(ws + 8601600);                           // 890*2048 float4 (end 15,892,480 fl)
    bool wsOK = ws_size >= (size_t)15892480 * sizeof(float);

    prep_pad<<<256, 256, 0, stream>>>(mi, pop, Wih0, mW1, x0p, xmp, Wp0, Wpm);

    // meta layer 1 (tiny K=32) — vector GEMM -> G (m1, ld 512)
    gemm_dual<1><<<dim3(4, 16), 256, 0, stream>>>(xmp, 32, Wpm, 32, 32,
                                                  nullptr, 0, nullptr, 0, 0,
                                                  mb1, nullptr, G, 512, 512);

    if (wsOK) {
        // meta layer 2 via MFMA: K3 = 3*512
        pack_split<false><<<(2048 * 512 + 255) / 256, 256, 0, stream>>>(G, 512, 512, nullptr, 0, 0, Ab, 2048);
        pack_split<true ><<<(512  * 512 + 255) / 256, 256, 0, stream>>>(mW2, 512, 512, nullptr, 0, 0, Wb, 512);
        gemm_mfma<1><<<dim3(4, 16), 256, 0, stream>>>(Ab, Wb, 1536, mb2, nullptr, Z + 512, 1024, 512);

        // 5-layer LSTM cell stack via MFMA
        for (int l = 0; l < 5; ++l) {
            const float* A1 = (l == 0) ? x0p : ((l & 1) ? X1 : X0);
            int          K1 = (l == 0) ? 32 : 512;
            const float* W1 = (l == 0) ? Wp0 : (WihR + (size_t)(l - 1) * 1048576);
            int K3 = 3 * (K1 + 512);
            pack_split<false><<<(2048 * (K1 + 512) + 255) / 256, 256, 0, stream>>>(
                A1, K1, K1, h0 + (size_t)l * 1048576, 512, 512, Ab, 2048);
            pack_split<true ><<<(2048 * (K1 + 512) + 255) / 256, 256, 0, stream>>>(
                W1, K1, K1, Whh + (size_t)l * 1048576, 512, 512, Wb, 2048);
            gemm_mfma<0><<<dim3(16, 16), 256, 0, stream>>>(
                Ab, Wb, K3, bih + l * 2048, bhh + l * 2048, G, 2048, 2048);
            float* xo  = (l == 4) ? Z : ((l & 1) ? X0 : X1);
            int    xol = (l == 4) ? 1024 : 512;
            lstm_gates<<<4096, 256, 0, stream>>>(G, c0 + (size_t)l * 1048576, xo, xol,
                                                 (l == 4) ? ts_o : nullptr);
        }

        // readout 1 via MFMA (tanh): K3 = 3*1024, N=1024
        pack_split<false><<<(2048 * 1024 + 255) / 256, 256, 0, stream>>>(Z, 1024, 1024, nullptr, 0, 0, Ab, 2048);
        pack_split<true ><<<(1024 * 1024 + 255) / 256, 256, 0, stream>>>(rW1, 1024, 1024, nullptr, 0, 0, Wb, 1024);
        gemm_mfma<2><<<dim3(8, 16), 256, 0, stream>>>(Ab, Wb, 3072, rb1, nullptr, G, 1024, 1024);
    } else {
        // fallback: full vector path
        gemm_dual<1><<<dim3(4, 16), 256, 0, stream>>>(G, 512, mW2, 512, 512,
                                                      nullptr, 0, nullptr, 0, 0,
                                                      mb2, nullptr, Z + 512, 1024, 512);
        for (int l = 0; l < 5; ++l) {
            const float* A1 = (l == 0) ? x0p : ((l & 1) ? X1 : X0);
            int          K1 = (l == 0) ? 32 : 512;
            const float* W1 = (l == 0) ? Wp0 : (WihR + (size_t)(l - 1) * 1048576);
            gemm_dual<0><<<dim3(16, 16), 256, 0, stream>>>(
                A1, K1, W1, K1, K1,
                h0 + (size_t)l * 1048576, 512, Whh + (size_t)l * 1048576, 512, 512,
                bih + l * 2048, bhh + l * 2048, G, 2048, 2048);
            float* xo  = (l == 4) ? Z : ((l & 1) ? X0 : X1);
            int    xol = (l == 4) ? 1024 : 512;
            lstm_gates<<<4096, 256, 0, stream>>>(G, c0 + (size_t)l * 1048576, xo, xol,
                                                 (l == 4) ? ts_o : nullptr);
        }
        gemm_dual<2><<<dim3(8, 16), 256, 0, stream>>>(Z, 1024, rW1, 1024, 1024,
                                                      nullptr, 0, nullptr, 0, 0,
                                                      rb1, nullptr, G, 1024, 1024);
    }

    // readout 2 (N=23) — vector GEMM -> raw
    gemm_dual<0><<<dim3(1, 16), 256, 0, stream>>>(G, 1024, rW2, 1024, 1024,
                                                  nullptr, 0, nullptr, 0, 0,
                                                  rb2, nullptr, raw_o, 23, 23);
    dnn_kernel<<<184, 256, 0, stream>>>(raw_o, ssp, rng, dnn_o);

    // ODE
    if (wsOK) {
        gampdt4_kernel<<<(NSTEPS * 2048 + 255) / 256, 256, 0, stream>>>(dnn_o, AG4);
        ode_kernel<true><<<32, 64, 0, stream>>>(dnn_o, pop, ccn, mort, AG4, sol_o);
    } else {
        ode_kernel<false><<<32, 64, 0, stream>>>(dnn_o, pop, ccn, mort, nullptr, sol_o);
    }
    (void)in_sizes; (void)n_in; (void)out_size;
}

// Round 4
// 1089.207 us; speedup vs baseline: 1.9720x; 1.1123x over previous
//
#include <hip/hip_runtime.h>
#include <hip/hip_bf16.h>
#include <math.h>

// ---------------- problem constants ----------------
#define BATCH 2048
#define HID 512
#define TPTS 90
#define NSEG 89
#define NSUB 10
#define NSTEPS 890          // NSEG*NSUB global substeps

__device__ __constant__ const float kR_I  = 0.6931471805599453f / 5.0f;
__device__ __constant__ const float kR_D  = 0.6931471805599453f / 2.0f;
__device__ __constant__ const float kR_RI = 0.6931471805599453f / 10.0f;
__device__ __constant__ const float kR_RH = 0.6931471805599453f / 15.0f;
__device__ __constant__ const float kR_RV = 0.6931471805599453f / 10.0f;

typedef __attribute__((ext_vector_type(8))) short short8;
typedef __attribute__((ext_vector_type(4))) float float4v;

__device__ __forceinline__ float sigmoidf_(float x) { return 1.0f / (1.0f + expf(-x)); }

// ---------------- prep: pad K=30 operands to K=32, x = mi[:, :30]/pop ----------------
__global__ void prep_pad(const float* __restrict__ mi, const float* __restrict__ pop,
                         const float* __restrict__ Wih0, const float* __restrict__ mW1,
                         float* __restrict__ x0p, float* __restrict__ xmp,
                         float* __restrict__ Wp0, float* __restrict__ Wpm)
{
    int i = blockIdx.x * 256 + threadIdx.x;     // < 2048*32
    int r = i >> 5, c = i & 31;
    bool v = (c < 30);
    x0p[i] = v ? mi[r * 60 + c] / pop[r] : 0.0f;
    xmp[i] = v ? mi[r * 60 + 30 + c] : 0.0f;
    Wp0[i] = v ? Wih0[r * 30 + c] : 0.0f;
    if (r < 512) Wpm[i] = v ? mW1[r * 30 + c] : 0.0f;
}

// ---------------- hi/lo bf16 split + K-concat packing ----------------
// A-mode (WMODE=false): segments [hi | hi | lo]
// W-mode (WMODE=true):  segments [hi | lo | hi]
template<bool WMODE>
__global__ void pack_split(const float* __restrict__ s1, int ld1, int K1,
                           const float* __restrict__ s2, int ld2, int K2,
                           __hip_bfloat16* __restrict__ dst, int rows)
{
    int idx = blockIdx.x * 256 + threadIdx.x;
    int Ks = K1 + K2;
    if (idx >= rows * Ks) return;
    int r = idx / Ks, k = idx - r * Ks;
    float x; int base, seg, kk;
    if (k < K1) { x = s1[(size_t)r * ld1 + k]; base = 0; seg = K1; kk = k; }
    else        { kk = k - K1; x = s2[(size_t)r * ld2 + kk]; base = 3 * K1; seg = K2; }
    __hip_bfloat16 hi = __float2bfloat16(x);
    __hip_bfloat16 lo = __float2bfloat16(x - __bfloat162float(hi));
    __hip_bfloat16* d = dst + (size_t)r * (3 * Ks) + base;
    d[kk]           = hi;
    d[seg + kk]     = WMODE ? lo : hi;
    d[2 * seg + kk] = WMODE ? hi : lo;
}

// ---------------- bf16 MFMA GEMM-NT ----------------
template<int ACT>
__global__ __launch_bounds__(256)
void gemm_mfma(const __hip_bfloat16* __restrict__ Ah,
               const __hip_bfloat16* __restrict__ Wh, int K3,
               const float* __restrict__ b1, const float* __restrict__ b2,
               float* __restrict__ Cp, int ldc, int N)
{
    __shared__ __hip_bfloat16 As[128 * 32];
    __shared__ __hip_bfloat16 Ws[128 * 32];
    const int tid  = threadIdx.x;
    const int m0   = blockIdx.y * 128;
    const int n0   = blockIdx.x * 128;
    const int lane = tid & 63, wv = tid >> 6;
    const int mw   = (wv >> 1) * 64, nw = (wv & 1) * 64;
    const int l15  = lane & 15, quad = lane >> 4;
    const int sr   = tid >> 2;
    const int sc   = (tid & 3) * 8;

    float4v acc[4][4];
    #pragma unroll
    for (int i = 0; i < 4; ++i)
        #pragma unroll
        for (int j = 0; j < 4; ++j)
            acc[i][j] = (float4v){0.0f, 0.0f, 0.0f, 0.0f};

    for (int kt = 0; kt < K3; kt += 32) {
        short8 a0 = *(const short8*)(Ah + (size_t)(m0 + sr)      * K3 + kt + sc);
        short8 a1 = *(const short8*)(Ah + (size_t)(m0 + sr + 64) * K3 + kt + sc);
        short8 w0 = *(const short8*)(Wh + (size_t)(n0 + sr)      * K3 + kt + sc);
        short8 w1 = *(const short8*)(Wh + (size_t)(n0 + sr + 64) * K3 + kt + sc);
        __syncthreads();
        *(short8*)(As + sr * 32 + sc)        = a0;
        *(short8*)(As + (sr + 64) * 32 + sc) = a1;
        *(short8*)(Ws + sr * 32 + sc)        = w0;
        *(short8*)(Ws + (sr + 64) * 32 + sc) = w1;
        __syncthreads();
        short8 af[4], bf[4];
        #pragma unroll
        for (int t = 0; t < 4; ++t) {
            af[t] = *(const short8*)(As + (mw + t * 16 + l15) * 32 + quad * 8);
            bf[t] = *(const short8*)(Ws + (nw + t * 16 + l15) * 32 + quad * 8);
        }
        #pragma unroll
        for (int i = 0; i < 4; ++i)
            #pragma unroll
            for (int j = 0; j < 4; ++j)
                acc[i][j] = __builtin_amdgcn_mfma_f32_16x16x32_bf16(af[i], bf[j], acc[i][j], 0, 0, 0);
    }

    #pragma unroll
    for (int j = 0; j < 4; ++j) {
        int col = n0 + nw + j * 16 + l15;
        float bias = b1[col] + (b2 ? b2[col] : 0.0f);
        #pragma unroll
        for (int i = 0; i < 4; ++i) {
            #pragma unroll
            for (int r = 0; r < 4; ++r) {
                int row = m0 + mw + i * 16 + quad * 4 + r;
                float v = acc[i][j][r] + bias;
                if (ACT == 1)      v = fmaxf(v, 0.0f);
                else if (ACT == 2) v = tanhf(v);
                Cp[(size_t)row * ldc + col] = v;
            }
        }
    }
}

// ---------------- fp32 tiled GEMM-NT (small GEMMs + fallback) ----------------
template<int ACT>
__global__ __launch_bounds__(256)
void gemm_dual(const float* __restrict__ A1, int lda1,
               const float* __restrict__ W1, int ldw1, int K1,
               const float* __restrict__ A2, int lda2,
               const float* __restrict__ W2, int ldw2, int K2,
               const float* __restrict__ b1p, const float* __restrict__ b2p,
               float* __restrict__ Cp, int ldc, int N)
{
    __shared__ float As[8][128];
    __shared__ float Ws[8][128];
    const int tid  = threadIdx.x;
    const int m0   = blockIdx.y * 128;
    const int n0   = blockIdx.x * 128;
    const int tm   = tid >> 4;
    const int tn   = tid & 15;
    const int lrow = tid >> 1;
    const int lkh  = (tid & 1) << 2;
    const int wrow = n0 + lrow;
    const int Ktot = K1 + K2;

    float acc[8][8];
    #pragma unroll
    for (int i = 0; i < 8; ++i)
        #pragma unroll
        for (int j = 0; j < 8; ++j) acc[i][j] = 0.0f;

    float4 av = *(const float4*)(A1 + (size_t)(m0 + lrow) * lda1 + lkh);
    float4 wv = make_float4(0.0f, 0.0f, 0.0f, 0.0f);
    if (wrow < N) wv = *(const float4*)(W1 + (size_t)wrow * ldw1 + lkh);

    for (int kt = 0; kt < Ktot; kt += 8) {
        __syncthreads();
        As[lkh + 0][lrow] = av.x; As[lkh + 1][lrow] = av.y;
        As[lkh + 2][lrow] = av.z; As[lkh + 3][lrow] = av.w;
        Ws[lkh + 0][lrow] = wv.x; Ws[lkh + 1][lrow] = wv.y;
        Ws[lkh + 2][lrow] = wv.z; Ws[lkh + 3][lrow] = wv.w;
        __syncthreads();

        int kn = kt + 8;
        float4 avn = make_float4(0.0f, 0.0f, 0.0f, 0.0f);
        float4 wvn = avn;
        if (kn < Ktot) {
            if (kn < K1) {
                avn = *(const float4*)(A1 + (size_t)(m0 + lrow) * lda1 + kn + lkh);
                if (wrow < N) wvn = *(const float4*)(W1 + (size_t)wrow * ldw1 + kn + lkh);
            } else {
                int k2 = kn - K1;
                avn = *(const float4*)(A2 + (size_t)(m0 + lrow) * lda2 + k2 + lkh);
                if (wrow < N) wvn = *(const float4*)(W2 + (size_t)wrow * ldw2 + k2 + lkh);
            }
        }

        #pragma unroll
        for (int kk = 0; kk < 8; ++kk) {
            float af[8], wf[8];
            #pragma unroll
            for (int i = 0; i < 4; ++i) {
                af[i]     = As[kk][tm * 8 + i];
                af[i + 4] = As[kk][tm * 8 + 4 + i];
                wf[i]     = Ws[kk][tn * 4 + i];
                wf[i + 4] = Ws[kk][64 + tn * 4 + i];
            }
            #pragma unroll
            for (int i = 0; i < 8; ++i)
                #pragma unroll
                for (int j = 0; j < 8; ++j)
                    acc[i][j] += af[i] * wf[j];
        }
        av = avn; wv = wvn;
    }

    #pragma unroll
    for (int j = 0; j < 8; ++j) {
        int col = n0 + ((j < 4) ? (tn * 4 + j) : (64 + tn * 4 + (j - 4)));
        if (col >= N) continue;
        float bias = b1p[col] + (b2p ? b2p[col] : 0.0f);
        #pragma unroll
        for (int i = 0; i < 8; ++i) {
            int rrow = m0 + tm * 8 + i;
            float v = acc[i][j] + bias;
            if (ACT == 1) v = fmaxf(v, 0.0f);
            else if (ACT == 2) v = tanhf(v);
            Cp[(size_t)rrow * ldc + col] = v;
        }
    }
}

// ---------------- LSTM gate nonlinearity ----------------
__global__ void lstm_gates(const float* __restrict__ G_, const float* __restrict__ c0l,
                           float* __restrict__ xout, int xld, float* __restrict__ ts)
{
    int i = blockIdx.x * 256 + threadIdx.x;     // < 2048*512
    int m = i >> 9, h = i & 511;
    const float* g = G_ + (size_t)m * 2048 + h;
    float gi = g[0], gf = g[512], gg = g[1024], go = g[1536];
    float c = sigmoidf_(gf) * c0l[i] + sigmoidf_(gi) * tanhf(gg);
    float x = sigmoidf_(go) * tanhf(c);
    xout[(size_t)m * xld + h] = x;
    if (ts) ts[i] = x;
}

// ---------------- dnn = sigmoid(raw*ss) * range ----------------
__global__ void dnn_kernel(const float* __restrict__ raw, const int* __restrict__ ssp,
                           const float* __restrict__ rng, float* __restrict__ dnn)
{
    int i = blockIdx.x * 256 + threadIdx.x;
    if (i >= 2048 * 23) return;
    int c = i % 23;
    int v = *ssp;
    float ss = (v > 100000 || v < 0) ? __int_as_float(v) : (float)v;
    dnn[i] = sigmoidf_(raw[i] * ss) * rng[c];
}

// ---------------- gam/pdt evaluation ----------------
__device__ __forceinline__ void gampdt_eval(float t, float alpha, float days, float rs20,
                                            float jump, float t_jump, float inv2s2,
                                            float pconst, float rdd20, float* ag, float* pd)
{
    float dtj = t - t_jump;
    float g = 0.6366197723675814f * atanf((days - t) * rs20) + 1.0f + jump * expf(-(dtj * dtj) * inv2s2);
    *ag = alpha * g;
    *pd = pconst * (atanf(-t * rdd20) + 1.5707963267948966f) + 0.001f;
}

// pack (ag_half, pd_half, ag_end, pd_end) per (substep k, chain e) as float4
__global__ void gampdt4_kernel(const float* __restrict__ dnn, float4* __restrict__ ag4)
{
    int idx = blockIdx.x * 256 + threadIdx.x;
    if (idx >= NSTEPS * 2048) return;
    int e = idx & 2047;
    int k = idx >> 11;
    int s = k / 10, j = k - s * 10;
    const float* p = dnn + e * 23 + 11;
    float alpha = p[0], days = p[1], r_s = p[2], p_dth = p[4], r_dthdecay = p[5];
    float jump = p[8], t_jump = p[9], stdn = p[10];
    float rs20   = r_s * 0.05f;
    float rdd20  = r_dthdecay * 0.05f;
    float inv2s2 = 1.0f / (2.0f * stdn * stdn);
    float pconst = 0.6366197723675814f * (p_dth - 0.001f);
    float t = (float)s + (float)j * 0.1f;
    float agh, pdh, ag1, pd1;
    gampdt_eval(t + 0.05f, alpha, days, rs20, jump, t_jump, inv2s2, pconst, rdd20, &agh, &pdh);
    gampdt_eval(t + 0.1f,  alpha, days, rs20, jump, t_jump, inv2s2, pconst, rdd20, &ag1, &pd1);
    ag4[idx] = make_float4(agh, pdh, ag1, pd1);
}

// ---------------- 8-lane-per-chain ODE ----------------
// Lanes g=0..7 of each chain: all replicate the nonlinear core (y0,y1,y2) with
// identical arithmetic (zero communication); lane g owns one linear decay state:
//   g: 0->y3  1->y4  2->y5  3->y6  4->y7  5->y8  6->y12  7->y13
// with d = c1*dq + c2*dp - r*y  (per-lane constants).  Pure-integral states
// (y9,y10,y11,y14,y15) are reconstructed at segment boundaries from the
// RK4-weighted stage sums W = y1s+2*y2s+2*y3s+y4s accumulated per segment
// (6 __shfl per boundary), det-sums are replicated so y11/y15 are local.
__global__ __launch_bounds__(64)
void ode8_kernel(const float* __restrict__ dnn, const float* __restrict__ pop,
                 const float* __restrict__ ccn, const float* __restrict__ mort,
                 const float4* __restrict__ ag4, float* __restrict__ sol)
{
    const int t  = blockIdx.x * 64 + threadIdx.x;   // 0..16383
    const int e  = t >> 3;
    const int g  = t & 7;
    const int lane = threadIdx.x & 63;
    const int base = lane & ~7;

    const float* p = dnn + e * 23 + 11;
    float alpha = p[0], days = p[1], r_s = p[2], r_dth = p[3], p_dth = p[4];
    float r_dthdecay = p[5], k1p = p[6], k2p = p[7], jump = p[8], t_jump = p[9], stdn = p[10];

    float N = pop[e];
    float invN = 1.0f / N;
    float PopI = ccn[e];
    float PopD = floorf(mort[e] * PopI);
    float R0v  = (PopI - PopD > 5.0f * PopD) ? 5.0f * PopD : 0.0f;
    float PopCI = PopI - PopD - R0v;
    float DP = PopCI / 0.2f;
    float ompd = 1.0f - p_dth;

    // core (replicated)
    float y0 = N - DP * (k1p + k2p) - R0v / 0.2f - PopD / 0.2f;
    float y1 = DP * k1p;
    float y2 = DP * k2p;
    // integrals (replicated)
    float y9  = R0v / 0.2f;
    float y10 = PopD / 0.2f;
    float y11 = PopCI * 0.15f;
    float y14 = PopD;
    float y15 = PopI;
    // decay-state inits
    float iy3  = (DP - PopCI) * ompd;
    float iy4  = PopCI * 0.15f * ompd;
    float iy5  = PopCI * 0.85f * ompd;
    float iy6  = (DP - PopCI) * p_dth;
    float iy7  = PopCI * 0.15f * p_dth;
    float iy8  = PopCI * 0.85f * p_dth;
    float iy12 = PopCI * 0.15f * 0.25f * ompd;
    float iy13 = PopCI * 0.15f * 0.25f * p_dth;

    // own decay state + per-lane constants
    float ha = (g == 0) ? iy3 : (g == 1) ? iy4 : (g == 2) ? iy5 : iy6;
    float hb = (g == 4) ? iy7 : (g == 5) ? iy8 : (g == 6) ? iy12 : iy13;
    float ys = (g < 4) ? ha : hb;
    float c1 = (g == 0) ? 0.8f : (g == 1) ? 0.03f : (g == 2) ? 0.17f : (g == 6) ? 0.0075f : 0.0f;
    float c2 = (g == 3) ? 0.8f : (g == 4) ? 0.03f : (g == 5) ? 0.17f : (g == 7) ? 0.0075f : 0.0f;
    float rr = (g == 0 || g == 2) ? kR_RI : (g == 1) ? kR_RH : (g == 6) ? kR_RV : r_dth;
    int own_idx = (g < 4) ? ((g < 2) ? (g == 0 ? 3 : 4) : (g == 2 ? 5 : 6))
                          : ((g < 6) ? (g == 4 ? 7 : 8) : (g == 6 ? 12 : 13));
    int ext_idx = (g < 4) ? ((g < 2) ? (g == 0 ? 0 : 1) : (g == 2 ? 2 : 9))
                          : ((g < 6) ? (g == 4 ? 10 : 11) : (g == 6 ? 14 : 15));

    float* sole = sol + (size_t)e * (TPTS * 16);
    {   // t=0 checkpoint
        float ev = (g < 4) ? ((g < 2) ? (g == 0 ? y0 : y1) : (g == 2 ? y2 : y9))
                           : ((g < 6) ? (g == 4 ? y10 : y11) : (g == 6 ? y14 : y15));
        sole[own_idx] = ys;
        sole[ext_idx] = ev;
    }

    // initial ag/pd (replicated)
    float rs20   = r_s * 0.05f;
    float rdd20  = r_dthdecay * 0.05f;
    float inv2s2 = 1.0f / (2.0f * stdn * stdn);
    float pconst = 0.6366197723675814f * (p_dth - 0.001f);
    float ag0, pd0;
    gampdt_eval(0.0f, alpha, days, rs20, jump, t_jump, inv2s2, pconst, rdd20, &ag0, &pd0);
    float omp0 = 1.0f - pd0;

    // 2-deep prefetch of packed (agh,pdh,ag1,pd1)
    float4 cv0 = ag4[e];
    float4 cv1 = ag4[2048 + e];

    const float h6 = 0.016666668f;
    float Sdet = 0.0f, Sy = 0.0f;       // per-segment weighted sums

    for (int s = 0; s < NSEG; ++s) {
        for (int j = 0; j < NSUB; ++j) {
            float agh = cv0.x, pdh = cv0.y, ag1 = cv0.z, pd1 = cv0.w;
            int k2 = s * 10 + j + 2;
            cv0 = cv1;
            if (k2 < NSTEPS) cv1 = ag4[(size_t)k2 * 2048 + e];
            float omph = 1.0f - pdh, omp1 = 1.0f - pd1;

            // ---- stage 1 (ag0, pd0) ----
            float det = kR_D * y2;
            float t1  = kR_I * y1;
            float inf = ag0 * y0 * y2 * invN;
            float d1c = inf - t1, d2c = t1 - det;
            float dq = det * omp0, dp = det * pd0;
            float k  = (c1 * dq + c2 * dp) - rr * ys;
            float a0 = -inf, a1 = d1c, a2 = d2c, ka = k;
            float Wd = det, Wy = ys;
            float z0 = y0 - 0.05f * inf, z1 = y1 + 0.05f * d1c, z2 = y2 + 0.05f * d2c;
            float zs = ys + 0.05f * k;

            // ---- stage 2 (agh, pdh) ----
            det = kR_D * z2; t1 = kR_I * z1; inf = agh * z0 * z2 * invN;
            d1c = inf - t1; d2c = t1 - det;
            dq = det * omph; dp = det * pdh;
            k  = (c1 * dq + c2 * dp) - rr * zs;
            a0 -= 2.0f * inf; a1 += 2.0f * d1c; a2 += 2.0f * d2c; ka += 2.0f * k;
            Wd += 2.0f * det; Wy += 2.0f * zs;
            z0 = y0 - 0.05f * inf; z1 = y1 + 0.05f * d1c; z2 = y2 + 0.05f * d2c;
            zs = ys + 0.05f * k;

            // ---- stage 3 (agh, pdh) ----
            det = kR_D * z2; t1 = kR_I * z1; inf = agh * z0 * z2 * invN;
            d1c = inf - t1; d2c = t1 - det;
            dq = det * omph; dp = det * pdh;
            k  = (c1 * dq + c2 * dp) - rr * zs;
            a0 -= 2.0f * inf; a1 += 2.0f * d1c; a2 += 2.0f * d2c; ka += 2.0f * k;
            Wd += 2.0f * det; Wy += 2.0f * zs;
            z0 = y0 - 0.1f * inf; z1 = y1 + 0.1f * d1c; z2 = y2 + 0.1f * d2c;
            zs = ys + 0.1f * k;

            // ---- stage 4 (ag1, pd1) ----
            det = kR_D * z2; t1 = kR_I * z1; inf = ag1 * z0 * z2 * invN;
            d1c = inf - t1; d2c = t1 - det;
            dq = det * omp1; dp = det * pd1;
            k  = (c1 * dq + c2 * dp) - rr * zs;
            a0 -= inf; a1 += d1c; a2 += d2c; ka += k;
            Wd += det; Wy += zs;

            // ---- combine ----
            y0 += h6 * a0; y1 += h6 * a1; y2 += h6 * a2; ys += h6 * ka;
            Sdet += Wd; Sy += Wy;
            ag0 = ag1; pd0 = pd1; omp0 = omp1;
        }

        // ---- segment boundary: integrals from segment sums, checkpoint ----
        float S0 = __shfl(Sy, base + 0, 64);
        float S1 = __shfl(Sy, base + 1, 64);
        float S2 = __shfl(Sy, base + 2, 64);
        float S3 = __shfl(Sy, base + 3, 64);
        float S4 = __shfl(Sy, base + 4, 64);
        float S5 = __shfl(Sy, base + 5, 64);
        y9  += h6 * (kR_RI * (S0 + S2) + kR_RH * S1);
        y10 += h6 * (r_dth * ((S3 + S4) + S5));
        y14 += h6 * (r_dth * (S4 + S5));
        y11 += h6 * (0.03f * Sdet);
        y15 += h6 * (0.2f * Sdet);
        Sdet = 0.0f; Sy = 0.0f;

        float* sp = sole + (size_t)(s + 1) * 16;
        float ev = (g < 4) ? ((g < 2) ? (g == 0 ? y0 : y1) : (g == 2 ? y2 : y9))
                           : ((g < 6) ? (g == 4 ? y10 : y11) : (g == 6 ? y14 : y15));
        sp[own_idx] = ys;
        sp[ext_idx] = ev;
    }
}

// ---------------- monolithic ODE fallback (no precompute) ----------------
__device__ __forceinline__ void deriv16(const float* y, float ag, float pd,
                                        float invN, float r_dth, float* d)
{
    float inf = ag * y[0] * y[2] * invN;
    float det = kR_D * y[2];
    float t1  = kR_I * y[1];
    float omp = 1.0f - pd;
    float dq  = det * omp;
    float dp  = det * pd;
    float dq003 = dq * 0.03f;
    float dp003 = dp * 0.03f;
    d[0]  = -inf;
    d[1]  = inf - t1;
    d[2]  = t1 - det;
    d[3]  = dq * 0.8f  - kR_RI * y[3];
    d[4]  = dq003      - kR_RH * y[4];
    d[5]  = dq * 0.17f - kR_RI * y[5];
    d[6]  = dp * 0.8f  - r_dth * y[6];
    d[7]  = dp003      - r_dth * y[7];
    d[8]  = dp * 0.17f - r_dth * y[8];
    d[9]  = kR_RI * (y[3] + y[5]) + kR_RH * y[4];
    d[10] = r_dth * ((y[6] + y[7]) + y[8]);
    d[11] = det * 0.03f;
    d[12] = 0.25f * dq003 - kR_RV * y[12];
    d[13] = 0.25f * dp003 - r_dth * y[13];
    d[14] = r_dth * (y[7] + y[8]);
    d[15] = det * 0.2f;
}

__global__ __launch_bounds__(64)
void ode_kernel(const float* __restrict__ dnn, const float* __restrict__ pop,
                const float* __restrict__ ccn, const float* __restrict__ mort,
                float* __restrict__ sol)
{
    int e = blockIdx.x * 64 + threadIdx.x;
    const float* p = dnn + e * 23 + 11;
    float alpha = p[0], days = p[1], r_s = p[2], r_dth = p[3], p_dth = p[4];
    float r_dthdecay = p[5], k1p = p[6], k2p = p[7], jump = p[8], t_jump = p[9], stdn = p[10];

    float N = pop[e];
    float invN = 1.0f / N;
    float PopI = ccn[e];
    float PopD = floorf(mort[e] * PopI);
    float R0v  = (PopI - PopD > 5.0f * PopD) ? 5.0f * PopD : 0.0f;
    float PopCI = PopI - PopD - R0v;
    float DP = PopCI / 0.2f;

    float y[16];
    y[0]  = N - DP * (k1p + k2p) - R0v / 0.2f - PopD / 0.2f;
    y[1]  = DP * k1p;
    y[2]  = DP * k2p;
    y[3]  = (DP - PopCI) * (1.0f - p_dth);
    y[4]  = PopCI * 0.15f * (1.0f - p_dth);
    y[5]  = PopCI * 0.85f * (1.0f - p_dth);
    y[6]  = (DP - PopCI) * p_dth;
    y[7]  = PopCI * 0.15f * p_dth;
    y[8]  = PopCI * 0.85f * p_dth;
    y[9]  = R0v / 0.2f;
    y[10] = PopD / 0.2f;
    y[11] = PopCI * 0.15f;
    y[12] = PopCI * 0.15f * 0.25f * (1.0f - p_dth);
    y[13] = PopCI * 0.15f * 0.25f * p_dth;
    y[14] = PopD;
    y[15] = PopI;

    {
        float* sp = sol + (size_t)e * (TPTS * 16);
        #pragma unroll
        for (int i = 0; i < 16; ++i) sp[i] = y[i];
    }

    float rs20   = r_s * 0.05f;
    float rdd20  = r_dthdecay * 0.05f;
    float inv2s2 = 1.0f / (2.0f * stdn * stdn);
    float pconst = 0.6366197723675814f * (p_dth - 0.001f);

    float ag0, pd0;
    gampdt_eval(0.0f, alpha, days, rs20, jump, t_jump, inv2s2, pconst, rdd20, &ag0, &pd0);

    for (int s = 0; s < NSEG; ++s) {
        float t0 = (float)s;
        for (int j = 0; j < NSUB; ++j) {
            float agh, pdh, ag1, pd1;
            float t = t0 + (float)j * 0.1f;
            gampdt_eval(t + 0.05f, alpha, days, rs20, jump, t_jump, inv2s2, pconst, rdd20, &agh, &pdh);
            gampdt_eval(t + 0.1f,  alpha, days, rs20, jump, t_jump, inv2s2, pconst, rdd20, &ag1, &pd1);
            float d[16], acc[16], yt[16];
            deriv16(y, ag0, pd0, invN, r_dth, d);
            #pragma unroll
            for (int i = 0; i < 16; ++i) { acc[i] = d[i]; yt[i] = y[i] + 0.05f * d[i]; }
            deriv16(yt, agh, pdh, invN, r_dth, d);
            #pragma unroll
            for (int i = 0; i < 16; ++i) { acc[i] += 2.0f * d[i]; yt[i] = y[i] + 0.05f * d[i]; }
            deriv16(yt, agh, pdh, invN, r_dth, d);
            #pragma unroll
            for (int i = 0; i < 16; ++i) { acc[i] += 2.0f * d[i]; yt[i] = y[i] + 0.1f * d[i]; }
            deriv16(yt, ag1, pd1, invN, r_dth, d);
            #pragma unroll
            for (int i = 0; i < 16; ++i) y[i] += 0.016666668f * (acc[i] + d[i]);
            ag0 = ag1; pd0 = pd1;
        }
        float* sp = sol + (size_t)e * (TPTS * 16) + (size_t)(s + 1) * 16;
        #pragma unroll
        for (int i = 0; i < 16; ++i) sp[i] = y[i];
    }
}

// ---------------- host launch ----------------
extern "C" void kernel_launch(void* const* d_in, const int* in_sizes, int n_in,
                              void* d_out, int out_size, void* d_ws, size_t ws_size,
                              hipStream_t stream)
{
    const float* mi   = (const float*)d_in[0];
    const float* pop  = (const float*)d_in[1];
    const float* ccn  = (const float*)d_in[2];
    const float* mort = (const float*)d_in[3];
    const float* h0   = (const float*)d_in[4];
    const float* c0   = (const float*)d_in[5];
    const float* Wih0 = (const float*)d_in[6];
    const float* WihR = (const float*)d_in[7];
    const float* Whh  = (const float*)d_in[8];
    const float* bih  = (const float*)d_in[9];
    const float* bhh  = (const float*)d_in[10];
    const float* mW1  = (const float*)d_in[11];
    const float* mb1  = (const float*)d_in[12];
    const float* mW2  = (const float*)d_in[13];
    const float* mb2  = (const float*)d_in[14];
    const float* rW1  = (const float*)d_in[15];
    const float* rb1  = (const float*)d_in[16];
    const float* rW2  = (const float*)d_in[17];
    const float* rb2  = (const float*)d_in[18];
    const float* rng  = (const float*)d_in[19];
    const int*   ssp  = (const int*)d_in[20];

    float* out   = (float*)d_out;
    float* sol_o = out;                                   // 2048*90*16
    float* dnn_o = out + 2949120;                         // 2048*23
    float* ts_o  = out + 2949120 + 47104;                 // 2048*512
    float* raw_o = out + 2949120 + 47104 + 1048576;       // 2048*23

    float* ws  = (float*)d_ws;
    float* G   = ws;                    // 4,194,304 floats
    float* Z   = ws + 4194304;          // 2,097,152
    float* X0  = ws + 6291456;          // 1,048,576
    float* X1  = ws + 7340032;          // 1,048,576
    float* x0p = ws + 8388608;          // 65,536
    float* xmp = ws + 8454144;          // 65,536
    float* Wp0 = ws + 8519680;          // 65,536
    float* Wpm = ws + 8585216;          // 16,384   (end 8,601,600)
    __hip_bfloat16* Ab = (__hip_bfloat16*)(ws + 8601600);
    __hip_bfloat16* Wb = (__hip_bfloat16*)(ws + 8601600 + 3145728);
    float4* AG4 = (float4*)(ws + 8601600);
    bool wsOK = ws_size >= (size_t)15892480 * sizeof(float);

    prep_pad<<<256, 256, 0, stream>>>(mi, pop, Wih0, mW1, x0p, xmp, Wp0, Wpm);

    gemm_dual<1><<<dim3(4, 16), 256, 0, stream>>>(xmp, 32, Wpm, 32, 32,
                                                  nullptr, 0, nullptr, 0, 0,
                                                  mb1, nullptr, G, 512, 512);

    if (wsOK) {
        pack_split<false><<<(2048 * 512 + 255) / 256, 256, 0, stream>>>(G, 512, 512, nullptr, 0, 0, Ab, 2048);
        pack_split<true ><<<(512  * 512 + 255) / 256, 256, 0, stream>>>(mW2, 512, 512, nullptr, 0, 0, Wb, 512);
        gemm_mfma<1><<<dim3(4, 16), 256, 0, stream>>>(Ab, Wb, 1536, mb2, nullptr, Z + 512, 1024, 512);

        for (int l = 0; l < 5; ++l) {
            const float* A1 = (l == 0) ? x0p : ((l & 1) ? X1 : X0);
            int          K1 = (l == 0) ? 32 : 512;
            const float* W1 = (l == 0) ? Wp0 : (WihR + (size_t)(l - 1) * 1048576);
            int K3 = 3 * (K1 + 512);
            pack_split<false><<<(2048 * (K1 + 512) + 255) / 256, 256, 0, stream>>>(
                A1, K1, K1, h0 + (size_t)l * 1048576, 512, 512, Ab, 2048);
            pack_split<true ><<<(2048 * (K1 + 512) + 255) / 256, 256, 0, stream>>>(
                W1, K1, K1, Whh + (size_t)l * 1048576, 512, 512, Wb, 2048);
            gemm_mfma<0><<<dim3(16, 16), 256, 0, stream>>>(
                Ab, Wb, K3, bih + l * 2048, bhh + l * 2048, G, 2048, 2048);
            float* xo  = (l == 4) ? Z : ((l & 1) ? X0 : X1);
            int    xol = (l == 4) ? 1024 : 512;
            lstm_gates<<<4096, 256, 0, stream>>>(G, c0 + (size_t)l * 1048576, xo, xol,
                                                 (l == 4) ? ts_o : nullptr);
        }

        pack_split<false><<<(2048 * 1024 + 255) / 256, 256, 0, stream>>>(Z, 1024, 1024, nullptr, 0, 0, Ab, 2048);
        pack_split<true ><<<(1024 * 1024 + 255) / 256, 256, 0, stream>>>(rW1, 1024, 1024, nullptr, 0, 0, Wb, 1024);
        gemm_mfma<2><<<dim3(8, 16), 256, 0, stream>>>(Ab, Wb, 3072, rb1, nullptr, G, 1024, 1024);
    } else {
        gemm_dual<1><<<dim3(4, 16), 256, 0, stream>>>(G, 512, mW2, 512, 512,
                                                      nullptr, 0, nullptr, 0, 0,
                                                      mb2, nullptr, Z + 512, 1024, 512);
        for (int l = 0; l < 5; ++l) {
            const float* A1 = (l == 0) ? x0p : ((l & 1) ? X1 : X0);
            int          K1 = (l == 0) ? 32 : 512;
            const float* W1 = (l == 0) ? Wp0 : (WihR + (size_t)(l - 1) * 1048576);
            gemm_dual<0><<<dim3(16, 16), 256, 0, stream>>>(
                A1, K1, W1, K1, K1,
                h0 + (size_t)l * 1048576, 512, Whh + (size_t)l * 1048576, 512, 512,
                bih + l * 2048, bhh + l * 2048, G, 2048, 2048);
            float* xo  = (l == 4) ? Z : ((l & 1) ? X0 : X1);
            int    xol = (l == 4) ? 1024 : 512;
            lstm_gates<<<4096, 256, 0, stream>>>(G, c0 + (size_t)l * 1048576, xo, xol,
                                                 (l == 4) ? ts_o : nullptr);
        }
        gemm_dual<2><<<dim3(8, 16), 256, 0, stream>>>(Z, 1024, rW1, 1024, 1024,
                                                      nullptr, 0, nullptr, 0, 0,
                                                      rb1, nullptr, G, 1024, 1024);
    }

    gemm_dual<0><<<dim3(1, 16), 256, 0, stream>>>(G, 1024, rW2, 1024, 1024,
                                                  nullptr, 0, nullptr, 0, 0,
                                                  rb2, nullptr, raw_o, 23, 23);
    dnn_kernel<<<184, 256, 0, stream>>>(raw_o, ssp, rng, dnn_o);

    if (wsOK) {
        gampdt4_kernel<<<(NSTEPS * 2048 + 255) / 256, 256, 0, stream>>>(dnn_o, AG4);
        ode8_kernel<<<256, 64, 0, stream>>>(dnn_o, pop, ccn, mort, AG4, sol_o);
    } else {
        ode_kernel<<<32, 64, 0, stream>>>(dnn_o, pop, ccn, mort, sol_o);
    }
    (void)in_sizes; (void)n_in; (void)out_size;
}

// Round 5
// 1081.324 us; speedup vs baseline: 1.9863x; 1.0073x over previous
//
#include <hip/hip_runtime.h>
#include <hip/hip_bf16.h>
#include <math.h>

// ---------------- problem constants ----------------
#define BATCH 2048
#define HID 512
#define TPTS 90
#define NSEG 89
#define NSUB 10
#define NSTEPS 890          // NSEG*NSUB global substeps

__device__ __constant__ const float kR_I  = 0.6931471805599453f / 5.0f;
__device__ __constant__ const float kR_D  = 0.6931471805599453f / 2.0f;
__device__ __constant__ const float kR_RI = 0.6931471805599453f / 10.0f;
__device__ __constant__ const float kR_RH = 0.6931471805599453f / 15.0f;
__device__ __constant__ const float kR_RV = 0.6931471805599453f / 10.0f;

typedef __attribute__((ext_vector_type(8))) short short8;
typedef __attribute__((ext_vector_type(4))) float float4v;

__device__ __forceinline__ float sigmoidf_(float x) { return 1.0f / (1.0f + expf(-x)); }

// ---------------- prep: pad K=30 operands to K=32, x = mi[:, :30]/pop ----------------
__global__ void prep_pad(const float* __restrict__ mi, const float* __restrict__ pop,
                         const float* __restrict__ Wih0, const float* __restrict__ mW1,
                         float* __restrict__ x0p, float* __restrict__ xmp,
                         float* __restrict__ Wp0, float* __restrict__ Wpm)
{
    int i = blockIdx.x * 256 + threadIdx.x;     // < 2048*32
    int r = i >> 5, c = i & 31;
    bool v = (c < 30);
    x0p[i] = v ? mi[r * 60 + c] / pop[r] : 0.0f;
    xmp[i] = v ? mi[r * 60 + 30 + c] : 0.0f;
    Wp0[i] = v ? Wih0[r * 30 + c] : 0.0f;
    if (r < 512) Wpm[i] = v ? mW1[r * 30 + c] : 0.0f;
}

// ---------------- hi/lo bf16 split + K-concat packing ----------------
// A-mode (WMODE=false): segments [hi | hi | lo]
// W-mode (WMODE=true):  segments [hi | lo | hi]
template<bool WMODE>
__global__ void pack_split(const float* __restrict__ s1, int ld1, int K1,
                           const float* __restrict__ s2, int ld2, int K2,
                           __hip_bfloat16* __restrict__ dst, int rows)
{
    int idx = blockIdx.x * 256 + threadIdx.x;
    int Ks = K1 + K2;
    if (idx >= rows * Ks) return;
    int r = idx / Ks, k = idx - r * Ks;
    float x; int base, seg, kk;
    if (k < K1) { x = s1[(size_t)r * ld1 + k]; base = 0; seg = K1; kk = k; }
    else        { kk = k - K1; x = s2[(size_t)r * ld2 + kk]; base = 3 * K1; seg = K2; }
    __hip_bfloat16 hi = __float2bfloat16(x);
    __hip_bfloat16 lo = __float2bfloat16(x - __bfloat162float(hi));
    __hip_bfloat16* d = dst + (size_t)r * (3 * Ks) + base;
    d[kk]           = hi;
    d[seg + kk]     = WMODE ? lo : hi;
    d[2 * seg + kk] = WMODE ? hi : lo;
}

// ---------------- bf16 MFMA GEMM-NT ----------------
template<int ACT>
__global__ __launch_bounds__(256)
void gemm_mfma(const __hip_bfloat16* __restrict__ Ah,
               const __hip_bfloat16* __restrict__ Wh, int K3,
               const float* __restrict__ b1, const float* __restrict__ b2,
               float* __restrict__ Cp, int ldc, int N)
{
    __shared__ __hip_bfloat16 As[128 * 32];
    __shared__ __hip_bfloat16 Ws[128 * 32];
    const int tid  = threadIdx.x;
    const int m0   = blockIdx.y * 128;
    const int n0   = blockIdx.x * 128;
    const int lane = tid & 63, wv = tid >> 6;
    const int mw   = (wv >> 1) * 64, nw = (wv & 1) * 64;
    const int l15  = lane & 15, quad = lane >> 4;
    const int sr   = tid >> 2;
    const int sc   = (tid & 3) * 8;

    float4v acc[4][4];
    #pragma unroll
    for (int i = 0; i < 4; ++i)
        #pragma unroll
        for (int j = 0; j < 4; ++j)
            acc[i][j] = (float4v){0.0f, 0.0f, 0.0f, 0.0f};

    for (int kt = 0; kt < K3; kt += 32) {
        short8 a0 = *(const short8*)(Ah + (size_t)(m0 + sr)      * K3 + kt + sc);
        short8 a1 = *(const short8*)(Ah + (size_t)(m0 + sr + 64) * K3 + kt + sc);
        short8 w0 = *(const short8*)(Wh + (size_t)(n0 + sr)      * K3 + kt + sc);
        short8 w1 = *(const short8*)(Wh + (size_t)(n0 + sr + 64) * K3 + kt + sc);
        __syncthreads();
        *(short8*)(As + sr * 32 + sc)        = a0;
        *(short8*)(As + (sr + 64) * 32 + sc) = a1;
        *(short8*)(Ws + sr * 32 + sc)        = w0;
        *(short8*)(Ws + (sr + 64) * 32 + sc) = w1;
        __syncthreads();
        short8 af[4], bf[4];
        #pragma unroll
        for (int t = 0; t < 4; ++t) {
            af[t] = *(const short8*)(As + (mw + t * 16 + l15) * 32 + quad * 8);
            bf[t] = *(const short8*)(Ws + (nw + t * 16 + l15) * 32 + quad * 8);
        }
        #pragma unroll
        for (int i = 0; i < 4; ++i)
            #pragma unroll
            for (int j = 0; j < 4; ++j)
                acc[i][j] = __builtin_amdgcn_mfma_f32_16x16x32_bf16(af[i], bf[j], acc[i][j], 0, 0, 0);
    }

    #pragma unroll
    for (int j = 0; j < 4; ++j) {
        int col = n0 + nw + j * 16 + l15;
        float bias = b1[col] + (b2 ? b2[col] : 0.0f);
        #pragma unroll
        for (int i = 0; i < 4; ++i) {
            #pragma unroll
            for (int r = 0; r < 4; ++r) {
                int row = m0 + mw + i * 16 + quad * 4 + r;
                float v = acc[i][j][r] + bias;
                if (ACT == 1)      v = fmaxf(v, 0.0f);
                else if (ACT == 2) v = tanhf(v);
                Cp[(size_t)row * ldc + col] = v;
            }
        }
    }
}

// ---------------- fp32 tiled GEMM-NT (small GEMMs + fallback) ----------------
template<int ACT>
__global__ __launch_bounds__(256)
void gemm_dual(const float* __restrict__ A1, int lda1,
               const float* __restrict__ W1, int ldw1, int K1,
               const float* __restrict__ A2, int lda2,
               const float* __restrict__ W2, int ldw2, int K2,
               const float* __restrict__ b1p, const float* __restrict__ b2p,
               float* __restrict__ Cp, int ldc, int N)
{
    __shared__ float As[8][128];
    __shared__ float Ws[8][128];
    const int tid  = threadIdx.x;
    const int m0   = blockIdx.y * 128;
    const int n0   = blockIdx.x * 128;
    const int tm   = tid >> 4;
    const int tn   = tid & 15;
    const int lrow = tid >> 1;
    const int lkh  = (tid & 1) << 2;
    const int wrow = n0 + lrow;
    const int Ktot = K1 + K2;

    float acc[8][8];
    #pragma unroll
    for (int i = 0; i < 8; ++i)
        #pragma unroll
        for (int j = 0; j < 8; ++j) acc[i][j] = 0.0f;

    float4 av = *(const float4*)(A1 + (size_t)(m0 + lrow) * lda1 + lkh);
    float4 wv = make_float4(0.0f, 0.0f, 0.0f, 0.0f);
    if (wrow < N) wv = *(const float4*)(W1 + (size_t)wrow * ldw1 + lkh);

    for (int kt = 0; kt < Ktot; kt += 8) {
        __syncthreads();
        As[lkh + 0][lrow] = av.x; As[lkh + 1][lrow] = av.y;
        As[lkh + 2][lrow] = av.z; As[lkh + 3][lrow] = av.w;
        Ws[lkh + 0][lrow] = wv.x; Ws[lkh + 1][lrow] = wv.y;
        Ws[lkh + 2][lrow] = wv.z; Ws[lkh + 3][lrow] = wv.w;
        __syncthreads();

        int kn = kt + 8;
        float4 avn = make_float4(0.0f, 0.0f, 0.0f, 0.0f);
        float4 wvn = avn;
        if (kn < Ktot) {
            if (kn < K1) {
                avn = *(const float4*)(A1 + (size_t)(m0 + lrow) * lda1 + kn + lkh);
                if (wrow < N) wvn = *(const float4*)(W1 + (size_t)wrow * ldw1 + kn + lkh);
            } else {
                int k2 = kn - K1;
                avn = *(const float4*)(A2 + (size_t)(m0 + lrow) * lda2 + k2 + lkh);
                if (wrow < N) wvn = *(const float4*)(W2 + (size_t)wrow * ldw2 + k2 + lkh);
            }
        }

        #pragma unroll
        for (int kk = 0; kk < 8; ++kk) {
            float af[8], wf[8];
            #pragma unroll
            for (int i = 0; i < 4; ++i) {
                af[i]     = As[kk][tm * 8 + i];
                af[i + 4] = As[kk][tm * 8 + 4 + i];
                wf[i]     = Ws[kk][tn * 4 + i];
                wf[i + 4] = Ws[kk][64 + tn * 4 + i];
            }
            #pragma unroll
            for (int i = 0; i < 8; ++i)
                #pragma unroll
                for (int j = 0; j < 8; ++j)
                    acc[i][j] += af[i] * wf[j];
        }
        av = avn; wv = wvn;
    }

    #pragma unroll
    for (int j = 0; j < 8; ++j) {
        int col = n0 + ((j < 4) ? (tn * 4 + j) : (64 + tn * 4 + (j - 4)));
        if (col >= N) continue;
        float bias = b1p[col] + (b2p ? b2p[col] : 0.0f);
        #pragma unroll
        for (int i = 0; i < 8; ++i) {
            int rrow = m0 + tm * 8 + i;
            float v = acc[i][j] + bias;
            if (ACT == 1) v = fmaxf(v, 0.0f);
            else if (ACT == 2) v = tanhf(v);
            Cp[(size_t)rrow * ldc + col] = v;
        }
    }
}

// ---------------- LSTM gate nonlinearity ----------------
__global__ void lstm_gates(const float* __restrict__ G_, const float* __restrict__ c0l,
                           float* __restrict__ xout, int xld, float* __restrict__ ts)
{
    int i = blockIdx.x * 256 + threadIdx.x;     // < 2048*512
    int m = i >> 9, h = i & 511;
    const float* g = G_ + (size_t)m * 2048 + h;
    float gi = g[0], gf = g[512], gg = g[1024], go = g[1536];
    float c = sigmoidf_(gf) * c0l[i] + sigmoidf_(gi) * tanhf(gg);
    float x = sigmoidf_(go) * tanhf(c);
    xout[(size_t)m * xld + h] = x;
    if (ts) ts[i] = x;
}

// ---------------- dnn = sigmoid(raw*ss) * range ----------------
__global__ void dnn_kernel(const float* __restrict__ raw, const int* __restrict__ ssp,
                           const float* __restrict__ rng, float* __restrict__ dnn)
{
    int i = blockIdx.x * 256 + threadIdx.x;
    if (i >= 2048 * 23) return;
    int c = i % 23;
    int v = *ssp;
    float ss = (v > 100000 || v < 0) ? __int_as_float(v) : (float)v;
    dnn[i] = sigmoidf_(raw[i] * ss) * rng[c];
}

// ---------------- gam/pdt evaluation ----------------
__device__ __forceinline__ void gampdt_eval(float t, float alpha, float days, float rs20,
                                            float jump, float t_jump, float inv2s2,
                                            float pconst, float rdd20, float* ag, float* pd)
{
    float dtj = t - t_jump;
    float g = 0.6366197723675814f * atanf((days - t) * rs20) + 1.0f + jump * expf(-(dtj * dtj) * inv2s2);
    *ag = alpha * g;
    *pd = pconst * (atanf(-t * rdd20) + 1.5707963267948966f) + 0.001f;
}

// pack (ag_half, pd_half, ag_end, pd_end) per (substep k, chain e) as float4
__global__ void gampdt4_kernel(const float* __restrict__ dnn, float4* __restrict__ ag4)
{
    int idx = blockIdx.x * 256 + threadIdx.x;
    if (idx >= NSTEPS * 2048) return;
    int e = idx & 2047;
    int k = idx >> 11;
    int s = k / 10, j = k - s * 10;
    const float* p = dnn + e * 23 + 11;
    float alpha = p[0], days = p[1], r_s = p[2], p_dth = p[4], r_dthdecay = p[5];
    float jump = p[8], t_jump = p[9], stdn = p[10];
    float rs20   = r_s * 0.05f;
    float rdd20  = r_dthdecay * 0.05f;
    float inv2s2 = 1.0f / (2.0f * stdn * stdn);
    float pconst = 0.6366197723675814f * (p_dth - 0.001f);
    float t = (float)s + (float)j * 0.1f;
    float agh, pdh, ag1, pd1;
    gampdt_eval(t + 0.05f, alpha, days, rs20, jump, t_jump, inv2s2, pconst, rdd20, &agh, &pdh);
    gampdt_eval(t + 0.1f,  alpha, days, rs20, jump, t_jump, inv2s2, pconst, rdd20, &ag1, &pd1);
    ag4[idx] = make_float4(agh, pdh, ag1, pd1);
}

// ---------------- 8-lane-per-chain ODE with 8-substep-deep cooperative prefetch ----
// Lanes g=0..7 of each chain replicate the nonlinear core (y0,y1,y2); lane g owns
// one linear decay state (y3,y4,y5,y6,y7,y8,y12,y13) with per-lane constants.
// Pure integrals (y9,y10,y11,y14,y15) reconstructed at segment boundaries from
// RK4-weighted stage sums (6 __shfl per boundary).
// ag4 delivery: lane g loads the float4 for substep blk*8+g (1 load / 8 substeps),
// broadcast per substep via 4 __shfl; double-buffered blocks give ~8-substep
// (~1100 cyc) lookahead, hiding L3/HBM latency.
__global__ __launch_bounds__(64)
void ode8_kernel(const float* __restrict__ dnn, const float* __restrict__ pop,
                 const float* __restrict__ ccn, const float* __restrict__ mort,
                 const float4* __restrict__ ag4, float* __restrict__ sol)
{
    const int t  = blockIdx.x * 64 + threadIdx.x;   // 0..16383
    const int e  = t >> 3;
    const int g  = t & 7;
    const int lane = threadIdx.x & 63;
    const int base = lane & ~7;

    const float* p = dnn + e * 23 + 11;
    float alpha = p[0], days = p[1], r_s = p[2], r_dth = p[3], p_dth = p[4];
    float r_dthdecay = p[5], k1p = p[6], k2p = p[7], jump = p[8], t_jump = p[9], stdn = p[10];

    float N = pop[e];
    float invN = 1.0f / N;
    float PopI = ccn[e];
    float PopD = floorf(mort[e] * PopI);
    float R0v  = (PopI - PopD > 5.0f * PopD) ? 5.0f * PopD : 0.0f;
    float PopCI = PopI - PopD - R0v;
    float DP = PopCI / 0.2f;
    float ompd = 1.0f - p_dth;

    // core (replicated)
    float y0 = N - DP * (k1p + k2p) - R0v / 0.2f - PopD / 0.2f;
    float y1 = DP * k1p;
    float y2 = DP * k2p;
    // integrals (replicated)
    float y9  = R0v / 0.2f;
    float y10 = PopD / 0.2f;
    float y11 = PopCI * 0.15f;
    float y14 = PopD;
    float y15 = PopI;
    // decay-state inits
    float iy3  = (DP - PopCI) * ompd;
    float iy4  = PopCI * 0.15f * ompd;
    float iy5  = PopCI * 0.85f * ompd;
    float iy6  = (DP - PopCI) * p_dth;
    float iy7  = PopCI * 0.15f * p_dth;
    float iy8  = PopCI * 0.85f * p_dth;
    float iy12 = PopCI * 0.15f * 0.25f * ompd;
    float iy13 = PopCI * 0.15f * 0.25f * p_dth;

    // own decay state + per-lane constants
    float ha = (g == 0) ? iy3 : (g == 1) ? iy4 : (g == 2) ? iy5 : iy6;
    float hb = (g == 4) ? iy7 : (g == 5) ? iy8 : (g == 6) ? iy12 : iy13;
    float ys = (g < 4) ? ha : hb;
    float c1 = (g == 0) ? 0.8f : (g == 1) ? 0.03f : (g == 2) ? 0.17f : (g == 6) ? 0.0075f : 0.0f;
    float c2 = (g == 3) ? 0.8f : (g == 4) ? 0.03f : (g == 5) ? 0.17f : (g == 7) ? 0.0075f : 0.0f;
    float rr = (g == 0 || g == 2) ? kR_RI : (g == 1) ? kR_RH : (g == 6) ? kR_RV : r_dth;
    int own_idx = (g < 4) ? ((g < 2) ? (g == 0 ? 3 : 4) : (g == 2 ? 5 : 6))
                          : ((g < 6) ? (g == 4 ? 7 : 8) : (g == 6 ? 12 : 13));
    int ext_idx = (g < 4) ? ((g < 2) ? (g == 0 ? 0 : 1) : (g == 2 ? 2 : 9))
                          : ((g < 6) ? (g == 4 ? 10 : 11) : (g == 6 ? 14 : 15));

    float* sole = sol + (size_t)e * (TPTS * 16);
    {   // t=0 checkpoint
        float ev = (g < 4) ? ((g < 2) ? (g == 0 ? y0 : y1) : (g == 2 ? y2 : y9))
                           : ((g < 6) ? (g == 4 ? y10 : y11) : (g == 6 ? y14 : y15));
        sole[own_idx] = ys;
        sole[ext_idx] = ev;
    }

    // initial ag/pd (replicated)
    float rs20   = r_s * 0.05f;
    float rdd20  = r_dthdecay * 0.05f;
    float inv2s2 = 1.0f / (2.0f * stdn * stdn);
    float pconst = 0.6366197723675814f * (p_dth - 0.001f);
    float ag0, pd0;
    gampdt_eval(0.0f, alpha, days, rs20, jump, t_jump, inv2s2, pconst, rdd20, &ag0, &pd0);
    float omp0 = 1.0f - pd0;

    // cooperative block prefetch: lane g holds substep blk*8+g
    float4 cvA = ag4[(size_t)g * 2048 + e];          // k = 0..7
    float4 cvB = ag4[(size_t)(8 + g) * 2048 + e];    // k = 8..15
    int kf = 16;                                     // next block base
    int kk = 0;

    const float h6 = 0.016666668f;
    float Sdet = 0.0f, Sy = 0.0f;       // per-segment weighted sums

    for (int s = 0; s < NSEG; ++s) {
        for (int j = 0; j < NSUB; ++j) {
            int jj = kk & 7;
            int src = base + jj;
            float agh = __shfl(cvA.x, src, 64);
            float pdh = __shfl(cvA.y, src, 64);
            float ag1 = __shfl(cvA.z, src, 64);
            float pd1 = __shfl(cvA.w, src, 64);
            if (jj == 7) {
                cvA = cvB;
                int kidx = kf + g;
                if (kidx >= NSTEPS) kidx = NSTEPS - 1;
                cvB = ag4[(size_t)kidx * 2048 + e];
                kf += 8;
            }
            kk++;
            float omph = 1.0f - pdh, omp1 = 1.0f - pd1;

            // ---- stage 1 (ag0, pd0) ----
            float det = kR_D * y2;
            float t1  = kR_I * y1;
            float inf = ag0 * y0 * y2 * invN;
            float d1c = inf - t1, d2c = t1 - det;
            float dq = det * omp0, dp = det * pd0;
            float k  = (c1 * dq + c2 * dp) - rr * ys;
            float a0 = -inf, a1 = d1c, a2 = d2c, ka = k;
            float Wd = det, Wy = ys;
            float z0 = y0 - 0.05f * inf, z1 = y1 + 0.05f * d1c, z2 = y2 + 0.05f * d2c;
            float zs = ys + 0.05f * k;

            // ---- stage 2 (agh, pdh) ----
            det = kR_D * z2; t1 = kR_I * z1; inf = agh * z0 * z2 * invN;
            d1c = inf - t1; d2c = t1 - det;
            dq = det * omph; dp = det * pdh;
            k  = (c1 * dq + c2 * dp) - rr * zs;
            a0 -= 2.0f * inf; a1 += 2.0f * d1c; a2 += 2.0f * d2c; ka += 2.0f * k;
            Wd += 2.0f * det; Wy += 2.0f * zs;
            z0 = y0 - 0.05f * inf; z1 = y1 + 0.05f * d1c; z2 = y2 + 0.05f * d2c;
            zs = ys + 0.05f * k;

            // ---- stage 3 (agh, pdh) ----
            det = kR_D * z2; t1 = kR_I * z1; inf = agh * z0 * z2 * invN;
            d1c = inf - t1; d2c = t1 - det;
            dq = det * omph; dp = det * pdh;
            k  = (c1 * dq + c2 * dp) - rr * zs;
            a0 -= 2.0f * inf; a1 += 2.0f * d1c; a2 += 2.0f * d2c; ka += 2.0f * k;
            Wd += 2.0f * det; Wy += 2.0f * zs;
            z0 = y0 - 0.1f * inf; z1 = y1 + 0.1f * d1c; z2 = y2 + 0.1f * d2c;
            zs = ys + 0.1f * k;

            // ---- stage 4 (ag1, pd1) ----
            det = kR_D * z2; t1 = kR_I * z1; inf = ag1 * z0 * z2 * invN;
            d1c = inf - t1; d2c = t1 - det;
            dq = det * omp1; dp = det * pd1;
            k  = (c1 * dq + c2 * dp) - rr * zs;
            a0 -= inf; a1 += d1c; a2 += d2c; ka += k;
            Wd += det; Wy += zs;

            // ---- combine ----
            y0 += h6 * a0; y1 += h6 * a1; y2 += h6 * a2; ys += h6 * ka;
            Sdet += Wd; Sy += Wy;
            ag0 = ag1; pd0 = pd1; omp0 = omp1;
        }

        // ---- segment boundary: integrals from segment sums, checkpoint ----
        float S0 = __shfl(Sy, base + 0, 64);
        float S1 = __shfl(Sy, base + 1, 64);
        float S2 = __shfl(Sy, base + 2, 64);
        float S3 = __shfl(Sy, base + 3, 64);
        float S4 = __shfl(Sy, base + 4, 64);
        float S5 = __shfl(Sy, base + 5, 64);
        y9  += h6 * (kR_RI * (S0 + S2) + kR_RH * S1);
        y10 += h6 * (r_dth * ((S3 + S4) + S5));
        y14 += h6 * (r_dth * (S4 + S5));
        y11 += h6 * (0.03f * Sdet);
        y15 += h6 * (0.2f * Sdet);
        Sdet = 0.0f; Sy = 0.0f;

        float* sp = sole + (size_t)(s + 1) * 16;
        float ev = (g < 4) ? ((g < 2) ? (g == 0 ? y0 : y1) : (g == 2 ? y2 : y9))
                           : ((g < 6) ? (g == 4 ? y10 : y11) : (g == 6 ? y14 : y15));
        sp[own_idx] = ys;
        sp[ext_idx] = ev;
    }
}

// ---------------- monolithic ODE fallback (no precompute) ----------------
__device__ __forceinline__ void deriv16(const float* y, float ag, float pd,
                                        float invN, float r_dth, float* d)
{
    float inf = ag * y[0] * y[2] * invN;
    float det = kR_D * y[2];
    float t1  = kR_I * y[1];
    float omp = 1.0f - pd;
    float dq  = det * omp;
    float dp  = det * pd;
    float dq003 = dq * 0.03f;
    float dp003 = dp * 0.03f;
    d[0]  = -inf;
    d[1]  = inf - t1;
    d[2]  = t1 - det;
    d[3]  = dq * 0.8f  - kR_RI * y[3];
    d[4]  = dq003      - kR_RH * y[4];
    d[5]  = dq * 0.17f - kR_RI * y[5];
    d[6]  = dp * 0.8f  - r_dth * y[6];
    d[7]  = dp003      - r_dth * y[7];
    d[8]  = dp * 0.17f - r_dth * y[8];
    d[9]  = kR_RI * (y[3] + y[5]) + kR_RH * y[4];
    d[10] = r_dth * ((y[6] + y[7]) + y[8]);
    d[11] = det * 0.03f;
    d[12] = 0.25f * dq003 - kR_RV * y[12];
    d[13] = 0.25f * dp003 - r_dth * y[13];
    d[14] = r_dth * (y[7] + y[8]);
    d[15] = det * 0.2f;
}

__global__ __launch_bounds__(64)
void ode_kernel(const float* __restrict__ dnn, const float* __restrict__ pop,
                const float* __restrict__ ccn, const float* __restrict__ mort,
                float* __restrict__ sol)
{
    int e = blockIdx.x * 64 + threadIdx.x;
    const float* p = dnn + e * 23 + 11;
    float alpha = p[0], days = p[1], r_s = p[2], r_dth = p[3], p_dth = p[4];
    float r_dthdecay = p[5], k1p = p[6], k2p = p[7], jump = p[8], t_jump = p[9], stdn = p[10];

    float N = pop[e];
    float invN = 1.0f / N;
    float PopI = ccn[e];
    float PopD = floorf(mort[e] * PopI);
    float R0v  = (PopI - PopD > 5.0f * PopD) ? 5.0f * PopD : 0.0f;
    float PopCI = PopI - PopD - R0v;
    float DP = PopCI / 0.2f;

    float y[16];
    y[0]  = N - DP * (k1p + k2p) - R0v / 0.2f - PopD / 0.2f;
    y[1]  = DP * k1p;
    y[2]  = DP * k2p;
    y[3]  = (DP - PopCI) * (1.0f - p_dth);
    y[4]  = PopCI * 0.15f * (1.0f - p_dth);
    y[5]  = PopCI * 0.85f * (1.0f - p_dth);
    y[6]  = (DP - PopCI) * p_dth;
    y[7]  = PopCI * 0.15f * p_dth;
    y[8]  = PopCI * 0.85f * p_dth;
    y[9]  = R0v / 0.2f;
    y[10] = PopD / 0.2f;
    y[11] = PopCI * 0.15f;
    y[12] = PopCI * 0.15f * 0.25f * (1.0f - p_dth);
    y[13] = PopCI * 0.15f * 0.25f * p_dth;
    y[14] = PopD;
    y[15] = PopI;

    {
        float* sp = sol + (size_t)e * (TPTS * 16);
        #pragma unroll
        for (int i = 0; i < 16; ++i) sp[i] = y[i];
    }

    float rs20   = r_s * 0.05f;
    float rdd20  = r_dthdecay * 0.05f;
    float inv2s2 = 1.0f / (2.0f * stdn * stdn);
    float pconst = 0.6366197723675814f * (p_dth - 0.001f);

    float ag0, pd0;
    gampdt_eval(0.0f, alpha, days, rs20, jump, t_jump, inv2s2, pconst, rdd20, &ag0, &pd0);

    for (int s = 0; s < NSEG; ++s) {
        float t0 = (float)s;
        for (int j = 0; j < NSUB; ++j) {
            float agh, pdh, ag1, pd1;
            float t = t0 + (float)j * 0.1f;
            gampdt_eval(t + 0.05f, alpha, days, rs20, jump, t_jump, inv2s2, pconst, rdd20, &agh, &pdh);
            gampdt_eval(t + 0.1f,  alpha, days, rs20, jump, t_jump, inv2s2, pconst, rdd20, &ag1, &pd1);
            float d[16], acc[16], yt[16];
            deriv16(y, ag0, pd0, invN, r_dth, d);
            #pragma unroll
            for (int i = 0; i < 16; ++i) { acc[i] = d[i]; yt[i] = y[i] + 0.05f * d[i]; }
            deriv16(yt, agh, pdh, invN, r_dth, d);
            #pragma unroll
            for (int i = 0; i < 16; ++i) { acc[i] += 2.0f * d[i]; yt[i] = y[i] + 0.05f * d[i]; }
            deriv16(yt, agh, pdh, invN, r_dth, d);
            #pragma unroll
            for (int i = 0; i < 16; ++i) { acc[i] += 2.0f * d[i]; yt[i] = y[i] + 0.1f * d[i]; }
            deriv16(yt, ag1, pd1, invN, r_dth, d);
            #pragma unroll
            for (int i = 0; i < 16; ++i) y[i] += 0.016666668f * (acc[i] + d[i]);
            ag0 = ag1; pd0 = pd1;
        }
        float* sp = sol + (size_t)e * (TPTS * 16) + (size_t)(s + 1) * 16;
        #pragma unroll
        for (int i = 0; i < 16; ++i) sp[i] = y[i];
    }
}

// ---------------- host launch ----------------
extern "C" void kernel_launch(void* const* d_in, const int* in_sizes, int n_in,
                              void* d_out, int out_size, void* d_ws, size_t ws_size,
                              hipStream_t stream)
{
    const float* mi   = (const float*)d_in[0];
    const float* pop  = (const float*)d_in[1];
    const float* ccn  = (const float*)d_in[2];
    const float* mort = (const float*)d_in[3];
    const float* h0   = (const float*)d_in[4];
    const float* c0   = (const float*)d_in[5];
    const float* Wih0 = (const float*)d_in[6];
    const float* WihR = (const float*)d_in[7];
    const float* Whh  = (const float*)d_in[8];
    const float* bih  = (const float*)d_in[9];
    const float* bhh  = (const float*)d_in[10];
    const float* mW1  = (const float*)d_in[11];
    const float* mb1  = (const float*)d_in[12];
    const float* mW2  = (const float*)d_in[13];
    const float* mb2  = (const float*)d_in[14];
    const float* rW1  = (const float*)d_in[15];
    const float* rb1  = (const float*)d_in[16];
    const float* rW2  = (const float*)d_in[17];
    const float* rb2  = (const float*)d_in[18];
    const float* rng  = (const float*)d_in[19];
    const int*   ssp  = (const int*)d_in[20];

    float* out   = (float*)d_out;
    float* sol_o = out;                                   // 2048*90*16
    float* dnn_o = out + 2949120;                         // 2048*23
    float* ts_o  = out + 2949120 + 47104;                 // 2048*512
    float* raw_o = out + 2949120 + 47104 + 1048576;       // 2048*23

    float* ws  = (float*)d_ws;
    float* G   = ws;                    // 4,194,304 floats
    float* Z   = ws + 4194304;          // 2,097,152
    float* X0  = ws + 6291456;          // 1,048,576
    float* X1  = ws + 7340032;          // 1,048,576
    float* x0p = ws + 8388608;          // 65,536
    float* xmp = ws + 8454144;          // 65,536
    float* Wp0 = ws + 8519680;          // 65,536
    float* Wpm = ws + 8585216;          // 16,384   (end 8,601,600)
    __hip_bfloat16* Ab = (__hip_bfloat16*)(ws + 8601600);
    __hip_bfloat16* Wb = (__hip_bfloat16*)(ws + 8601600 + 3145728);
    float4* AG4 = (float4*)(ws + 8601600);
    bool wsOK = ws_size >= (size_t)15892480 * sizeof(float);

    prep_pad<<<256, 256, 0, stream>>>(mi, pop, Wih0, mW1, x0p, xmp, Wp0, Wpm);

    gemm_dual<1><<<dim3(4, 16), 256, 0, stream>>>(xmp, 32, Wpm, 32, 32,
                                                  nullptr, 0, nullptr, 0, 0,
                                                  mb1, nullptr, G, 512, 512);

    if (wsOK) {
        pack_split<false><<<(2048 * 512 + 255) / 256, 256, 0, stream>>>(G, 512, 512, nullptr, 0, 0, Ab, 2048);
        pack_split<true ><<<(512  * 512 + 255) / 256, 256, 0, stream>>>(mW2, 512, 512, nullptr, 0, 0, Wb, 512);
        gemm_mfma<1><<<dim3(4, 16), 256, 0, stream>>>(Ab, Wb, 1536, mb2, nullptr, Z + 512, 1024, 512);

        for (int l = 0; l < 5; ++l) {
            const float* A1 = (l == 0) ? x0p : ((l & 1) ? X1 : X0);
            int          K1 = (l == 0) ? 32 : 512;
            const float* W1 = (l == 0) ? Wp0 : (WihR + (size_t)(l - 1) * 1048576);
            int K3 = 3 * (K1 + 512);
            pack_split<false><<<(2048 * (K1 + 512) + 255) / 256, 256, 0, stream>>>(
                A1, K1, K1, h0 + (size_t)l * 1048576, 512, 512, Ab, 2048);
            pack_split<true ><<<(2048 * (K1 + 512) + 255) / 256, 256, 0, stream>>>(
                W1, K1, K1, Whh + (size_t)l * 1048576, 512, 512, Wb, 2048);
            gemm_mfma<0><<<dim3(16, 16), 256, 0, stream>>>(
                Ab, Wb, K3, bih + l * 2048, bhh + l * 2048, G, 2048, 2048);
            float* xo  = (l == 4) ? Z : ((l & 1) ? X0 : X1);
            int    xol = (l == 4) ? 1024 : 512;
            lstm_gates<<<4096, 256, 0, stream>>>(G, c0 + (size_t)l * 1048576, xo, xol,
                                                 (l == 4) ? ts_o : nullptr);
        }

        pack_split<false><<<(2048 * 1024 + 255) / 256, 256, 0, stream>>>(Z, 1024, 1024, nullptr, 0, 0, Ab, 2048);
        pack_split<true ><<<(1024 * 1024 + 255) / 256, 256, 0, stream>>>(rW1, 1024, 1024, nullptr, 0, 0, Wb, 1024);
        gemm_mfma<2><<<dim3(8, 16), 256, 0, stream>>>(Ab, Wb, 3072, rb1, nullptr, G, 1024, 1024);
    } else {
        gemm_dual<1><<<dim3(4, 16), 256, 0, stream>>>(G, 512, mW2, 512, 512,
                                                      nullptr, 0, nullptr, 0, 0,
                                                      mb2, nullptr, Z + 512, 1024, 512);
        for (int l = 0; l < 5; ++l) {
            const float* A1 = (l == 0) ? x0p : ((l & 1) ? X1 : X0);
            int          K1 = (l == 0) ? 32 : 512;
            const float* W1 = (l == 0) ? Wp0 : (WihR + (size_t)(l - 1) * 1048576);
            gemm_dual<0><<<dim3(16, 16), 256, 0, stream>>>(
                A1, K1, W1, K1, K1,
                h0 + (size_t)l * 1048576, 512, Whh + (size_t)l * 1048576, 512, 512,
                bih + l * 2048, bhh + l * 2048, G, 2048, 2048);
            float* xo  = (l == 4) ? Z : ((l & 1) ? X0 : X1);
            int    xol = (l == 4) ? 1024 : 512;
            lstm_gates<<<4096, 256, 0, stream>>>(G, c0 + (size_t)l * 1048576, xo, xol,
                                                 (l == 4) ? ts_o : nullptr);
        }
        gemm_dual<2><<<dim3(8, 16), 256, 0, stream>>>(Z, 1024, rW1, 1024, 1024,
                                                      nullptr, 0, nullptr, 0, 0,
                                                      rb1, nullptr, G, 1024, 1024);
    }

    gemm_dual<0><<<dim3(1, 16), 256, 0, stream>>>(G, 1024, rW2, 1024, 1024,
                                                  nullptr, 0, nullptr, 0, 0,
                                                  rb2, nullptr, raw_o, 23, 23);
    dnn_kernel<<<184, 256, 0, stream>>>(raw_o, ssp, rng, dnn_o);

    if (wsOK) {
        gampdt4_kernel<<<(NSTEPS * 2048 + 255) / 256, 256, 0, stream>>>(dnn_o, AG4);
        ode8_kernel<<<256, 64, 0, stream>>>(dnn_o, pop, ccn, mort, AG4, sol_o);
    } else {
        ode_kernel<<<32, 64, 0, stream>>>(dnn_o, pop, ccn, mort, sol_o);
    }
    (void)in_sizes; (void)n_in; (void)out_size;
}

// Round 6
// 1020.089 us; speedup vs baseline: 2.1056x; 1.0600x over previous
//
#include <hip/hip_runtime.h>
#include <hip/hip_bf16.h>
#include <math.h>

// ---------------- problem constants ----------------
#define BATCH 2048
#define HID 512
#define TPTS 90
#define NSEG 89
#define NSUB 10
#define NSTEPS 890          // NSEG*NSUB global substeps

__device__ __constant__ const float kR_I  = 0.6931471805599453f / 5.0f;
__device__ __constant__ const float kR_D  = 0.6931471805599453f / 2.0f;
__device__ __constant__ const float kR_RI = 0.6931471805599453f / 10.0f;
__device__ __constant__ const float kR_RH = 0.6931471805599453f / 15.0f;
__device__ __constant__ const float kR_RV = 0.6931471805599453f / 10.0f;

typedef __attribute__((ext_vector_type(8))) short short8;
typedef __attribute__((ext_vector_type(4))) short short4v;
typedef __attribute__((ext_vector_type(4))) float float4v;

__device__ __forceinline__ float sigmoidf_(float x) { return 1.0f / (1.0f + expf(-x)); }

// ---------------- prep: pad K=30 operands to K=32, x = mi[:, :30]/pop ----------------
__global__ void prep_pad(const float* __restrict__ mi, const float* __restrict__ pop,
                         const float* __restrict__ Wih0, const float* __restrict__ mW1,
                         float* __restrict__ x0p, float* __restrict__ xmp,
                         float* __restrict__ Wp0, float* __restrict__ Wpm)
{
    int i = blockIdx.x * 256 + threadIdx.x;     // < 2048*32
    int r = i >> 5, c = i & 31;
    bool v = (c < 30);
    x0p[i] = v ? mi[r * 60 + c] / pop[r] : 0.0f;
    xmp[i] = v ? mi[r * 60 + 30 + c] : 0.0f;
    Wp0[i] = v ? Wih0[r * 30 + c] : 0.0f;
    if (r < 512) Wpm[i] = v ? mW1[r * 30 + c] : 0.0f;
}

// ---------------- hi/lo bf16 split + K-concat packing (x4 vectorized) ----------------
// A-mode (WMODE=false): segments [hi | hi | lo];  W-mode (WMODE=true): [hi | lo | hi]
// K1, K2 multiples of 4.  One thread = 4 consecutive k of one row.
template<bool WMODE>
__global__ void pack_split4(const float* __restrict__ s1, int ld1, int K1,
                            const float* __restrict__ s2, int ld2, int K2,
                            __hip_bfloat16* __restrict__ dst, int rows)
{
    int idx = blockIdx.x * 256 + threadIdx.x;
    int Ks = K1 + K2, Kq = Ks >> 2;
    if (idx >= rows * Kq) return;
    int r = idx / Kq, k4 = (idx - r * Kq) << 2;
    const float* srcp; int base, seg, kk;
    if (k4 < K1) { srcp = s1 + (size_t)r * ld1 + k4; base = 0; seg = K1; kk = k4; }
    else { kk = k4 - K1; srcp = s2 + (size_t)r * ld2 + kk; base = 3 * K1; seg = K2; }
    float4 x = *(const float4*)srcp;
    union { __hip_bfloat16 b[4]; short4v v; } H, L;
    H.b[0] = __float2bfloat16(x.x); H.b[1] = __float2bfloat16(x.y);
    H.b[2] = __float2bfloat16(x.z); H.b[3] = __float2bfloat16(x.w);
    L.b[0] = __float2bfloat16(x.x - __bfloat162float(H.b[0]));
    L.b[1] = __float2bfloat16(x.y - __bfloat162float(H.b[1]));
    L.b[2] = __float2bfloat16(x.z - __bfloat162float(H.b[2]));
    L.b[3] = __float2bfloat16(x.w - __bfloat162float(H.b[3]));
    __hip_bfloat16* d = dst + (size_t)r * (3 * Ks) + base;
    *(short4v*)(d + kk)           = H.v;
    *(short4v*)(d + seg + kk)     = WMODE ? L.v : H.v;
    *(short4v*)(d + 2 * seg + kk) = WMODE ? H.v : L.v;
}

// ---------------- bf16 MFMA GEMM-NT ----------------
template<int ACT>
__global__ __launch_bounds__(256)
void gemm_mfma(const __hip_bfloat16* __restrict__ Ah,
               const __hip_bfloat16* __restrict__ Wh, int K3,
               const float* __restrict__ b1, const float* __restrict__ b2,
               float* __restrict__ Cp, int ldc, int N)
{
    __shared__ __hip_bfloat16 As[128 * 32];
    __shared__ __hip_bfloat16 Ws[128 * 32];
    const int tid  = threadIdx.x;
    const int m0   = blockIdx.y * 128;
    const int n0   = blockIdx.x * 128;
    const int lane = tid & 63, wv = tid >> 6;
    const int mw   = (wv >> 1) * 64, nw = (wv & 1) * 64;
    const int l15  = lane & 15, quad = lane >> 4;
    const int sr   = tid >> 2;
    const int sc   = (tid & 3) * 8;

    float4v acc[4][4];
    #pragma unroll
    for (int i = 0; i < 4; ++i)
        #pragma unroll
        for (int j = 0; j < 4; ++j)
            acc[i][j] = (float4v){0.0f, 0.0f, 0.0f, 0.0f};

    for (int kt = 0; kt < K3; kt += 32) {
        short8 a0 = *(const short8*)(Ah + (size_t)(m0 + sr)      * K3 + kt + sc);
        short8 a1 = *(const short8*)(Ah + (size_t)(m0 + sr + 64) * K3 + kt + sc);
        short8 w0 = *(const short8*)(Wh + (size_t)(n0 + sr)      * K3 + kt + sc);
        short8 w1 = *(const short8*)(Wh + (size_t)(n0 + sr + 64) * K3 + kt + sc);
        __syncthreads();
        *(short8*)(As + sr * 32 + sc)        = a0;
        *(short8*)(As + (sr + 64) * 32 + sc) = a1;
        *(short8*)(Ws + sr * 32 + sc)        = w0;
        *(short8*)(Ws + (sr + 64) * 32 + sc) = w1;
        __syncthreads();
        short8 af[4], bf[4];
        #pragma unroll
        for (int t = 0; t < 4; ++t) {
            af[t] = *(const short8*)(As + (mw + t * 16 + l15) * 32 + quad * 8);
            bf[t] = *(const short8*)(Ws + (nw + t * 16 + l15) * 32 + quad * 8);
        }
        #pragma unroll
        for (int i = 0; i < 4; ++i)
            #pragma unroll
            for (int j = 0; j < 4; ++j)
                acc[i][j] = __builtin_amdgcn_mfma_f32_16x16x32_bf16(af[i], bf[j], acc[i][j], 0, 0, 0);
    }

    #pragma unroll
    for (int j = 0; j < 4; ++j) {
        int col = n0 + nw + j * 16 + l15;
        float bias = b1[col] + (b2 ? b2[col] : 0.0f);
        #pragma unroll
        for (int i = 0; i < 4; ++i) {
            #pragma unroll
            for (int r = 0; r < 4; ++r) {
                int row = m0 + mw + i * 16 + quad * 4 + r;
                float v = acc[i][j][r] + bias;
                if (ACT == 1)      v = fmaxf(v, 0.0f);
                else if (ACT == 2) v = tanhf(v);
                Cp[(size_t)row * ldc + col] = v;
            }
        }
    }
}

// ---------------- fp32 tiled GEMM-NT (small GEMMs + fallback) ----------------
template<int ACT>
__global__ __launch_bounds__(256)
void gemm_dual(const float* __restrict__ A1, int lda1,
               const float* __restrict__ W1, int ldw1, int K1,
               const float* __restrict__ A2, int lda2,
               const float* __restrict__ W2, int ldw2, int K2,
               const float* __restrict__ b1p, const float* __restrict__ b2p,
               float* __restrict__ Cp, int ldc, int N)
{
    __shared__ float As[8][128];
    __shared__ float Ws[8][128];
    const int tid  = threadIdx.x;
    const int m0   = blockIdx.y * 128;
    const int n0   = blockIdx.x * 128;
    const int tm   = tid >> 4;
    const int tn   = tid & 15;
    const int lrow = tid >> 1;
    const int lkh  = (tid & 1) << 2;
    const int wrow = n0 + lrow;
    const int Ktot = K1 + K2;

    float acc[8][8];
    #pragma unroll
    for (int i = 0; i < 8; ++i)
        #pragma unroll
        for (int j = 0; j < 8; ++j) acc[i][j] = 0.0f;

    float4 av = *(const float4*)(A1 + (size_t)(m0 + lrow) * lda1 + lkh);
    float4 wv = make_float4(0.0f, 0.0f, 0.0f, 0.0f);
    if (wrow < N) wv = *(const float4*)(W1 + (size_t)wrow * ldw1 + lkh);

    for (int kt = 0; kt < Ktot; kt += 8) {
        __syncthreads();
        As[lkh + 0][lrow] = av.x; As[lkh + 1][lrow] = av.y;
        As[lkh + 2][lrow] = av.z; As[lkh + 3][lrow] = av.w;
        Ws[lkh + 0][lrow] = wv.x; Ws[lkh + 1][lrow] = wv.y;
        Ws[lkh + 2][lrow] = wv.z; Ws[lkh + 3][lrow] = wv.w;
        __syncthreads();

        int kn = kt + 8;
        float4 avn = make_float4(0.0f, 0.0f, 0.0f, 0.0f);
        float4 wvn = avn;
        if (kn < Ktot) {
            if (kn < K1) {
                avn = *(const float4*)(A1 + (size_t)(m0 + lrow) * lda1 + kn + lkh);
                if (wrow < N) wvn = *(const float4*)(W1 + (size_t)wrow * ldw1 + kn + lkh);
            } else {
                int k2 = kn - K1;
                avn = *(const float4*)(A2 + (size_t)(m0 + lrow) * lda2 + k2 + lkh);
                if (wrow < N) wvn = *(const float4*)(W2 + (size_t)wrow * ldw2 + k2 + lkh);
            }
        }

        #pragma unroll
        for (int kk = 0; kk < 8; ++kk) {
            float af[8], wf[8];
            #pragma unroll
            for (int i = 0; i < 4; ++i) {
                af[i]     = As[kk][tm * 8 + i];
                af[i + 4] = As[kk][tm * 8 + 4 + i];
                wf[i]     = Ws[kk][tn * 4 + i];
                wf[i + 4] = Ws[kk][64 + tn * 4 + i];
            }
            #pragma unroll
            for (int i = 0; i < 8; ++i)
                #pragma unroll
                for (int j = 0; j < 8; ++j)
                    acc[i][j] += af[i] * wf[j];
        }
        av = avn; wv = wvn;
    }

    #pragma unroll
    for (int j = 0; j < 8; ++j) {
        int col = n0 + ((j < 4) ? (tn * 4 + j) : (64 + tn * 4 + (j - 4)));
        if (col >= N) continue;
        float bias = b1p[col] + (b2p ? b2p[col] : 0.0f);
        #pragma unroll
        for (int i = 0; i < 8; ++i) {
            int rrow = m0 + tm * 8 + i;
            float v = acc[i][j] + bias;
            if (ACT == 1) v = fmaxf(v, 0.0f);
            else if (ACT == 2) v = tanhf(v);
            Cp[(size_t)rrow * ldc + col] = v;
        }
    }
}

// ---------------- LSTM gate nonlinearity ----------------
__global__ void lstm_gates(const float* __restrict__ G_, const float* __restrict__ c0l,
                           float* __restrict__ xout, int xld, float* __restrict__ ts)
{
    int i = blockIdx.x * 256 + threadIdx.x;     // < 2048*512
    int m = i >> 9, h = i & 511;
    const float* g = G_ + (size_t)m * 2048 + h;
    float gi = g[0], gf = g[512], gg = g[1024], go = g[1536];
    float c = sigmoidf_(gf) * c0l[i] + sigmoidf_(gi) * tanhf(gg);
    float x = sigmoidf_(go) * tanhf(c);
    xout[(size_t)m * xld + h] = x;
    if (ts) ts[i] = x;
}

// ---------------- dnn = sigmoid(raw*ss) * range ----------------
__global__ void dnn_kernel(const float* __restrict__ raw, const int* __restrict__ ssp,
                           const float* __restrict__ rng, float* __restrict__ dnn)
{
    int i = blockIdx.x * 256 + threadIdx.x;
    if (i >= 2048 * 23) return;
    int c = i % 23;
    int v = *ssp;
    float ss = (v > 100000 || v < 0) ? __int_as_float(v) : (float)v;
    dnn[i] = sigmoidf_(raw[i] * ss) * rng[c];
}

// ---------------- gam/pdt evaluation ----------------
__device__ __forceinline__ void gampdt_eval(float t, float alpha, float days, float rs20,
                                            float jump, float t_jump, float inv2s2,
                                            float pconst, float rdd20, float* ag, float* pd)
{
    float dtj = t - t_jump;
    float g = 0.6366197723675814f * atanf((days - t) * rs20) + 1.0f + jump * expf(-(dtj * dtj) * inv2s2);
    *ag = alpha * g;
    *pd = pconst * (atanf(-t * rdd20) + 1.5707963267948966f) + 0.001f;
}

// pack (ag_half*invN, pd_half, ag_end*invN, pd_end) per (substep k, chain e)
__global__ void gampdt4_kernel(const float* __restrict__ dnn, const float* __restrict__ pop,
                               float4* __restrict__ ag4)
{
    int idx = blockIdx.x * 256 + threadIdx.x;
    if (idx >= NSTEPS * 2048) return;
    int e = idx & 2047;
    int k = idx >> 11;
    int s = k / 10, j = k - s * 10;
    const float* p = dnn + e * 23 + 11;
    float alpha = p[0], days = p[1], r_s = p[2], p_dth = p[4], r_dthdecay = p[5];
    float jump = p[8], t_jump = p[9], stdn = p[10];
    float invN = 1.0f / pop[e];
    float rs20   = r_s * 0.05f;
    float rdd20  = r_dthdecay * 0.05f;
    float inv2s2 = 1.0f / (2.0f * stdn * stdn);
    float pconst = 0.6366197723675814f * (p_dth - 0.001f);
    float t = (float)s + (float)j * 0.1f;
    float agh, pdh, ag1, pd1;
    gampdt_eval(t + 0.05f, alpha, days, rs20, jump, t_jump, inv2s2, pconst, rdd20, &agh, &pdh);
    gampdt_eval(t + 0.1f,  alpha, days, rs20, jump, t_jump, inv2s2, pconst, rdd20, &ag1, &pd1);
    ag4[idx] = make_float4(agh * invN, pdh, ag1 * invN, pd1);
}

// ---------------- ODE pass 1: nonlinear core (S,E,I) + det stream + y11/y15 ----------
// One lane per chain (2048 lanes).  Stores (det1,det2,det3,det4) per substep for
// pass 2, and writes sol indices {0,1,2,11,15} per segment.  10-slot register
// ring prefetch of ag4 (consume (s,j), reload slot j <- (s+1,j): 10-substep lookahead).
__global__ __launch_bounds__(64)
void ode_core(const float* __restrict__ dnn, const float* __restrict__ pop,
              const float* __restrict__ ccn, const float* __restrict__ mort,
              const float4* __restrict__ ag4, float4* __restrict__ det4,
              float* __restrict__ sol)
{
    int e = blockIdx.x * 64 + threadIdx.x;      // 0..2047
    const float* p = dnn + e * 23 + 11;
    float alpha = p[0], days = p[1], r_s = p[2], k1p = p[6], k2p = p[7];
    float jump = p[8], t_jump = p[9], stdn = p[10], p_dth = p[4], rdd = p[5];

    float N = pop[e];
    float invN = 1.0f / N;
    float PopI = ccn[e];
    float PopD = floorf(mort[e] * PopI);
    float R0v  = (PopI - PopD > 5.0f * PopD) ? 5.0f * PopD : 0.0f;
    float PopCI = PopI - PopD - R0v;
    float DP = PopCI / 0.2f;

    float y0 = N - DP * (k1p + k2p) - R0v / 0.2f - PopD / 0.2f;
    float y1 = DP * k1p;
    float y2 = DP * k2p;
    float y11 = PopCI * 0.15f;
    float y15 = PopI;

    float* sole = sol + (size_t)e * (TPTS * 16);
    sole[0] = y0; sole[1] = y1; sole[2] = y2; sole[11] = y11; sole[15] = y15;

    // initial ag (t=0), folded with invN
    float rs20   = r_s * 0.05f;
    float rdd20  = rdd * 0.05f;
    float inv2s2 = 1.0f / (2.0f * stdn * stdn);
    float pconst = 0.6366197723675814f * (p_dth - 0.001f);
    float ag0, pd0;
    gampdt_eval(0.0f, alpha, days, rs20, jump, t_jump, inv2s2, pconst, rdd20, &ag0, &pd0);
    float agI = ag0 * invN;

    float4 cv[10];
    #pragma unroll
    for (int j = 0; j < 10; ++j) cv[j] = ag4[(size_t)j * 2048 + e];

    const float h6 = 0.016666668f;
    for (int s = 0; s < NSEG; ++s) {
        float Sdet = 0.0f;
        #pragma unroll
        for (int j = 0; j < 10; ++j) {
            float agh = cv[j].x, ag1 = cv[j].z;     // already * invN
            int kn = (s + 1) * 10 + j;
            if (kn >= NSTEPS) kn = NSTEPS - 1;
            cv[j] = ag4[(size_t)kn * 2048 + e];

            // stage 1
            float det1 = kR_D * y2;
            float t1   = kR_I * y1;
            float inf  = agI * y0 * y2;
            float d1 = inf - t1, d2 = t1 - det1;
            float a0 = -inf, a1 = d1, a2 = d2;
            float z0 = y0 - 0.05f * inf, z1 = y1 + 0.05f * d1, z2 = y2 + 0.05f * d2;
            // stage 2
            float det2 = kR_D * z2; t1 = kR_I * z1; inf = agh * z0 * z2;
            d1 = inf - t1; d2 = t1 - det2;
            a0 -= 2.0f * inf; a1 += 2.0f * d1; a2 += 2.0f * d2;
            z0 = y0 - 0.05f * inf; z1 = y1 + 0.05f * d1; z2 = y2 + 0.05f * d2;
            // stage 3
            float det3 = kR_D * z2; t1 = kR_I * z1; inf = agh * z0 * z2;
            d1 = inf - t1; d2 = t1 - det3;
            a0 -= 2.0f * inf; a1 += 2.0f * d1; a2 += 2.0f * d2;
            z0 = y0 - 0.1f * inf; z1 = y1 + 0.1f * d1; z2 = y2 + 0.1f * d2;
            // stage 4
            float det4v = kR_D * z2; t1 = kR_I * z1; inf = ag1 * z0 * z2;
            d1 = inf - t1; d2 = t1 - det4v;
            a0 -= inf; a1 += d1; a2 += d2;

            y0 += h6 * a0; y1 += h6 * a1; y2 += h6 * a2;
            float Wd = det1;
            Wd += 2.0f * det2; Wd += 2.0f * det3; Wd += det4v;
            Sdet += Wd;
            det4[(size_t)(s * 10 + j) * 2048 + e] = make_float4(det1, det2, det3, det4v);
            agI = ag1;
        }
        y11 += h6 * (0.03f * Sdet);
        y15 += h6 * (0.2f * Sdet);
        float* sp = sole + (size_t)(s + 1) * 16;
        sp[0] = y0; sp[1] = y1; sp[2] = y2; sp[11] = y11; sp[15] = y15;
    }
}

// ---------------- ODE pass 2: 8 linear decay states/chain + integrals ------------
// Lane g of chain e owns state [3,4,5,6,7,8,12,13][g]:  k = det*u - r*y with
// u = c1*(1-pd)+c2*pd.  Integrals y9/y10/y14 from shuffle-reduced segment sums.
__global__ __launch_bounds__(64)
void ode_decay(const float* __restrict__ dnn, const float* __restrict__ ccn,
               const float* __restrict__ mort, const float4* __restrict__ ag4,
               const float4* __restrict__ det4, float* __restrict__ sol)
{
    const int t  = blockIdx.x * 64 + threadIdx.x;   // 0..16383
    const int e  = t >> 3;
    const int g  = t & 7;
    const int lane = threadIdx.x & 63;
    const int base = lane & ~7;

    const float* p = dnn + e * 23 + 11;
    float r_dth = p[3], p_dth = p[4];

    float PopI = ccn[e];
    float PopD = floorf(mort[e] * PopI);
    float R0v  = (PopI - PopD > 5.0f * PopD) ? 5.0f * PopD : 0.0f;
    float PopCI = PopI - PopD - R0v;
    float DP = PopCI / 0.2f;
    float ompd = 1.0f - p_dth;

    float iy3  = (DP - PopCI) * ompd;
    float iy4  = PopCI * 0.15f * ompd;
    float iy5  = PopCI * 0.85f * ompd;
    float iy6  = (DP - PopCI) * p_dth;
    float iy7  = PopCI * 0.15f * p_dth;
    float iy8  = PopCI * 0.85f * p_dth;
    float iy12 = PopCI * 0.15f * 0.25f * ompd;
    float iy13 = PopCI * 0.15f * 0.25f * p_dth;

    float ha = (g == 0) ? iy3 : (g == 1) ? iy4 : (g == 2) ? iy5 : iy6;
    float hb = (g == 4) ? iy7 : (g == 5) ? iy8 : (g == 6) ? iy12 : iy13;
    float ys = (g < 4) ? ha : hb;
    float c1 = (g == 0) ? 0.8f : (g == 1) ? 0.03f : (g == 2) ? 0.17f : (g == 6) ? 0.0075f : 0.0f;
    float c2 = (g == 3) ? 0.8f : (g == 4) ? 0.03f : (g == 5) ? 0.17f : (g == 7) ? 0.0075f : 0.0f;
    float rr = (g == 0 || g == 2) ? kR_RI : (g == 1) ? kR_RH : (g == 6) ? kR_RV : r_dth;
    int own_idx = (g < 4) ? ((g < 2) ? (g == 0 ? 3 : 4) : (g == 2 ? 5 : 6))
                          : ((g < 6) ? (g == 4 ? 7 : 8) : (g == 6 ? 12 : 13));

    float y9  = R0v / 0.2f;
    float y10 = PopD / 0.2f;
    float y14 = PopD;

    float* sole = sol + (size_t)e * (TPTS * 16);
    sole[own_idx] = ys;
    if (g == 0) sole[9]  = y9;
    if (g == 1) sole[10] = y10;
    if (g == 2) sole[14] = y14;

    // initial pd (t=0): pconst*(atan(0)+pi/2)+0.001
    float pconst = 0.6366197723675814f * (p_dth - 0.001f);
    float pd0 = pconst * (0.0f + 1.5707963267948966f) + 0.001f;
    float u0 = c1 * (1.0f - pd0) + c2 * pd0;

    float4 cvd[10], cva[10];
    #pragma unroll
    for (int j = 0; j < 10; ++j) {
        cvd[j] = det4[(size_t)j * 2048 + e];
        cva[j] = ag4[(size_t)j * 2048 + e];
    }

    const float h6 = 0.016666668f;
    for (int s = 0; s < NSEG; ++s) {
        float Sy = 0.0f;
        #pragma unroll
        for (int j = 0; j < 10; ++j) {
            float4 dd = cvd[j];
            float pdh = cva[j].y, pd1 = cva[j].w;
            int kn = (s + 1) * 10 + j;
            if (kn >= NSTEPS) kn = NSTEPS - 1;
            cvd[j] = det4[(size_t)kn * 2048 + e];
            cva[j] = ag4[(size_t)kn * 2048 + e];

            float uh = c1 * (1.0f - pdh) + c2 * pdh;
            float u1 = c1 * (1.0f - pd1) + c2 * pd1;
            float k1v = dd.x * u0 - rr * ys;
            float zs1 = ys + 0.05f * k1v;
            float k2v = dd.y * uh - rr * zs1;
            float zs2 = ys + 0.05f * k2v;
            float k3v = dd.z * uh - rr * zs2;
            float zs3 = ys + 0.1f * k3v;
            float k4v = dd.w * u1 - rr * zs3;
            float ka = k1v + 2.0f * (k2v + k3v) + k4v;
            Sy += ys + 2.0f * (zs1 + zs2) + zs3;
            ys += h6 * ka;
            u0 = u1;
        }
        float S0 = __shfl(Sy, base + 0, 64);
        float S1 = __shfl(Sy, base + 1, 64);
        float S2 = __shfl(Sy, base + 2, 64);
        float S3 = __shfl(Sy, base + 3, 64);
        float S4 = __shfl(Sy, base + 4, 64);
        float S5 = __shfl(Sy, base + 5, 64);
        y9  += h6 * (kR_RI * (S0 + S2) + kR_RH * S1);
        y10 += h6 * (r_dth * ((S3 + S4) + S5));
        y14 += h6 * (r_dth * (S4 + S5));

        float* sp = sole + (size_t)(s + 1) * 16;
        sp[own_idx] = ys;
        if (g == 0) sp[9]  = y9;
        if (g == 1) sp[10] = y10;
        if (g == 2) sp[14] = y14;
    }
}

// ---------------- monolithic ODE fallback (no precompute) ----------------
__device__ __forceinline__ void deriv16(const float* y, float ag, float pd,
                                        float invN, float r_dth, float* d)
{
    float inf = ag * y[0] * y[2] * invN;
    float det = kR_D * y[2];
    float t1  = kR_I * y[1];
    float omp = 1.0f - pd;
    float dq  = det * omp;
    float dp  = det * pd;
    float dq003 = dq * 0.03f;
    float dp003 = dp * 0.03f;
    d[0]  = -inf;
    d[1]  = inf - t1;
    d[2]  = t1 - det;
    d[3]  = dq * 0.8f  - kR_RI * y[3];
    d[4]  = dq003      - kR_RH * y[4];
    d[5]  = dq * 0.17f - kR_RI * y[5];
    d[6]  = dp * 0.8f  - r_dth * y[6];
    d[7]  = dp003      - r_dth * y[7];
    d[8]  = dp * 0.17f - r_dth * y[8];
    d[9]  = kR_RI * (y[3] + y[5]) + kR_RH * y[4];
    d[10] = r_dth * ((y[6] + y[7]) + y[8]);
    d[11] = det * 0.03f;
    d[12] = 0.25f * dq003 - kR_RV * y[12];
    d[13] = 0.25f * dp003 - r_dth * y[13];
    d[14] = r_dth * (y[7] + y[8]);
    d[15] = det * 0.2f;
}

__global__ __launch_bounds__(64)
void ode_kernel(const float* __restrict__ dnn, const float* __restrict__ pop,
                const float* __restrict__ ccn, const float* __restrict__ mort,
                float* __restrict__ sol)
{
    int e = blockIdx.x * 64 + threadIdx.x;
    const float* p = dnn + e * 23 + 11;
    float alpha = p[0], days = p[1], r_s = p[2], r_dth = p[3], p_dth = p[4];
    float r_dthdecay = p[5], k1p = p[6], k2p = p[7], jump = p[8], t_jump = p[9], stdn = p[10];

    float N = pop[e];
    float invN = 1.0f / N;
    float PopI = ccn[e];
    float PopD = floorf(mort[e] * PopI);
    float R0v  = (PopI - PopD > 5.0f * PopD) ? 5.0f * PopD : 0.0f;
    float PopCI = PopI - PopD - R0v;
    float DP = PopCI / 0.2f;

    float y[16];
    y[0]  = N - DP * (k1p + k2p) - R0v / 0.2f - PopD / 0.2f;
    y[1]  = DP * k1p;
    y[2]  = DP * k2p;
    y[3]  = (DP - PopCI) * (1.0f - p_dth);
    y[4]  = PopCI * 0.15f * (1.0f - p_dth);
    y[5]  = PopCI * 0.85f * (1.0f - p_dth);
    y[6]  = (DP - PopCI) * p_dth;
    y[7]  = PopCI * 0.15f * p_dth;
    y[8]  = PopCI * 0.85f * p_dth;
    y[9]  = R0v / 0.2f;
    y[10] = PopD / 0.2f;
    y[11] = PopCI * 0.15f;
    y[12] = PopCI * 0.15f * 0.25f * (1.0f - p_dth);
    y[13] = PopCI * 0.15f * 0.25f * p_dth;
    y[14] = PopD;
    y[15] = PopI;

    {
        float* sp = sol + (size_t)e * (TPTS * 16);
        #pragma unroll
        for (int i = 0; i < 16; ++i) sp[i] = y[i];
    }

    float rs20   = r_s * 0.05f;
    float rdd20  = r_dthdecay * 0.05f;
    float inv2s2 = 1.0f / (2.0f * stdn * stdn);
    float pconst = 0.6366197723675814f * (p_dth - 0.001f);

    float ag0, pd0;
    gampdt_eval(0.0f, alpha, days, rs20, jump, t_jump, inv2s2, pconst, rdd20, &ag0, &pd0);

    for (int s = 0; s < NSEG; ++s) {
        float t0 = (float)s;
        for (int j = 0; j < NSUB; ++j) {
            float agh, pdh, ag1, pd1;
            float t = t0 + (float)j * 0.1f;
            gampdt_eval(t + 0.05f, alpha, days, rs20, jump, t_jump, inv2s2, pconst, rdd20, &agh, &pdh);
            gampdt_eval(t + 0.1f,  alpha, days, rs20, jump, t_jump, inv2s2, pconst, rdd20, &ag1, &pd1);
            float d[16], acc[16], yt[16];
            deriv16(y, ag0, pd0, invN, r_dth, d);
            #pragma unroll
            for (int i = 0; i < 16; ++i) { acc[i] = d[i]; yt[i] = y[i] + 0.05f * d[i]; }
            deriv16(yt, agh, pdh, invN, r_dth, d);
            #pragma unroll
            for (int i = 0; i < 16; ++i) { acc[i] += 2.0f * d[i]; yt[i] = y[i] + 0.05f * d[i]; }
            deriv16(yt, agh, pdh, invN, r_dth, d);
            #pragma unroll
            for (int i = 0; i < 16; ++i) { acc[i] += 2.0f * d[i]; yt[i] = y[i] + 0.1f * d[i]; }
            deriv16(yt, ag1, pd1, invN, r_dth, d);
            #pragma unroll
            for (int i = 0; i < 16; ++i) y[i] += 0.016666668f * (acc[i] + d[i]);
            ag0 = ag1; pd0 = pd1;
        }
        float* sp = sol + (size_t)e * (TPTS * 16) + (size_t)(s + 1) * 16;
        #pragma unroll
        for (int i = 0; i < 16; ++i) sp[i] = y[i];
    }
}

// ---------------- host launch ----------------
extern "C" void kernel_launch(void* const* d_in, const int* in_sizes, int n_in,
                              void* d_out, int out_size, void* d_ws, size_t ws_size,
                              hipStream_t stream)
{
    const float* mi   = (const float*)d_in[0];
    const float* pop  = (const float*)d_in[1];
    const float* ccn  = (const float*)d_in[2];
    const float* mort = (const float*)d_in[3];
    const float* h0   = (const float*)d_in[4];
    const float* c0   = (const float*)d_in[5];
    const float* Wih0 = (const float*)d_in[6];
    const float* WihR = (const float*)d_in[7];
    const float* Whh  = (const float*)d_in[8];
    const float* bih  = (const float*)d_in[9];
    const float* bhh  = (const float*)d_in[10];
    const float* mW1  = (const float*)d_in[11];
    const float* mb1  = (const float*)d_in[12];
    const float* mW2  = (const float*)d_in[13];
    const float* mb2  = (const float*)d_in[14];
    const float* rW1  = (const float*)d_in[15];
    const float* rb1  = (const float*)d_in[16];
    const float* rW2  = (const float*)d_in[17];
    const float* rb2  = (const float*)d_in[18];
    const float* rng  = (const float*)d_in[19];
    const int*   ssp  = (const int*)d_in[20];

    float* out   = (float*)d_out;
    float* sol_o = out;                                   // 2048*90*16
    float* dnn_o = out + 2949120;                         // 2048*23
    float* ts_o  = out + 2949120 + 47104;                 // 2048*512
    float* raw_o = out + 2949120 + 47104 + 1048576;       // 2048*23

    float* ws  = (float*)d_ws;
    float* G   = ws;                    // 4,194,304 floats (NN scratch; DET4 aliases after ro2)
    float* Z   = ws + 4194304;          // 2,097,152
    float* X0  = ws + 6291456;          // 1,048,576
    float* X1  = ws + 7340032;          // 1,048,576
    float* x0p = ws + 8388608;          // 65,536
    float* xmp = ws + 8454144;          // 65,536
    float* Wp0 = ws + 8519680;          // 65,536
    float* Wpm = ws + 8585216;          // 16,384   (end 8,601,600)
    __hip_bfloat16* Ab = (__hip_bfloat16*)(ws + 8601600);
    __hip_bfloat16* Wb = (__hip_bfloat16*)(ws + 8601600 + 3145728);
    float4* AG4  = (float4*)(ws + 8601600);          // 890*2048 float4 (aliases pack region)
    float4* DET4 = (float4*)ws;                      // 890*2048 float4 = 7,290,880 fl (aliases G+Z+X0, free after ro2)
    bool wsOK = ws_size >= (size_t)15892480 * sizeof(float);

    prep_pad<<<256, 256, 0, stream>>>(mi, pop, Wih0, mW1, x0p, xmp, Wp0, Wpm);

    gemm_dual<1><<<dim3(4, 16), 256, 0, stream>>>(xmp, 32, Wpm, 32, 32,
                                                  nullptr, 0, nullptr, 0, 0,
                                                  mb1, nullptr, G, 512, 512);

    if (wsOK) {
        // meta layer 2: K3 = 3*512
        pack_split4<false><<<(2048 * 128 + 255) / 256, 256, 0, stream>>>(G, 512, 512, nullptr, 0, 0, Ab, 2048);
        pack_split4<true ><<<(512  * 128 + 255) / 256, 256, 0, stream>>>(mW2, 512, 512, nullptr, 0, 0, Wb, 512);
        gemm_mfma<1><<<dim3(4, 16), 256, 0, stream>>>(Ab, Wb, 1536, mb2, nullptr, Z + 512, 1024, 512);

        for (int l = 0; l < 5; ++l) {
            const float* A1 = (l == 0) ? x0p : ((l & 1) ? X1 : X0);
            int          K1 = (l == 0) ? 32 : 512;
            const float* W1 = (l == 0) ? Wp0 : (WihR + (size_t)(l - 1) * 1048576);
            int Ks = K1 + 512, K3 = 3 * Ks, Kq = Ks >> 2;
            pack_split4<false><<<(2048 * Kq + 255) / 256, 256, 0, stream>>>(
                A1, K1, K1, h0 + (size_t)l * 1048576, 512, 512, Ab, 2048);
            pack_split4<true ><<<(2048 * Kq + 255) / 256, 256, 0, stream>>>(
                W1, K1, K1, Whh + (size_t)l * 1048576, 512, 512, Wb, 2048);
            gemm_mfma<0><<<dim3(16, 16), 256, 0, stream>>>(
                Ab, Wb, K3, bih + l * 2048, bhh + l * 2048, G, 2048, 2048);
            float* xo  = (l == 4) ? Z : ((l & 1) ? X0 : X1);
            int    xol = (l == 4) ? 1024 : 512;
            lstm_gates<<<4096, 256, 0, stream>>>(G, c0 + (size_t)l * 1048576, xo, xol,
                                                 (l == 4) ? ts_o : nullptr);
        }

        // readout 1: K3 = 3*1024
        pack_split4<false><<<(2048 * 256 + 255) / 256, 256, 0, stream>>>(Z, 1024, 1024, nullptr, 0, 0, Ab, 2048);
        pack_split4<true ><<<(1024 * 256 + 255) / 256, 256, 0, stream>>>(rW1, 1024, 1024, nullptr, 0, 0, Wb, 1024);
        gemm_mfma<2><<<dim3(8, 16), 256, 0, stream>>>(Ab, Wb, 3072, rb1, nullptr, G, 1024, 1024);
    } else {
        gemm_dual<1><<<dim3(4, 16), 256, 0, stream>>>(G, 512, mW2, 512, 512,
                                                      nullptr, 0, nullptr, 0, 0,
                                                      mb2, nullptr, Z + 512, 1024, 512);
        for (int l = 0; l < 5; ++l) {
            const float* A1 = (l == 0) ? x0p : ((l & 1) ? X1 : X0);
            int          K1 = (l == 0) ? 32 : 512;
            const float* W1 = (l == 0) ? Wp0 : (WihR + (size_t)(l - 1) * 1048576);
            gemm_dual<0><<<dim3(16, 16), 256, 0, stream>>>(
                A1, K1, W1, K1, K1,
                h0 + (size_t)l * 1048576, 512, Whh + (size_t)l * 1048576, 512, 512,
                bih + l * 2048, bhh + l * 2048, G, 2048, 2048);
            float* xo  = (l == 4) ? Z : ((l & 1) ? X0 : X1);
            int    xol = (l == 4) ? 1024 : 512;
            lstm_gates<<<4096, 256, 0, stream>>>(G, c0 + (size_t)l * 1048576, xo, xol,
                                                 (l == 4) ? ts_o : nullptr);
        }
        gemm_dual<2><<<dim3(8, 16), 256, 0, stream>>>(Z, 1024, rW1, 1024, 1024,
                                                      nullptr, 0, nullptr, 0, 0,
                                                      rb1, nullptr, G, 1024, 1024);
    }

    gemm_dual<0><<<dim3(1, 16), 256, 0, stream>>>(G, 1024, rW2, 1024, 1024,
                                                  nullptr, 0, nullptr, 0, 0,
                                                  rb2, nullptr, raw_o, 23, 23);
    dnn_kernel<<<184, 256, 0, stream>>>(raw_o, ssp, rng, dnn_o);

    if (wsOK) {
        gampdt4_kernel<<<(NSTEPS * 2048 + 255) / 256, 256, 0, stream>>>(dnn_o, pop, AG4);
        ode_core<<<32, 64, 0, stream>>>(dnn_o, pop, ccn, mort, AG4, DET4, sol_o);
        ode_decay<<<256, 64, 0, stream>>>(dnn_o, ccn, mort, AG4, DET4, sol_o);
    } else {
        ode_kernel<<<32, 64, 0, stream>>>(dnn_o, pop, ccn, mort, sol_o);
    }
    (void)in_sizes; (void)n_in; (void)out_size;
}

// Round 7
// 812.619 us; speedup vs baseline: 2.6432x; 1.2553x over previous
//
#include <hip/hip_runtime.h>
#include <hip/hip_bf16.h>
#include <math.h>

// ---------------- problem constants ----------------
#define BATCH 2048
#define HID 512
#define TPTS 90
#define NSEG 89
#define NSUB 10
#define NSTEPS 890          // NSEG*NSUB global substeps

__device__ __constant__ const float kR_I  = 0.6931471805599453f / 5.0f;
__device__ __constant__ const float kR_D  = 0.6931471805599453f / 2.0f;
__device__ __constant__ const float kR_RI = 0.6931471805599453f / 10.0f;
__device__ __constant__ const float kR_RH = 0.6931471805599453f / 15.0f;
__device__ __constant__ const float kR_RV = 0.6931471805599453f / 10.0f;

typedef __attribute__((ext_vector_type(8))) short short8;
typedef __attribute__((ext_vector_type(4))) short short4v;
typedef __attribute__((ext_vector_type(4))) float float4v;

__device__ __forceinline__ float sigmoidf_(float x) { return 1.0f / (1.0f + expf(-x)); }

// ---------------- prep: pad K=30 operands to K=32, x = mi[:, :30]/pop ----------------
__global__ void prep_pad(const float* __restrict__ mi, const float* __restrict__ pop,
                         const float* __restrict__ Wih0, const float* __restrict__ mW1,
                         float* __restrict__ x0p, float* __restrict__ xmp,
                         float* __restrict__ Wp0, float* __restrict__ Wpm)
{
    int i = blockIdx.x * 256 + threadIdx.x;     // < 2048*32
    int r = i >> 5, c = i & 31;
    bool v = (c < 30);
    x0p[i] = v ? mi[r * 60 + c] / pop[r] : 0.0f;
    xmp[i] = v ? mi[r * 60 + 30 + c] : 0.0f;
    Wp0[i] = v ? Wih0[r * 30 + c] : 0.0f;
    if (r < 512) Wpm[i] = v ? mW1[r * 30 + c] : 0.0f;
}

// ---------------- hi/lo bf16 split + K-concat packing (x4 vectorized) ----------------
// A-mode (WMODE=false): segments [hi | hi | lo];  W-mode (WMODE=true): [hi | lo | hi]
template<bool WMODE>
__global__ void pack_split4(const float* __restrict__ s1, int ld1, int K1,
                            const float* __restrict__ s2, int ld2, int K2,
                            __hip_bfloat16* __restrict__ dst, int rows)
{
    int idx = blockIdx.x * 256 + threadIdx.x;
    int Ks = K1 + K2, Kq = Ks >> 2;
    if (idx >= rows * Kq) return;
    int r = idx / Kq, k4 = (idx - r * Kq) << 2;
    const float* srcp; int base, seg, kk;
    if (k4 < K1) { srcp = s1 + (size_t)r * ld1 + k4; base = 0; seg = K1; kk = k4; }
    else { kk = k4 - K1; srcp = s2 + (size_t)r * ld2 + kk; base = 3 * K1; seg = K2; }
    float4 x = *(const float4*)srcp;
    union { __hip_bfloat16 b[4]; short4v v; } H, L;
    H.b[0] = __float2bfloat16(x.x); H.b[1] = __float2bfloat16(x.y);
    H.b[2] = __float2bfloat16(x.z); H.b[3] = __float2bfloat16(x.w);
    L.b[0] = __float2bfloat16(x.x - __bfloat162float(H.b[0]));
    L.b[1] = __float2bfloat16(x.y - __bfloat162float(H.b[1]));
    L.b[2] = __float2bfloat16(x.z - __bfloat162float(H.b[2]));
    L.b[3] = __float2bfloat16(x.w - __bfloat162float(H.b[3]));
    __hip_bfloat16* d = dst + (size_t)r * (3 * Ks) + base;
    *(short4v*)(d + kk)           = H.v;
    *(short4v*)(d + seg + kk)     = WMODE ? L.v : H.v;
    *(short4v*)(d + 2 * seg + kk) = WMODE ? H.v : L.v;
}

// ---------------- bf16 MFMA GEMM-NT with register-prefetch pipelining ----------------
template<int ACT>
__global__ __launch_bounds__(256)
void gemm_mfma(const __hip_bfloat16* __restrict__ Ah,
               const __hip_bfloat16* __restrict__ Wh, int K3,
               const float* __restrict__ b1, const float* __restrict__ b2,
               float* __restrict__ Cp, int ldc, int N)
{
    __shared__ __hip_bfloat16 As[128 * 32];
    __shared__ __hip_bfloat16 Ws[128 * 32];
    const int tid  = threadIdx.x;
    const int m0   = blockIdx.y * 128;
    const int n0   = blockIdx.x * 128;
    const int lane = tid & 63, wv = tid >> 6;
    const int mw   = (wv >> 1) * 64, nw = (wv & 1) * 64;
    const int l15  = lane & 15, quad = lane >> 4;
    const int sr   = tid >> 2;
    const int sc   = (tid & 3) * 8;

    float4v acc[4][4];
    #pragma unroll
    for (int i = 0; i < 4; ++i)
        #pragma unroll
        for (int j = 0; j < 4; ++j)
            acc[i][j] = (float4v){0.0f, 0.0f, 0.0f, 0.0f};

    const __hip_bfloat16* pa0 = Ah + (size_t)(m0 + sr)      * K3 + sc;
    const __hip_bfloat16* pa1 = Ah + (size_t)(m0 + sr + 64) * K3 + sc;
    const __hip_bfloat16* pw0 = Wh + (size_t)(n0 + sr)      * K3 + sc;
    const __hip_bfloat16* pw1 = Wh + (size_t)(n0 + sr + 64) * K3 + sc;

    short8 a0 = *(const short8*)(pa0);
    short8 a1 = *(const short8*)(pa1);
    short8 w0 = *(const short8*)(pw0);
    short8 w1 = *(const short8*)(pw1);

    for (int kt = 0; kt < K3; kt += 32) {
        __syncthreads();                 // previous iter's LDS reads done
        *(short8*)(As + sr * 32 + sc)        = a0;
        *(short8*)(As + (sr + 64) * 32 + sc) = a1;
        *(short8*)(Ws + sr * 32 + sc)        = w0;
        *(short8*)(Ws + (sr + 64) * 32 + sc) = w1;
        __syncthreads();

        // prefetch next k-tile; overlaps the ds_read + MFMA phase below
        int kn = kt + 32;
        if (kn < K3) {
            a0 = *(const short8*)(pa0 + kn);
            a1 = *(const short8*)(pa1 + kn);
            w0 = *(const short8*)(pw0 + kn);
            w1 = *(const short8*)(pw1 + kn);
        }

        short8 af[4], bf[4];
        #pragma unroll
        for (int t = 0; t < 4; ++t) {
            af[t] = *(const short8*)(As + (mw + t * 16 + l15) * 32 + quad * 8);
            bf[t] = *(const short8*)(Ws + (nw + t * 16 + l15) * 32 + quad * 8);
        }
        #pragma unroll
        for (int i = 0; i < 4; ++i)
            #pragma unroll
            for (int j = 0; j < 4; ++j)
                acc[i][j] = __builtin_amdgcn_mfma_f32_16x16x32_bf16(af[i], bf[j], acc[i][j], 0, 0, 0);
    }

    #pragma unroll
    for (int j = 0; j < 4; ++j) {
        int col = n0 + nw + j * 16 + l15;
        float bias = b1[col] + (b2 ? b2[col] : 0.0f);
        #pragma unroll
        for (int i = 0; i < 4; ++i) {
            #pragma unroll
            for (int r = 0; r < 4; ++r) {
                int row = m0 + mw + i * 16 + quad * 4 + r;
                float v = acc[i][j][r] + bias;
                if (ACT == 1)      v = fmaxf(v, 0.0f);
                else if (ACT == 2) v = tanhf(v);
                Cp[(size_t)row * ldc + col] = v;
            }
        }
    }
}

// ---------------- fp32 tiled GEMM-NT (small GEMMs + fallback) ----------------
template<int ACT>
__global__ __launch_bounds__(256)
void gemm_dual(const float* __restrict__ A1, int lda1,
               const float* __restrict__ W1, int ldw1, int K1,
               const float* __restrict__ A2, int lda2,
               const float* __restrict__ W2, int ldw2, int K2,
               const float* __restrict__ b1p, const float* __restrict__ b2p,
               float* __restrict__ Cp, int ldc, int N)
{
    __shared__ float As[8][128];
    __shared__ float Ws[8][128];
    const int tid  = threadIdx.x;
    const int m0   = blockIdx.y * 128;
    const int n0   = blockIdx.x * 128;
    const int tm   = tid >> 4;
    const int tn   = tid & 15;
    const int lrow = tid >> 1;
    const int lkh  = (tid & 1) << 2;
    const int wrow = n0 + lrow;
    const int Ktot = K1 + K2;

    float acc[8][8];
    #pragma unroll
    for (int i = 0; i < 8; ++i)
        #pragma unroll
        for (int j = 0; j < 8; ++j) acc[i][j] = 0.0f;

    float4 av = *(const float4*)(A1 + (size_t)(m0 + lrow) * lda1 + lkh);
    float4 wv = make_float4(0.0f, 0.0f, 0.0f, 0.0f);
    if (wrow < N) wv = *(const float4*)(W1 + (size_t)wrow * ldw1 + lkh);

    for (int kt = 0; kt < Ktot; kt += 8) {
        __syncthreads();
        As[lkh + 0][lrow] = av.x; As[lkh + 1][lrow] = av.y;
        As[lkh + 2][lrow] = av.z; As[lkh + 3][lrow] = av.w;
        Ws[lkh + 0][lrow] = wv.x; Ws[lkh + 1][lrow] = wv.y;
        Ws[lkh + 2][lrow] = wv.z; Ws[lkh + 3][lrow] = wv.w;
        __syncthreads();

        int kn = kt + 8;
        float4 avn = make_float4(0.0f, 0.0f, 0.0f, 0.0f);
        float4 wvn = avn;
        if (kn < Ktot) {
            if (kn < K1) {
                avn = *(const float4*)(A1 + (size_t)(m0 + lrow) * lda1 + kn + lkh);
                if (wrow < N) wvn = *(const float4*)(W1 + (size_t)wrow * ldw1 + kn + lkh);
            } else {
                int k2 = kn - K1;
                avn = *(const float4*)(A2 + (size_t)(m0 + lrow) * lda2 + k2 + lkh);
                if (wrow < N) wvn = *(const float4*)(W2 + (size_t)wrow * ldw2 + k2 + lkh);
            }
        }

        #pragma unroll
        for (int kk = 0; kk < 8; ++kk) {
            float af[8], wf[8];
            #pragma unroll
            for (int i = 0; i < 4; ++i) {
                af[i]     = As[kk][tm * 8 + i];
                af[i + 4] = As[kk][tm * 8 + 4 + i];
                wf[i]     = Ws[kk][tn * 4 + i];
                wf[i + 4] = Ws[kk][64 + tn * 4 + i];
            }
            #pragma unroll
            for (int i = 0; i < 8; ++i)
                #pragma unroll
                for (int j = 0; j < 8; ++j)
                    acc[i][j] += af[i] * wf[j];
        }
        av = avn; wv = wvn;
    }

    #pragma unroll
    for (int j = 0; j < 8; ++j) {
        int col = n0 + ((j < 4) ? (tn * 4 + j) : (64 + tn * 4 + (j - 4)));
        if (col >= N) continue;
        float bias = b1p[col] + (b2p ? b2p[col] : 0.0f);
        #pragma unroll
        for (int i = 0; i < 8; ++i) {
            int rrow = m0 + tm * 8 + i;
            float v = acc[i][j] + bias;
            if (ACT == 1) v = fmaxf(v, 0.0f);
            else if (ACT == 2) v = tanhf(v);
            Cp[(size_t)rrow * ldc + col] = v;
        }
    }
}

// ---------------- dedicated small-N readout GEMV: raw = G @ rW2^T + rb2 ----------
// One wave per row m (2048 waves, grid 512x256thr).  Row of A in registers;
// 23 dot products, wave-shuffle reduction.
__global__ __launch_bounds__(256)
void gemv_ro2(const float* __restrict__ A, const float* __restrict__ W,
              const float* __restrict__ b, float* __restrict__ C)
{
    int m    = blockIdx.x * 4 + (threadIdx.x >> 6);
    int lane = threadIdx.x & 63;
    const float* ar = A + (size_t)m * 1024 + lane * 4;
    float4 a0 = *(const float4*)(ar);
    float4 a1 = *(const float4*)(ar + 256);
    float4 a2 = *(const float4*)(ar + 512);
    float4 a3 = *(const float4*)(ar + 768);
    #pragma unroll 1
    for (int n = 0; n < 23; ++n) {
        const float* wr = W + (size_t)n * 1024 + lane * 4;
        float4 w0 = *(const float4*)(wr);
        float4 w1 = *(const float4*)(wr + 256);
        float4 w2 = *(const float4*)(wr + 512);
        float4 w3 = *(const float4*)(wr + 768);
        float s = a0.x * w0.x + a0.y * w0.y + a0.z * w0.z + a0.w * w0.w
                + a1.x * w1.x + a1.y * w1.y + a1.z * w1.z + a1.w * w1.w
                + a2.x * w2.x + a2.y * w2.y + a2.z * w2.z + a2.w * w2.w
                + a3.x * w3.x + a3.y * w3.y + a3.z * w3.z + a3.w * w3.w;
        #pragma unroll
        for (int o = 32; o > 0; o >>= 1) s += __shfl_xor(s, o, 64);
        if (lane == 0) C[m * 23 + n] = s + b[n];
    }
}

// ---------------- LSTM gate nonlinearity ----------------
__global__ void lstm_gates(const float* __restrict__ G_, const float* __restrict__ c0l,
                           float* __restrict__ xout, int xld, float* __restrict__ ts)
{
    int i = blockIdx.x * 256 + threadIdx.x;     // < 2048*512
    int m = i >> 9, h = i & 511;
    const float* g = G_ + (size_t)m * 2048 + h;
    float gi = g[0], gf = g[512], gg = g[1024], go = g[1536];
    float c = sigmoidf_(gf) * c0l[i] + sigmoidf_(gi) * tanhf(gg);
    float x = sigmoidf_(go) * tanhf(c);
    xout[(size_t)m * xld + h] = x;
    if (ts) ts[i] = x;
}

// ---------------- dnn = sigmoid(raw*ss) * range ----------------
__global__ void dnn_kernel(const float* __restrict__ raw, const int* __restrict__ ssp,
                           const float* __restrict__ rng, float* __restrict__ dnn)
{
    int i = blockIdx.x * 256 + threadIdx.x;
    if (i >= 2048 * 23) return;
    int c = i % 23;
    int v = *ssp;
    float ss = (v > 100000 || v < 0) ? __int_as_float(v) : (float)v;
    dnn[i] = sigmoidf_(raw[i] * ss) * rng[c];
}

// ---------------- gam/pdt evaluation ----------------
__device__ __forceinline__ void gampdt_eval(float t, float alpha, float days, float rs20,
                                            float jump, float t_jump, float inv2s2,
                                            float pconst, float rdd20, float* ag, float* pd)
{
    float dtj = t - t_jump;
    float g = 0.6366197723675814f * atanf((days - t) * rs20) + 1.0f + jump * expf(-(dtj * dtj) * inv2s2);
    *ag = alpha * g;
    *pd = pconst * (atanf(-t * rdd20) + 1.5707963267948966f) + 0.001f;
}

// pack (ag_half*invN, pd_half, ag_end*invN, pd_end) per (substep k, chain e)
__global__ void gampdt4_kernel(const float* __restrict__ dnn, const float* __restrict__ pop,
                               float4* __restrict__ ag4)
{
    int idx = blockIdx.x * 256 + threadIdx.x;
    if (idx >= NSTEPS * 2048) return;
    int e = idx & 2047;
    int k = idx >> 11;
    int s = k / 10, j = k - s * 10;
    const float* p = dnn + e * 23 + 11;
    float alpha = p[0], days = p[1], r_s = p[2], p_dth = p[4], r_dthdecay = p[5];
    float jump = p[8], t_jump = p[9], stdn = p[10];
    float invN = 1.0f / pop[e];
    float rs20   = r_s * 0.05f;
    float rdd20  = r_dthdecay * 0.05f;
    float inv2s2 = 1.0f / (2.0f * stdn * stdn);
    float pconst = 0.6366197723675814f * (p_dth - 0.001f);
    float t = (float)s + (float)j * 0.1f;
    float agh, pdh, ag1, pd1;
    gampdt_eval(t + 0.05f, alpha, days, rs20, jump, t_jump, inv2s2, pconst, rdd20, &agh, &pdh);
    gampdt_eval(t + 0.1f,  alpha, days, rs20, jump, t_jump, inv2s2, pconst, rdd20, &ag1, &pd1);
    ag4[idx] = make_float4(agh * invN, pdh, ag1 * invN, pd1);
}

// ---------------- ODE pass 1: nonlinear core (S,E,I) + det stream + y11/y15 ----------
__global__ __launch_bounds__(64)
void ode_core(const float* __restrict__ dnn, const float* __restrict__ pop,
              const float* __restrict__ ccn, const float* __restrict__ mort,
              const float4* __restrict__ ag4, float4* __restrict__ det4,
              float* __restrict__ sol)
{
    int e = blockIdx.x * 64 + threadIdx.x;      // 0..2047
    const float* p = dnn + e * 23 + 11;
    float alpha = p[0], days = p[1], r_s = p[2], k1p = p[6], k2p = p[7];
    float jump = p[8], t_jump = p[9], stdn = p[10], p_dth = p[4], rdd = p[5];

    float N = pop[e];
    float invN = 1.0f / N;
    float PopI = ccn[e];
    float PopD = floorf(mort[e] * PopI);
    float R0v  = (PopI - PopD > 5.0f * PopD) ? 5.0f * PopD : 0.0f;
    float PopCI = PopI - PopD - R0v;
    float DP = PopCI / 0.2f;

    float y0 = N - DP * (k1p + k2p) - R0v / 0.2f - PopD / 0.2f;
    float y1 = DP * k1p;
    float y2 = DP * k2p;
    float y11 = PopCI * 0.15f;
    float y15 = PopI;

    float* sole = sol + (size_t)e * (TPTS * 16);
    sole[0] = y0; sole[1] = y1; sole[2] = y2; sole[11] = y11; sole[15] = y15;

    float rs20   = r_s * 0.05f;
    float rdd20  = rdd * 0.05f;
    float inv2s2 = 1.0f / (2.0f * stdn * stdn);
    float pconst = 0.6366197723675814f * (p_dth - 0.001f);
    float ag0, pd0;
    gampdt_eval(0.0f, alpha, days, rs20, jump, t_jump, inv2s2, pconst, rdd20, &ag0, &pd0);
    float agI = ag0 * invN;

    float4 cv[10];
    #pragma unroll
    for (int j = 0; j < 10; ++j) cv[j] = ag4[(size_t)j * 2048 + e];

    const float h6 = 0.016666668f;
    for (int s = 0; s < NSEG; ++s) {
        float Sdet = 0.0f;
        #pragma unroll
        for (int j = 0; j < 10; ++j) {
            float agh = cv[j].x, ag1 = cv[j].z;     // already * invN
            int kn = (s + 1) * 10 + j;
            if (kn >= NSTEPS) kn = NSTEPS - 1;
            cv[j] = ag4[(size_t)kn * 2048 + e];

            float det1 = kR_D * y2;
            float t1   = kR_I * y1;
            float inf  = agI * y0 * y2;
            float d1 = inf - t1, d2 = t1 - det1;
            float a0 = -inf, a1 = d1, a2 = d2;
            float z0 = y0 - 0.05f * inf, z1 = y1 + 0.05f * d1, z2 = y2 + 0.05f * d2;
            float det2 = kR_D * z2; t1 = kR_I * z1; inf = agh * z0 * z2;
            d1 = inf - t1; d2 = t1 - det2;
            a0 -= 2.0f * inf; a1 += 2.0f * d1; a2 += 2.0f * d2;
            z0 = y0 - 0.05f * inf; z1 = y1 + 0.05f * d1; z2 = y2 + 0.05f * d2;
            float det3 = kR_D * z2; t1 = kR_I * z1; inf = agh * z0 * z2;
            d1 = inf - t1; d2 = t1 - det3;
            a0 -= 2.0f * inf; a1 += 2.0f * d1; a2 += 2.0f * d2;
            z0 = y0 - 0.1f * inf; z1 = y1 + 0.1f * d1; z2 = y2 + 0.1f * d2;
            float det4v = kR_D * z2; t1 = kR_I * z1; inf = ag1 * z0 * z2;
            d1 = inf - t1; d2 = t1 - det4v;
            a0 -= inf; a1 += d1; a2 += d2;

            y0 += h6 * a0; y1 += h6 * a1; y2 += h6 * a2;
            float Wd = det1;
            Wd += 2.0f * det2; Wd += 2.0f * det3; Wd += det4v;
            Sdet += Wd;
            det4[(size_t)(s * 10 + j) * 2048 + e] = make_float4(det1, det2, det3, det4v);
            agI = ag1;
        }
        y11 += h6 * (0.03f * Sdet);
        y15 += h6 * (0.2f * Sdet);
        float* sp = sole + (size_t)(s + 1) * 16;
        sp[0] = y0; sp[1] = y1; sp[2] = y2; sp[11] = y11; sp[15] = y15;
    }
}

// ---------------- ODE pass 2: 8 linear decay states/chain + integrals ------------
__global__ __launch_bounds__(64)
void ode_decay(const float* __restrict__ dnn, const float* __restrict__ ccn,
               const float* __restrict__ mort, const float4* __restrict__ ag4,
               const float4* __restrict__ det4, float* __restrict__ sol)
{
    const int t  = blockIdx.x * 64 + threadIdx.x;   // 0..16383
    const int e  = t >> 3;
    const int g  = t & 7;
    const int lane = threadIdx.x & 63;
    const int base = lane & ~7;

    const float* p = dnn + e * 23 + 11;
    float r_dth = p[3], p_dth = p[4];

    float PopI = ccn[e];
    float PopD = floorf(mort[e] * PopI);
    float R0v  = (PopI - PopD > 5.0f * PopD) ? 5.0f * PopD : 0.0f;
    float PopCI = PopI - PopD - R0v;
    float DP = PopCI / 0.2f;
    float ompd = 1.0f - p_dth;

    float iy3  = (DP - PopCI) * ompd;
    float iy4  = PopCI * 0.15f * ompd;
    float iy5  = PopCI * 0.85f * ompd;
    float iy6  = (DP - PopCI) * p_dth;
    float iy7  = PopCI * 0.15f * p_dth;
    float iy8  = PopCI * 0.85f * p_dth;
    float iy12 = PopCI * 0.15f * 0.25f * ompd;
    float iy13 = PopCI * 0.15f * 0.25f * p_dth;

    float ha = (g == 0) ? iy3 : (g == 1) ? iy4 : (g == 2) ? iy5 : iy6;
    float hb = (g == 4) ? iy7 : (g == 5) ? iy8 : (g == 6) ? iy12 : iy13;
    float ys = (g < 4) ? ha : hb;
    float c1 = (g == 0) ? 0.8f : (g == 1) ? 0.03f : (g == 2) ? 0.17f : (g == 6) ? 0.0075f : 0.0f;
    float c2 = (g == 3) ? 0.8f : (g == 4) ? 0.03f : (g == 5) ? 0.17f : (g == 7) ? 0.0075f : 0.0f;
    float rr = (g == 0 || g == 2) ? kR_RI : (g == 1) ? kR_RH : (g == 6) ? kR_RV : r_dth;
    int own_idx = (g < 4) ? ((g < 2) ? (g == 0 ? 3 : 4) : (g == 2 ? 5 : 6))
                          : ((g < 6) ? (g == 4 ? 7 : 8) : (g == 6 ? 12 : 13));

    float y9  = R0v / 0.2f;
    float y10 = PopD / 0.2f;
    float y14 = PopD;

    float* sole = sol + (size_t)e * (TPTS * 16);
    sole[own_idx] = ys;
    if (g == 0) sole[9]  = y9;
    if (g == 1) sole[10] = y10;
    if (g == 2) sole[14] = y14;

    float pconst = 0.6366197723675814f * (p_dth - 0.001f);
    float pd0 = pconst * 1.5707963267948966f + 0.001f;
    float u0 = c1 * (1.0f - pd0) + c2 * pd0;

    float4 cvd[10], cva[10];
    #pragma unroll
    for (int j = 0; j < 10; ++j) {
        cvd[j] = det4[(size_t)j * 2048 + e];
        cva[j] = ag4[(size_t)j * 2048 + e];
    }

    const float h6 = 0.016666668f;
    for (int s = 0; s < NSEG; ++s) {
        float Sy = 0.0f;
        #pragma unroll
        for (int j = 0; j < 10; ++j) {
            float4 dd = cvd[j];
            float pdh = cva[j].y, pd1 = cva[j].w;
            int kn = (s + 1) * 10 + j;
            if (kn >= NSTEPS) kn = NSTEPS - 1;
            cvd[j] = det4[(size_t)kn * 2048 + e];
            cva[j] = ag4[(size_t)kn * 2048 + e];

            float uh = c1 * (1.0f - pdh) + c2 * pdh;
            float u1 = c1 * (1.0f - pd1) + c2 * pd1;
            float k1v = dd.x * u0 - rr * ys;
            float zs1 = ys + 0.05f * k1v;
            float k2v = dd.y * uh - rr * zs1;
            float zs2 = ys + 0.05f * k2v;
            float k3v = dd.z * uh - rr * zs2;
            float zs3 = ys + 0.1f * k3v;
            float k4v = dd.w * u1 - rr * zs3;
            float ka = k1v + 2.0f * (k2v + k3v) + k4v;
            Sy += ys + 2.0f * (zs1 + zs2) + zs3;
            ys += h6 * ka;
            u0 = u1;
        }
        float S0 = __shfl(Sy, base + 0, 64);
        float S1 = __shfl(Sy, base + 1, 64);
        float S2 = __shfl(Sy, base + 2, 64);
        float S3 = __shfl(Sy, base + 3, 64);
        float S4 = __shfl(Sy, base + 4, 64);
        float S5 = __shfl(Sy, base + 5, 64);
        y9  += h6 * (kR_RI * (S0 + S2) + kR_RH * S1);
        y10 += h6 * (r_dth * ((S3 + S4) + S5));
        y14 += h6 * (r_dth * (S4 + S5));

        float* sp = sole + (size_t)(s + 1) * 16;
        sp[own_idx] = ys;
        if (g == 0) sp[9]  = y9;
        if (g == 1) sp[10] = y10;
        if (g == 2) sp[14] = y14;
    }
}

// ---------------- monolithic ODE fallback (no precompute) ----------------
__device__ __forceinline__ void deriv16(const float* y, float ag, float pd,
                                        float invN, float r_dth, float* d)
{
    float inf = ag * y[0] * y[2] * invN;
    float det = kR_D * y[2];
    float t1  = kR_I * y[1];
    float omp = 1.0f - pd;
    float dq  = det * omp;
    float dp  = det * pd;
    float dq003 = dq * 0.03f;
    float dp003 = dp * 0.03f;
    d[0]  = -inf;
    d[1]  = inf - t1;
    d[2]  = t1 - det;
    d[3]  = dq * 0.8f  - kR_RI * y[3];
    d[4]  = dq003      - kR_RH * y[4];
    d[5]  = dq * 0.17f - kR_RI * y[5];
    d[6]  = dp * 0.8f  - r_dth * y[6];
    d[7]  = dp003      - r_dth * y[7];
    d[8]  = dp * 0.17f - r_dth * y[8];
    d[9]  = kR_RI * (y[3] + y[5]) + kR_RH * y[4];
    d[10] = r_dth * ((y[6] + y[7]) + y[8]);
    d[11] = det * 0.03f;
    d[12] = 0.25f * dq003 - kR_RV * y[12];
    d[13] = 0.25f * dp003 - r_dth * y[13];
    d[14] = r_dth * (y[7] + y[8]);
    d[15] = det * 0.2f;
}

__global__ __launch_bounds__(64)
void ode_kernel(const float* __restrict__ dnn, const float* __restrict__ pop,
                const float* __restrict__ ccn, const float* __restrict__ mort,
                float* __restrict__ sol)
{
    int e = blockIdx.x * 64 + threadIdx.x;
    const float* p = dnn + e * 23 + 11;
    float alpha = p[0], days = p[1], r_s = p[2], r_dth = p[3], p_dth = p[4];
    float r_dthdecay = p[5], k1p = p[6], k2p = p[7], jump = p[8], t_jump = p[9], stdn = p[10];

    float N = pop[e];
    float invN = 1.0f / N;
    float PopI = ccn[e];
    float PopD = floorf(mort[e] * PopI);
    float R0v  = (PopI - PopD > 5.0f * PopD) ? 5.0f * PopD : 0.0f;
    float PopCI = PopI - PopD - R0v;
    float DP = PopCI / 0.2f;

    float y[16];
    y[0]  = N - DP * (k1p + k2p) - R0v / 0.2f - PopD / 0.2f;
    y[1]  = DP * k1p;
    y[2]  = DP * k2p;
    y[3]  = (DP - PopCI) * (1.0f - p_dth);
    y[4]  = PopCI * 0.15f * (1.0f - p_dth);
    y[5]  = PopCI * 0.85f * (1.0f - p_dth);
    y[6]  = (DP - PopCI) * p_dth;
    y[7]  = PopCI * 0.15f * p_dth;
    y[8]  = PopCI * 0.85f * p_dth;
    y[9]  = R0v / 0.2f;
    y[10] = PopD / 0.2f;
    y[11] = PopCI * 0.15f;
    y[12] = PopCI * 0.15f * 0.25f * (1.0f - p_dth);
    y[13] = PopCI * 0.15f * 0.25f * p_dth;
    y[14] = PopD;
    y[15] = PopI;

    {
        float* sp = sol + (size_t)e * (TPTS * 16);
        #pragma unroll
        for (int i = 0; i < 16; ++i) sp[i] = y[i];
    }

    float rs20   = r_s * 0.05f;
    float rdd20  = r_dthdecay * 0.05f;
    float inv2s2 = 1.0f / (2.0f * stdn * stdn);
    float pconst = 0.6366197723675814f * (p_dth - 0.001f);

    float ag0, pd0;
    gampdt_eval(0.0f, alpha, days, rs20, jump, t_jump, inv2s2, pconst, rdd20, &ag0, &pd0);

    for (int s = 0; s < NSEG; ++s) {
        float t0 = (float)s;
        for (int j = 0; j < NSUB; ++j) {
            float agh, pdh, ag1, pd1;
            float t = t0 + (float)j * 0.1f;
            gampdt_eval(t + 0.05f, alpha, days, rs20, jump, t_jump, inv2s2, pconst, rdd20, &agh, &pdh);
            gampdt_eval(t + 0.1f,  alpha, days, rs20, jump, t_jump, inv2s2, pconst, rdd20, &ag1, &pd1);
            float d[16], acc[16], yt[16];
            deriv16(y, ag0, pd0, invN, r_dth, d);
            #pragma unroll
            for (int i = 0; i < 16; ++i) { acc[i] = d[i]; yt[i] = y[i] + 0.05f * d[i]; }
            deriv16(yt, agh, pdh, invN, r_dth, d);
            #pragma unroll
            for (int i = 0; i < 16; ++i) { acc[i] += 2.0f * d[i]; yt[i] = y[i] + 0.05f * d[i]; }
            deriv16(yt, agh, pdh, invN, r_dth, d);
            #pragma unroll
            for (int i = 0; i < 16; ++i) { acc[i] += 2.0f * d[i]; yt[i] = y[i] + 0.1f * d[i]; }
            deriv16(yt, ag1, pd1, invN, r_dth, d);
            #pragma unroll
            for (int i = 0; i < 16; ++i) y[i] += 0.016666668f * (acc[i] + d[i]);
            ag0 = ag1; pd0 = pd1;
        }
        float* sp = sol + (size_t)e * (TPTS * 16) + (size_t)(s + 1) * 16;
        #pragma unroll
        for (int i = 0; i < 16; ++i) sp[i] = y[i];
    }
}

// ---------------- host launch ----------------
extern "C" void kernel_launch(void* const* d_in, const int* in_sizes, int n_in,
                              void* d_out, int out_size, void* d_ws, size_t ws_size,
                              hipStream_t stream)
{
    const float* mi   = (const float*)d_in[0];
    const float* pop  = (const float*)d_in[1];
    const float* ccn  = (const float*)d_in[2];
    const float* mort = (const float*)d_in[3];
    const float* h0   = (const float*)d_in[4];
    const float* c0   = (const float*)d_in[5];
    const float* Wih0 = (const float*)d_in[6];
    const float* WihR = (const float*)d_in[7];
    const float* Whh  = (const float*)d_in[8];
    const float* bih  = (const float*)d_in[9];
    const float* bhh  = (const float*)d_in[10];
    const float* mW1  = (const float*)d_in[11];
    const float* mb1  = (const float*)d_in[12];
    const float* mW2  = (const float*)d_in[13];
    const float* mb2  = (const float*)d_in[14];
    const float* rW1  = (const float*)d_in[15];
    const float* rb1  = (const float*)d_in[16];
    const float* rW2  = (const float*)d_in[17];
    const float* rb2  = (const float*)d_in[18];
    const float* rng  = (const float*)d_in[19];
    const int*   ssp  = (const int*)d_in[20];

    float* out   = (float*)d_out;
    float* sol_o = out;                                   // 2048*90*16
    float* dnn_o = out + 2949120;                         // 2048*23
    float* ts_o  = out + 2949120 + 47104;                 // 2048*512
    float* raw_o = out + 2949120 + 47104 + 1048576;       // 2048*23

    float* ws  = (float*)d_ws;
    float* G   = ws;                    // 4,194,304 floats (NN scratch; DET4 aliases after ro2)
    float* Z   = ws + 4194304;          // 2,097,152
    float* X0  = ws + 6291456;          // 1,048,576
    float* X1  = ws + 7340032;          // 1,048,576
    float* x0p = ws + 8388608;          // 65,536
    float* xmp = ws + 8454144;          // 65,536
    float* Wp0 = ws + 8519680;          // 65,536
    float* Wpm = ws + 8585216;          // 16,384   (end 8,601,600)
    __hip_bfloat16* Ab = (__hip_bfloat16*)(ws + 8601600);
    __hip_bfloat16* Wb = (__hip_bfloat16*)(ws + 8601600 + 3145728);
    float4* AG4  = (float4*)(ws + 8601600);          // aliases pack region (packs done first)
    float4* DET4 = (float4*)ws;                      // aliases G+Z+X0 (free after ro2)
    bool wsOK = ws_size >= (size_t)15892480 * sizeof(float);

    prep_pad<<<256, 256, 0, stream>>>(mi, pop, Wih0, mW1, x0p, xmp, Wp0, Wpm);

    gemm_dual<1><<<dim3(4, 16), 256, 0, stream>>>(xmp, 32, Wpm, 32, 32,
                                                  nullptr, 0, nullptr, 0, 0,
                                                  mb1, nullptr, G, 512, 512);

    if (wsOK) {
        // meta layer 2: K3 = 3*512
        pack_split4<false><<<(2048 * 128 + 255) / 256, 256, 0, stream>>>(G, 512, 512, nullptr, 0, 0, Ab, 2048);
        pack_split4<true ><<<(512  * 128 + 255) / 256, 256, 0, stream>>>(mW2, 512, 512, nullptr, 0, 0, Wb, 512);
        gemm_mfma<1><<<dim3(4, 16), 256, 0, stream>>>(Ab, Wb, 1536, mb2, nullptr, Z + 512, 1024, 512);

        for (int l = 0; l < 5; ++l) {
            const float* A1 = (l == 0) ? x0p : ((l & 1) ? X1 : X0);
            int          K1 = (l == 0) ? 32 : 512;
            const float* W1 = (l == 0) ? Wp0 : (WihR + (size_t)(l - 1) * 1048576);
            int Ks = K1 + 512, K3 = 3 * Ks, Kq = Ks >> 2;
            pack_split4<false><<<(2048 * Kq + 255) / 256, 256, 0, stream>>>(
                A1, K1, K1, h0 + (size_t)l * 1048576, 512, 512, Ab, 2048);
            pack_split4<true ><<<(2048 * Kq + 255) / 256, 256, 0, stream>>>(
                W1, K1, K1, Whh + (size_t)l * 1048576, 512, 512, Wb, 2048);
            gemm_mfma<0><<<dim3(16, 16), 256, 0, stream>>>(
                Ab, Wb, K3, bih + l * 2048, bhh + l * 2048, G, 2048, 2048);
            float* xo  = (l == 4) ? Z : ((l & 1) ? X0 : X1);
            int    xol = (l == 4) ? 1024 : 512;
            lstm_gates<<<4096, 256, 0, stream>>>(G, c0 + (size_t)l * 1048576, xo, xol,
                                                 (l == 4) ? ts_o : nullptr);
        }

        // readout 1: K3 = 3*1024
        pack_split4<false><<<(2048 * 256 + 255) / 256, 256, 0, stream>>>(Z, 1024, 1024, nullptr, 0, 0, Ab, 2048);
        pack_split4<true ><<<(1024 * 256 + 255) / 256, 256, 0, stream>>>(rW1, 1024, 1024, nullptr, 0, 0, Wb, 1024);
        gemm_mfma<2><<<dim3(8, 16), 256, 0, stream>>>(Ab, Wb, 3072, rb1, nullptr, G, 1024, 1024);
    } else {
        gemm_dual<1><<<dim3(4, 16), 256, 0, stream>>>(G, 512, mW2, 512, 512,
                                                      nullptr, 0, nullptr, 0, 0,
                                                      mb2, nullptr, Z + 512, 1024, 512);
        for (int l = 0; l < 5; ++l) {
            const float* A1 = (l == 0) ? x0p : ((l & 1) ? X1 : X0);
            int          K1 = (l == 0) ? 32 : 512;
            const float* W1 = (l == 0) ? Wp0 : (WihR + (size_t)(l - 1) * 1048576);
            gemm_dual<0><<<dim3(16, 16), 256, 0, stream>>>(
                A1, K1, W1, K1, K1,
                h0 + (size_t)l * 1048576, 512, Whh + (size_t)l * 1048576, 512, 512,
                bih + l * 2048, bhh + l * 2048, G, 2048, 2048);
            float* xo  = (l == 4) ? Z : ((l & 1) ? X0 : X1);
            int    xol = (l == 4) ? 1024 : 512;
            lstm_gates<<<4096, 256, 0, stream>>>(G, c0 + (size_t)l * 1048576, xo, xol,
                                                 (l == 4) ? ts_o : nullptr);
        }
        gemm_dual<2><<<dim3(8, 16), 256, 0, stream>>>(Z, 1024, rW1, 1024, 1024,
                                                      nullptr, 0, nullptr, 0, 0,
                                                      rb1, nullptr, G, 1024, 1024);
    }

    // readout 2 (N=23): dedicated GEMV — wave per row
    gemv_ro2<<<512, 256, 0, stream>>>(G, rW2, rb2, raw_o);
    dnn_kernel<<<184, 256, 0, stream>>>(raw_o, ssp, rng, dnn_o);

    if (wsOK) {
        gampdt4_kernel<<<(NSTEPS * 2048 + 255) / 256, 256, 0, stream>>>(dnn_o, pop, AG4);
        ode_core<<<32, 64, 0, stream>>>(dnn_o, pop, ccn, mort, AG4, DET4, sol_o);
        ode_decay<<<256, 64, 0, stream>>>(dnn_o, ccn, mort, AG4, DET4, sol_o);
    } else {
        ode_kernel<<<32, 64, 0, stream>>>(dnn_o, pop, ccn, mort, sol_o);
    }
    (void)in_sizes; (void)n_in; (void)out_size;
}

// Round 8
// 794.678 us; speedup vs baseline: 2.7028x; 1.0226x over previous
//
#include <hip/hip_runtime.h>
#include <hip/hip_bf16.h>
#include <math.h>

// ---------------- problem constants ----------------
#define BATCH 2048
#define HID 512
#define TPTS 90
#define NSEG 89
#define NSUB 10
#define NSTEPS 890          // NSEG*NSUB global substeps

#if defined(__has_builtin)
#if __has_builtin(__builtin_amdgcn_global_load_lds)
#define HAS_GLL 1
#endif
#endif
#ifndef HAS_GLL
#define HAS_GLL 0
#endif

__device__ __constant__ const float kR_I  = 0.6931471805599453f / 5.0f;
__device__ __constant__ const float kR_D  = 0.6931471805599453f / 2.0f;
__device__ __constant__ const float kR_RI = 0.6931471805599453f / 10.0f;
__device__ __constant__ const float kR_RH = 0.6931471805599453f / 15.0f;
__device__ __constant__ const float kR_RV = 0.6931471805599453f / 10.0f;

typedef __attribute__((ext_vector_type(8))) short short8;
typedef __attribute__((ext_vector_type(4))) short short4v;
typedef __attribute__((ext_vector_type(4))) float float4v;

__device__ __forceinline__ float sigmoidf_(float x) { return 1.0f / (1.0f + expf(-x)); }

#if HAS_GLL
__device__ __forceinline__ void gll16(const void* g, void* l) {
    __builtin_amdgcn_global_load_lds(
        (const __attribute__((address_space(1))) unsigned int*)g,
        (__attribute__((address_space(3))) unsigned int*)l, 16, 0, 0);
}
#endif

// ---------------- prep: pad K=30 operands to K=32, x = mi[:, :30]/pop ----------------
__global__ void prep_pad(const float* __restrict__ mi, const float* __restrict__ pop,
                         const float* __restrict__ Wih0, const float* __restrict__ mW1,
                         float* __restrict__ x0p, float* __restrict__ xmp,
                         float* __restrict__ Wp0, float* __restrict__ Wpm)
{
    int i = blockIdx.x * 256 + threadIdx.x;     // < 2048*32
    int r = i >> 5, c = i & 31;
    bool v = (c < 30);
    x0p[i] = v ? mi[r * 60 + c] / pop[r] : 0.0f;
    xmp[i] = v ? mi[r * 60 + 30 + c] : 0.0f;
    Wp0[i] = v ? Wih0[r * 30 + c] : 0.0f;
    if (r < 512) Wpm[i] = v ? mW1[r * 30 + c] : 0.0f;
}

// ---------------- hi/lo bf16 split + K-concat packing ----------------
// A-mode (wm=false): segments [hi | hi | lo];  W-mode (wm=true): [hi | lo | hi]
__device__ __forceinline__ void pack_quad(const float* __restrict__ s1, int ld1, int K1,
                                          const float* __restrict__ s2, int ld2, int K2,
                                          __hip_bfloat16* __restrict__ dst, int idx, bool wm)
{
    int Ks = K1 + K2, Kq = Ks >> 2;
    int r = idx / Kq, k4 = (idx - r * Kq) << 2;
    const float* srcp; int base, seg, kk;
    if (k4 < K1) { srcp = s1 + (size_t)r * ld1 + k4; base = 0; seg = K1; kk = k4; }
    else { kk = k4 - K1; srcp = s2 + (size_t)r * ld2 + kk; base = 3 * K1; seg = K2; }
    float4 x = *(const float4*)srcp;
    union { __hip_bfloat16 b[4]; short4v v; } H, L;
    H.b[0] = __float2bfloat16(x.x); H.b[1] = __float2bfloat16(x.y);
    H.b[2] = __float2bfloat16(x.z); H.b[3] = __float2bfloat16(x.w);
    L.b[0] = __float2bfloat16(x.x - __bfloat162float(H.b[0]));
    L.b[1] = __float2bfloat16(x.y - __bfloat162float(H.b[1]));
    L.b[2] = __float2bfloat16(x.z - __bfloat162float(H.b[2]));
    L.b[3] = __float2bfloat16(x.w - __bfloat162float(H.b[3]));
    __hip_bfloat16* d = dst + (size_t)r * (3 * Ks) + base;
    *(short4v*)(d + kk)           = H.v;
    *(short4v*)(d + seg + kk)     = wm ? L.v : H.v;
    *(short4v*)(d + 2 * seg + kk) = wm ? H.v : L.v;
}

// one launch packs both A (wm=false) and W (wm=true) operands of a layer
__global__ void pack_pair(const float* __restrict__ a1, int alda1, int aK1,
                          const float* __restrict__ a2, int alda2, int aK2,
                          __hip_bfloat16* __restrict__ da, int arows,
                          const float* __restrict__ w1, int wld1, int wK1,
                          const float* __restrict__ w2, int wld2, int wK2,
                          __hip_bfloat16* __restrict__ dw, int wrows)
{
    int aKq = (aK1 + aK2) >> 2, wKq = (wK1 + wK2) >> 2;
    int qa = arows * aKq;
    int idx = blockIdx.x * 256 + threadIdx.x;
    if (idx < qa) {
        pack_quad(a1, alda1, aK1, a2, alda2, aK2, da, idx, false);
    } else {
        idx -= qa;
        if (idx < wrows * wKq) pack_quad(w1, wld1, wK1, w2, wld2, wK2, dw, idx, true);
    }
}

// ---------------- bf16 MFMA GEMM-NT, 128x64 tile, direct global->LDS staging -------
// 256 thr = 4 waves, each wave a 64x32 quadrant via 4x2 mfma_f32_16x16x32_bf16.
// N multiple of 64, K3 multiple of 32.  ACT: 0=none, 1=relu, 2=tanh
template<int ACT>
__global__ __launch_bounds__(256, 2)
void gemm_mfma(const __hip_bfloat16* __restrict__ Ah,
               const __hip_bfloat16* __restrict__ Wh, int K3,
               const float* __restrict__ b1, const float* __restrict__ b2,
               float* __restrict__ Cp, int ldc, int N)
{
    __shared__ __hip_bfloat16 As[128 * 32];
    __shared__ __hip_bfloat16 Ws[64 * 32];
    const int tid  = threadIdx.x;
    const int m0   = blockIdx.y * 128;
    const int n0   = blockIdx.x * 64;
    const int lane = tid & 63, wv = tid >> 6;
    const int mw   = (wv >> 1) * 64, nw = (wv & 1) * 32;
    const int l15  = lane & 15, quad = lane >> 4;
    const int sr   = tid >> 2;          // 0..63
    const int sc   = (tid & 3) * 8;     // {0,8,16,24}

    float4v acc[4][2];
    #pragma unroll
    for (int i = 0; i < 4; ++i)
        #pragma unroll
        for (int j = 0; j < 2; ++j)
            acc[i][j] = (float4v){0.0f, 0.0f, 0.0f, 0.0f};

    const __hip_bfloat16* pa0 = Ah + (size_t)(m0 + sr)      * K3 + sc;
    const __hip_bfloat16* pa1 = Ah + (size_t)(m0 + sr + 64) * K3 + sc;
    const __hip_bfloat16* pw0 = Wh + (size_t)(n0 + sr)      * K3 + sc;

#if HAS_GLL
    char* ldsA0 = (char*)As + wv * 1024;            // rows 0..63, chunk = tid
    char* ldsA1 = (char*)As + 4096 + wv * 1024;     // rows 64..127
    char* ldsW0 = (char*)Ws + wv * 1024;            // rows 0..63
#endif

#if !HAS_GLL
    short8 a0 = *(const short8*)(pa0);
    short8 a1 = *(const short8*)(pa1);
    short8 w0 = *(const short8*)(pw0);
#endif

    for (int kt = 0; kt < K3; kt += 32) {
#if HAS_GLL
        __syncthreads();                 // previous iter's ds_reads done
        gll16(pa0 + kt, ldsA0);
        gll16(pa1 + kt, ldsA1);
        gll16(pw0 + kt, ldsW0);
        __syncthreads();                 // vmcnt(0) drain: data in LDS
#else
        __syncthreads();
        *(short8*)(As + sr * 32 + sc)        = a0;
        *(short8*)(As + (sr + 64) * 32 + sc) = a1;
        *(short8*)(Ws + sr * 32 + sc)        = w0;
        __syncthreads();
        int kn = kt + 32;
        if (kn < K3) {
            a0 = *(const short8*)(pa0 + kn);
            a1 = *(const short8*)(pa1 + kn);
            w0 = *(const short8*)(pw0 + kn);
        }
#endif
        short8 af[4], bf[2];
        #pragma unroll
        for (int t = 0; t < 4; ++t)
            af[t] = *(const short8*)(As + (mw + t * 16 + l15) * 32 + quad * 8);
        #pragma unroll
        for (int t = 0; t < 2; ++t)
            bf[t] = *(const short8*)(Ws + (nw + t * 16 + l15) * 32 + quad * 8);
        #pragma unroll
        for (int i = 0; i < 4; ++i)
            #pragma unroll
            for (int j = 0; j < 2; ++j)
                acc[i][j] = __builtin_amdgcn_mfma_f32_16x16x32_bf16(af[i], bf[j], acc[i][j], 0, 0, 0);
    }

    // epilogue: C/D layout col = lane&15, row = quad*4 + reg
    #pragma unroll
    for (int j = 0; j < 2; ++j) {
        int col = n0 + nw + j * 16 + l15;
        float bias = b1[col] + (b2 ? b2[col] : 0.0f);
        #pragma unroll
        for (int i = 0; i < 4; ++i) {
            #pragma unroll
            for (int r = 0; r < 4; ++r) {
                int row = m0 + mw + i * 16 + quad * 4 + r;
                float v = acc[i][j][r] + bias;
                if (ACT == 1)      v = fmaxf(v, 0.0f);
                else if (ACT == 2) v = tanhf(v);
                Cp[(size_t)row * ldc + col] = v;
            }
        }
    }
}

// ---------------- fp32 tiled GEMM-NT (meta1 + fallback) ----------------
template<int ACT>
__global__ __launch_bounds__(256)
void gemm_dual(const float* __restrict__ A1, int lda1,
               const float* __restrict__ W1, int ldw1, int K1,
               const float* __restrict__ A2, int lda2,
               const float* __restrict__ W2, int ldw2, int K2,
               const float* __restrict__ b1p, const float* __restrict__ b2p,
               float* __restrict__ Cp, int ldc, int N)
{
    __shared__ float As[8][128];
    __shared__ float Ws[8][128];
    const int tid  = threadIdx.x;
    const int m0   = blockIdx.y * 128;
    const int n0   = blockIdx.x * 128;
    const int tm   = tid >> 4;
    const int tn   = tid & 15;
    const int lrow = tid >> 1;
    const int lkh  = (tid & 1) << 2;
    const int wrow = n0 + lrow;
    const int Ktot = K1 + K2;

    float acc[8][8];
    #pragma unroll
    for (int i = 0; i < 8; ++i)
        #pragma unroll
        for (int j = 0; j < 8; ++j) acc[i][j] = 0.0f;

    float4 av = *(const float4*)(A1 + (size_t)(m0 + lrow) * lda1 + lkh);
    float4 wv = make_float4(0.0f, 0.0f, 0.0f, 0.0f);
    if (wrow < N) wv = *(const float4*)(W1 + (size_t)wrow * ldw1 + lkh);

    for (int kt = 0; kt < Ktot; kt += 8) {
        __syncthreads();
        As[lkh + 0][lrow] = av.x; As[lkh + 1][lrow] = av.y;
        As[lkh + 2][lrow] = av.z; As[lkh + 3][lrow] = av.w;
        Ws[lkh + 0][lrow] = wv.x; Ws[lkh + 1][lrow] = wv.y;
        Ws[lkh + 2][lrow] = wv.z; Ws[lkh + 3][lrow] = wv.w;
        __syncthreads();

        int kn = kt + 8;
        float4 avn = make_float4(0.0f, 0.0f, 0.0f, 0.0f);
        float4 wvn = avn;
        if (kn < Ktot) {
            if (kn < K1) {
                avn = *(const float4*)(A1 + (size_t)(m0 + lrow) * lda1 + kn + lkh);
                if (wrow < N) wvn = *(const float4*)(W1 + (size_t)wrow * ldw1 + kn + lkh);
            } else {
                int k2 = kn - K1;
                avn = *(const float4*)(A2 + (size_t)(m0 + lrow) * lda2 + k2 + lkh);
                if (wrow < N) wvn = *(const float4*)(W2 + (size_t)wrow * ldw2 + k2 + lkh);
            }
        }

        #pragma unroll
        for (int kk = 0; kk < 8; ++kk) {
            float af[8], wf[8];
            #pragma unroll
            for (int i = 0; i < 4; ++i) {
                af[i]     = As[kk][tm * 8 + i];
                af[i + 4] = As[kk][tm * 8 + 4 + i];
                wf[i]     = Ws[kk][tn * 4 + i];
                wf[i + 4] = Ws[kk][64 + tn * 4 + i];
            }
            #pragma unroll
            for (int i = 0; i < 8; ++i)
                #pragma unroll
                for (int j = 0; j < 8; ++j)
                    acc[i][j] += af[i] * wf[j];
        }
        av = avn; wv = wvn;
    }

    #pragma unroll
    for (int j = 0; j < 8; ++j) {
        int col = n0 + ((j < 4) ? (tn * 4 + j) : (64 + tn * 4 + (j - 4)));
        if (col >= N) continue;
        float bias = b1p[col] + (b2p ? b2p[col] : 0.0f);
        #pragma unroll
        for (int i = 0; i < 8; ++i) {
            int rrow = m0 + tm * 8 + i;
            float v = acc[i][j] + bias;
            if (ACT == 1) v = fmaxf(v, 0.0f);
            else if (ACT == 2) v = tanhf(v);
            Cp[(size_t)rrow * ldc + col] = v;
        }
    }
}

// ---------------- fused ro2 GEMV + dnn: raw = G@rW2^T + rb2; dnn = sig(raw*ss)*rng --
__global__ __launch_bounds__(256)
void gemv_ro2(const float* __restrict__ A, const float* __restrict__ W,
              const float* __restrict__ b, const int* __restrict__ ssp,
              const float* __restrict__ rng, float* __restrict__ raw,
              float* __restrict__ dnn)
{
    int m    = blockIdx.x * 4 + (threadIdx.x >> 6);
    int lane = threadIdx.x & 63;
    const float* ar = A + (size_t)m * 1024 + lane * 4;
    float4 a0 = *(const float4*)(ar);
    float4 a1 = *(const float4*)(ar + 256);
    float4 a2 = *(const float4*)(ar + 512);
    float4 a3 = *(const float4*)(ar + 768);
    int v = *ssp;
    float ss = (v > 100000 || v < 0) ? __int_as_float(v) : (float)v;
    #pragma unroll 1
    for (int n = 0; n < 23; ++n) {
        const float* wr = W + (size_t)n * 1024 + lane * 4;
        float4 w0 = *(const float4*)(wr);
        float4 w1 = *(const float4*)(wr + 256);
        float4 w2 = *(const float4*)(wr + 512);
        float4 w3 = *(const float4*)(wr + 768);
        float s = a0.x * w0.x + a0.y * w0.y + a0.z * w0.z + a0.w * w0.w
                + a1.x * w1.x + a1.y * w1.y + a1.z * w1.z + a1.w * w1.w
                + a2.x * w2.x + a2.y * w2.y + a2.z * w2.z + a2.w * w2.w
                + a3.x * w3.x + a3.y * w3.y + a3.z * w3.z + a3.w * w3.w;
        #pragma unroll
        for (int o = 32; o > 0; o >>= 1) s += __shfl_xor(s, o, 64);
        if (lane == 0) {
            float r2 = s + b[n];
            raw[m * 23 + n] = r2;
            dnn[m * 23 + n] = sigmoidf_(r2 * ss) * rng[n];
        }
    }
}

// ---------------- LSTM gate nonlinearity ----------------
__global__ void lstm_gates(const float* __restrict__ G_, const float* __restrict__ c0l,
                           float* __restrict__ xout, int xld, float* __restrict__ ts)
{
    int i = blockIdx.x * 256 + threadIdx.x;     // < 2048*512
    int m = i >> 9, h = i & 511;
    const float* g = G_ + (size_t)m * 2048 + h;
    float gi = g[0], gf = g[512], gg = g[1024], go = g[1536];
    float c = sigmoidf_(gf) * c0l[i] + sigmoidf_(gi) * tanhf(gg);
    float x = sigmoidf_(go) * tanhf(c);
    xout[(size_t)m * xld + h] = x;
    if (ts) ts[i] = x;
}

// ---------------- dnn (fallback path only) ----------------
__global__ void dnn_kernel(const float* __restrict__ raw, const int* __restrict__ ssp,
                           const float* __restrict__ rng, float* __restrict__ dnn)
{
    int i = blockIdx.x * 256 + threadIdx.x;
    if (i >= 2048 * 23) return;
    int c = i % 23;
    int v = *ssp;
    float ss = (v > 100000 || v < 0) ? __int_as_float(v) : (float)v;
    dnn[i] = sigmoidf_(raw[i] * ss) * rng[c];
}

// ---------------- gam/pdt evaluation ----------------
__device__ __forceinline__ void gampdt_eval(float t, float alpha, float days, float rs20,
                                            float jump, float t_jump, float inv2s2,
                                            float pconst, float rdd20, float* ag, float* pd)
{
    float dtj = t - t_jump;
    float g = 0.6366197723675814f * atanf((days - t) * rs20) + 1.0f + jump * expf(-(dtj * dtj) * inv2s2);
    *ag = alpha * g;
    *pd = pconst * (atanf(-t * rdd20) + 1.5707963267948966f) + 0.001f;
}

// pack (ag_half*invN, pd_half, ag_end*invN, pd_end) per (substep k, chain e)
__global__ void gampdt4_kernel(const float* __restrict__ dnn, const float* __restrict__ pop,
                               float4* __restrict__ ag4)
{
    int idx = blockIdx.x * 256 + threadIdx.x;
    if (idx >= NSTEPS * 2048) return;
    int e = idx & 2047;
    int k = idx >> 11;
    int s = k / 10, j = k - s * 10;
    const float* p = dnn + e * 23 + 11;
    float alpha = p[0], days = p[1], r_s = p[2], p_dth = p[4], r_dthdecay = p[5];
    float jump = p[8], t_jump = p[9], stdn = p[10];
    float invN = 1.0f / pop[e];
    float rs20   = r_s * 0.05f;
    float rdd20  = r_dthdecay * 0.05f;
    float inv2s2 = 1.0f / (2.0f * stdn * stdn);
    float pconst = 0.6366197723675814f * (p_dth - 0.001f);
    float t = (float)s + (float)j * 0.1f;
    float agh, pdh, ag1, pd1;
    gampdt_eval(t + 0.05f, alpha, days, rs20, jump, t_jump, inv2s2, pconst, rdd20, &agh, &pdh);
    gampdt_eval(t + 0.1f,  alpha, days, rs20, jump, t_jump, inv2s2, pconst, rdd20, &ag1, &pd1);
    ag4[idx] = make_float4(agh * invN, pdh, ag1 * invN, pd1);
}

// ---------------- ODE pass 1: nonlinear core (S,E,I) + det stream + y11/y15 ----------
__global__ __launch_bounds__(64)
void ode_core(const float* __restrict__ dnn, const float* __restrict__ pop,
              const float* __restrict__ ccn, const float* __restrict__ mort,
              const float4* __restrict__ ag4, float4* __restrict__ det4,
              float* __restrict__ sol)
{
    int e = blockIdx.x * 64 + threadIdx.x;      // 0..2047
    const float* p = dnn + e * 23 + 11;
    float alpha = p[0], days = p[1], r_s = p[2], k1p = p[6], k2p = p[7];
    float jump = p[8], t_jump = p[9], stdn = p[10], p_dth = p[4], rdd = p[5];

    float N = pop[e];
    float invN = 1.0f / N;
    float PopI = ccn[e];
    float PopD = floorf(mort[e] * PopI);
    float R0v  = (PopI - PopD > 5.0f * PopD) ? 5.0f * PopD : 0.0f;
    float PopCI = PopI - PopD - R0v;
    float DP = PopCI / 0.2f;

    float y0 = N - DP * (k1p + k2p) - R0v / 0.2f - PopD / 0.2f;
    float y1 = DP * k1p;
    float y2 = DP * k2p;
    float y11 = PopCI * 0.15f;
    float y15 = PopI;

    float* sole = sol + (size_t)e * (TPTS * 16);
    sole[0] = y0; sole[1] = y1; sole[2] = y2; sole[11] = y11; sole[15] = y15;

    float rs20   = r_s * 0.05f;
    float rdd20  = rdd * 0.05f;
    float inv2s2 = 1.0f / (2.0f * stdn * stdn);
    float pconst = 0.6366197723675814f * (p_dth - 0.001f);
    float ag0, pd0;
    gampdt_eval(0.0f, alpha, days, rs20, jump, t_jump, inv2s2, pconst, rdd20, &ag0, &pd0);
    float agI = ag0 * invN;

    float4 cv[10];
    #pragma unroll
    for (int j = 0; j < 10; ++j) cv[j] = ag4[(size_t)j * 2048 + e];

    const float h6 = 0.016666668f;
    for (int s = 0; s < NSEG; ++s) {
        float Sdet = 0.0f;
        #pragma unroll
        for (int j = 0; j < 10; ++j) {
            float agh = cv[j].x, ag1 = cv[j].z;     // already * invN
            int kn = (s + 1) * 10 + j;
            if (kn >= NSTEPS) kn = NSTEPS - 1;
            cv[j] = ag4[(size_t)kn * 2048 + e];

            float det1 = kR_D * y2;
            float t1   = kR_I * y1;
            float inf  = agI * y0 * y2;
            float d1 = inf - t1, d2 = t1 - det1;
            float a0 = -inf, a1 = d1, a2 = d2;
            float z0 = y0 - 0.05f * inf, z1 = y1 + 0.05f * d1, z2 = y2 + 0.05f * d2;
            float det2 = kR_D * z2; t1 = kR_I * z1; inf = agh * z0 * z2;
            d1 = inf - t1; d2 = t1 - det2;
            a0 -= 2.0f * inf; a1 += 2.0f * d1; a2 += 2.0f * d2;
            z0 = y0 - 0.05f * inf; z1 = y1 + 0.05f * d1; z2 = y2 + 0.05f * d2;
            float det3 = kR_D * z2; t1 = kR_I * z1; inf = agh * z0 * z2;
            d1 = inf - t1; d2 = t1 - det3;
            a0 -= 2.0f * inf; a1 += 2.0f * d1; a2 += 2.0f * d2;
            z0 = y0 - 0.1f * inf; z1 = y1 + 0.1f * d1; z2 = y2 + 0.1f * d2;
            float det4v = kR_D * z2; t1 = kR_I * z1; inf = ag1 * z0 * z2;
            d1 = inf - t1; d2 = t1 - det4v;
            a0 -= inf; a1 += d1; a2 += d2;

            y0 += h6 * a0; y1 += h6 * a1; y2 += h6 * a2;
            float Wd = det1;
            Wd += 2.0f * det2; Wd += 2.0f * det3; Wd += det4v;
            Sdet += Wd;
            det4[(size_t)(s * 10 + j) * 2048 + e] = make_float4(det1, det2, det3, det4v);
            agI = ag1;
        }
        y11 += h6 * (0.03f * Sdet);
        y15 += h6 * (0.2f * Sdet);
        float* sp = sole + (size_t)(s + 1) * 16;
        sp[0] = y0; sp[1] = y1; sp[2] = y2; sp[11] = y11; sp[15] = y15;
    }
}

// ---------------- ODE pass 2: 8 linear decay states/chain + integrals ------------
__global__ __launch_bounds__(64)
void ode_decay(const float* __restrict__ dnn, const float* __restrict__ ccn,
               const float* __restrict__ mort, const float4* __restrict__ ag4,
               const float4* __restrict__ det4, float* __restrict__ sol)
{
    const int t  = blockIdx.x * 64 + threadIdx.x;   // 0..16383
    const int e  = t >> 3;
    const int g  = t & 7;
    const int lane = threadIdx.x & 63;
    const int base = lane & ~7;

    const float* p = dnn + e * 23 + 11;
    float r_dth = p[3], p_dth = p[4];

    float PopI = ccn[e];
    float PopD = floorf(mort[e] * PopI);
    float R0v  = (PopI - PopD > 5.0f * PopD) ? 5.0f * PopD : 0.0f;
    float PopCI = PopI - PopD - R0v;
    float DP = PopCI / 0.2f;
    float ompd = 1.0f - p_dth;

    float iy3  = (DP - PopCI) * ompd;
    float iy4  = PopCI * 0.15f * ompd;
    float iy5  = PopCI * 0.85f * ompd;
    float iy6  = (DP - PopCI) * p_dth;
    float iy7  = PopCI * 0.15f * p_dth;
    float iy8  = PopCI * 0.85f * p_dth;
    float iy12 = PopCI * 0.15f * 0.25f * ompd;
    float iy13 = PopCI * 0.15f * 0.25f * p_dth;

    float ha = (g == 0) ? iy3 : (g == 1) ? iy4 : (g == 2) ? iy5 : iy6;
    float hb = (g == 4) ? iy7 : (g == 5) ? iy8 : (g == 6) ? iy12 : iy13;
    float ys = (g < 4) ? ha : hb;
    float c1 = (g == 0) ? 0.8f : (g == 1) ? 0.03f : (g == 2) ? 0.17f : (g == 6) ? 0.0075f : 0.0f;
    float c2 = (g == 3) ? 0.8f : (g == 4) ? 0.03f : (g == 5) ? 0.17f : (g == 7) ? 0.0075f : 0.0f;
    float rr = (g == 0 || g == 2) ? kR_RI : (g == 1) ? kR_RH : (g == 6) ? kR_RV : r_dth;
    int own_idx = (g < 4) ? ((g < 2) ? (g == 0 ? 3 : 4) : (g == 2 ? 5 : 6))
                          : ((g < 6) ? (g == 4 ? 7 : 8) : (g == 6 ? 12 : 13));

    float y9  = R0v / 0.2f;
    float y10 = PopD / 0.2f;
    float y14 = PopD;

    float* sole = sol + (size_t)e * (TPTS * 16);
    sole[own_idx] = ys;
    if (g == 0) sole[9]  = y9;
    if (g == 1) sole[10] = y10;
    if (g == 2) sole[14] = y14;

    float pconst = 0.6366197723675814f * (p_dth - 0.001f);
    float pd0 = pconst * 1.5707963267948966f + 0.001f;
    float u0 = c1 * (1.0f - pd0) + c2 * pd0;

    float4 cvd[10], cva[10];
    #pragma unroll
    for (int j = 0; j < 10; ++j) {
        cvd[j] = det4[(size_t)j * 2048 + e];
        cva[j] = ag4[(size_t)j * 2048 + e];
    }

    const float h6 = 0.016666668f;
    for (int s = 0; s < NSEG; ++s) {
        float Sy = 0.0f;
        #pragma unroll
        for (int j = 0; j < 10; ++j) {
            float4 dd = cvd[j];
            float pdh = cva[j].y, pd1 = cva[j].w;
            int kn = (s + 1) * 10 + j;
            if (kn >= NSTEPS) kn = NSTEPS - 1;
            cvd[j] = det4[(size_t)kn * 2048 + e];
            cva[j] = ag4[(size_t)kn * 2048 + e];

            float uh = c1 * (1.0f - pdh) + c2 * pdh;
            float u1 = c1 * (1.0f - pd1) + c2 * pd1;
            float k1v = dd.x * u0 - rr * ys;
            float zs1 = ys + 0.05f * k1v;
            float k2v = dd.y * uh - rr * zs1;
            float zs2 = ys + 0.05f * k2v;
            float k3v = dd.z * uh - rr * zs2;
            float zs3 = ys + 0.1f * k3v;
            float k4v = dd.w * u1 - rr * zs3;
            float ka = k1v + 2.0f * (k2v + k3v) + k4v;
            Sy += ys + 2.0f * (zs1 + zs2) + zs3;
            ys += h6 * ka;
            u0 = u1;
        }
        float S0 = __shfl(Sy, base + 0, 64);
        float S1 = __shfl(Sy, base + 1, 64);
        float S2 = __shfl(Sy, base + 2, 64);
        float S3 = __shfl(Sy, base + 3, 64);
        float S4 = __shfl(Sy, base + 4, 64);
        float S5 = __shfl(Sy, base + 5, 64);
        y9  += h6 * (kR_RI * (S0 + S2) + kR_RH * S1);
        y10 += h6 * (r_dth * ((S3 + S4) + S5));
        y14 += h6 * (r_dth * (S4 + S5));

        float* sp = sole + (size_t)(s + 1) * 16;
        sp[own_idx] = ys;
        if (g == 0) sp[9]  = y9;
        if (g == 1) sp[10] = y10;
        if (g == 2) sp[14] = y14;
    }
}

// ---------------- monolithic ODE fallback (no precompute) ----------------
__device__ __forceinline__ void deriv16(const float* y, float ag, float pd,
                                        float invN, float r_dth, float* d)
{
    float inf = ag * y[0] * y[2] * invN;
    float det = kR_D * y[2];
    float t1  = kR_I * y[1];
    float omp = 1.0f - pd;
    float dq  = det * omp;
    float dp  = det * pd;
    float dq003 = dq * 0.03f;
    float dp003 = dp * 0.03f;
    d[0]  = -inf;
    d[1]  = inf - t1;
    d[2]  = t1 - det;
    d[3]  = dq * 0.8f  - kR_RI * y[3];
    d[4]  = dq003      - kR_RH * y[4];
    d[5]  = dq * 0.17f - kR_RI * y[5];
    d[6]  = dp * 0.8f  - r_dth * y[6];
    d[7]  = dp003      - r_dth * y[7];
    d[8]  = dp * 0.17f - r_dth * y[8];
    d[9]  = kR_RI * (y[3] + y[5]) + kR_RH * y[4];
    d[10] = r_dth * ((y[6] + y[7]) + y[8]);
    d[11] = det * 0.03f;
    d[12] = 0.25f * dq003 - kR_RV * y[12];
    d[13] = 0.25f * dp003 - r_dth * y[13];
    d[14] = r_dth * (y[7] + y[8]);
    d[15] = det * 0.2f;
}

__global__ __launch_bounds__(64)
void ode_kernel(const float* __restrict__ dnn, const float* __restrict__ pop,
                const float* __restrict__ ccn, const float* __restrict__ mort,
                float* __restrict__ sol)
{
    int e = blockIdx.x * 64 + threadIdx.x;
    const float* p = dnn + e * 23 + 11;
    float alpha = p[0], days = p[1], r_s = p[2], r_dth = p[3], p_dth = p[4];
    float r_dthdecay = p[5], k1p = p[6], k2p = p[7], jump = p[8], t_jump = p[9], stdn = p[10];

    float N = pop[e];
    float invN = 1.0f / N;
    float PopI = ccn[e];
    float PopD = floorf(mort[e] * PopI);
    float R0v  = (PopI - PopD > 5.0f * PopD) ? 5.0f * PopD : 0.0f;
    float PopCI = PopI - PopD - R0v;
    float DP = PopCI / 0.2f;

    float y[16];
    y[0]  = N - DP * (k1p + k2p) - R0v / 0.2f - PopD / 0.2f;
    y[1]  = DP * k1p;
    y[2]  = DP * k2p;
    y[3]  = (DP - PopCI) * (1.0f - p_dth);
    y[4]  = PopCI * 0.15f * (1.0f - p_dth);
    y[5]  = PopCI * 0.85f * (1.0f - p_dth);
    y[6]  = (DP - PopCI) * p_dth;
    y[7]  = PopCI * 0.15f * p_dth;
    y[8]  = PopCI * 0.85f * p_dth;
    y[9]  = R0v / 0.2f;
    y[10] = PopD / 0.2f;
    y[11] = PopCI * 0.15f;
    y[12] = PopCI * 0.15f * 0.25f * (1.0f - p_dth);
    y[13] = PopCI * 0.15f * 0.25f * p_dth;
    y[14] = PopD;
    y[15] = PopI;

    {
        float* sp = sol + (size_t)e * (TPTS * 16);
        #pragma unroll
        for (int i = 0; i < 16; ++i) sp[i] = y[i];
    }

    float rs20   = r_s * 0.05f;
    float rdd20  = r_dthdecay * 0.05f;
    float inv2s2 = 1.0f / (2.0f * stdn * stdn);
    float pconst = 0.6366197723675814f * (p_dth - 0.001f);

    float ag0, pd0;
    gampdt_eval(0.0f, alpha, days, rs20, jump, t_jump, inv2s2, pconst, rdd20, &ag0, &pd0);

    for (int s = 0; s < NSEG; ++s) {
        float t0 = (float)s;
        for (int j = 0; j < NSUB; ++j) {
            float agh, pdh, ag1, pd1;
            float t = t0 + (float)j * 0.1f;
            gampdt_eval(t + 0.05f, alpha, days, rs20, jump, t_jump, inv2s2, pconst, rdd20, &agh, &pdh);
            gampdt_eval(t + 0.1f,  alpha, days, rs20, jump, t_jump, inv2s2, pconst, rdd20, &ag1, &pd1);
            float d[16], acc[16], yt[16];
            deriv16(y, ag0, pd0, invN, r_dth, d);
            #pragma unroll
            for (int i = 0; i < 16; ++i) { acc[i] = d[i]; yt[i] = y[i] + 0.05f * d[i]; }
            deriv16(yt, agh, pdh, invN, r_dth, d);
            #pragma unroll
            for (int i = 0; i < 16; ++i) { acc[i] += 2.0f * d[i]; yt[i] = y[i] + 0.05f * d[i]; }
            deriv16(yt, agh, pdh, invN, r_dth, d);
            #pragma unroll
            for (int i = 0; i < 16; ++i) { acc[i] += 2.0f * d[i]; yt[i] = y[i] + 0.1f * d[i]; }
            deriv16(yt, ag1, pd1, invN, r_dth, d);
            #pragma unroll
            for (int i = 0; i < 16; ++i) y[i] += 0.016666668f * (acc[i] + d[i]);
            ag0 = ag1; pd0 = pd1;
        }
        float* sp = sol + (size_t)e * (TPTS * 16) + (size_t)(s + 1) * 16;
        #pragma unroll
        for (int i = 0; i < 16; ++i) sp[i] = y[i];
    }
}

// ---------------- host launch ----------------
extern "C" void kernel_launch(void* const* d_in, const int* in_sizes, int n_in,
                              void* d_out, int out_size, void* d_ws, size_t ws_size,
                              hipStream_t stream)
{
    const float* mi   = (const float*)d_in[0];
    const float* pop  = (const float*)d_in[1];
    const float* ccn  = (const float*)d_in[2];
    const float* mort = (const float*)d_in[3];
    const float* h0   = (const float*)d_in[4];
    const float* c0   = (const float*)d_in[5];
    const float* Wih0 = (const float*)d_in[6];
    const float* WihR = (const float*)d_in[7];
    const float* Whh  = (const float*)d_in[8];
    const float* bih  = (const float*)d_in[9];
    const float* bhh  = (const float*)d_in[10];
    const float* mW1  = (const float*)d_in[11];
    const float* mb1  = (const float*)d_in[12];
    const float* mW2  = (const float*)d_in[13];
    const float* mb2  = (const float*)d_in[14];
    const float* rW1  = (const float*)d_in[15];
    const float* rb1  = (const float*)d_in[16];
    const float* rW2  = (const float*)d_in[17];
    const float* rb2  = (const float*)d_in[18];
    const float* rng  = (const float*)d_in[19];
    const int*   ssp  = (const int*)d_in[20];

    float* out   = (float*)d_out;
    float* sol_o = out;                                   // 2048*90*16
    float* dnn_o = out + 2949120;                         // 2048*23
    float* ts_o  = out + 2949120 + 47104;                 // 2048*512
    float* raw_o = out + 2949120 + 47104 + 1048576;       // 2048*23

    float* ws  = (float*)d_ws;
    float* G   = ws;                    // 4,194,304 floats (NN scratch; DET4 aliases after ro2)
    float* Z   = ws + 4194304;          // 2,097,152
    float* X0  = ws + 6291456;          // 1,048,576
    float* X1  = ws + 7340032;          // 1,048,576
    float* x0p = ws + 8388608;          // 65,536
    float* xmp = ws + 8454144;          // 65,536
    float* Wp0 = ws + 8519680;          // 65,536
    float* Wpm = ws + 8585216;          // 16,384   (end 8,601,600)
    __hip_bfloat16* Ab = (__hip_bfloat16*)(ws + 8601600);
    __hip_bfloat16* Wb = (__hip_bfloat16*)(ws + 8601600 + 3145728);
    float4* AG4  = (float4*)(ws + 8601600);          // aliases pack region (packs done first)
    float4* DET4 = (float4*)ws;                      // aliases G+Z+X0 (free after ro2)
    bool wsOK = ws_size >= (size_t)15892480 * sizeof(float);

    prep_pad<<<256, 256, 0, stream>>>(mi, pop, Wih0, mW1, x0p, xmp, Wp0, Wpm);

    gemm_dual<1><<<dim3(4, 16), 256, 0, stream>>>(xmp, 32, Wpm, 32, 32,
                                                  nullptr, 0, nullptr, 0, 0,
                                                  mb1, nullptr, G, 512, 512);

    if (wsOK) {
        // meta layer 2: K3 = 3*512, N=512
        pack_pair<<<(2048 * 128 + 512 * 128 + 255) / 256, 256, 0, stream>>>(
            G, 512, 512, nullptr, 0, 0, Ab, 2048,
            mW2, 512, 512, nullptr, 0, 0, Wb, 512);
        gemm_mfma<1><<<dim3(8, 16), 256, 0, stream>>>(Ab, Wb, 1536, mb2, nullptr, Z + 512, 1024, 512);

        for (int l = 0; l < 5; ++l) {
            const float* A1 = (l == 0) ? x0p : ((l & 1) ? X1 : X0);
            int          K1 = (l == 0) ? 32 : 512;
            const float* W1 = (l == 0) ? Wp0 : (WihR + (size_t)(l - 1) * 1048576);
            int Ks = K1 + 512, K3 = 3 * Ks, Kq = Ks >> 2;
            pack_pair<<<(2048 * Kq * 2 + 255) / 256, 256, 0, stream>>>(
                A1, K1, K1, h0 + (size_t)l * 1048576, 512, 512, Ab, 2048,
                W1, K1, K1, Whh + (size_t)l * 1048576, 512, 512, Wb, 2048);
            gemm_mfma<0><<<dim3(32, 16), 256, 0, stream>>>(
                Ab, Wb, K3, bih + l * 2048, bhh + l * 2048, G, 2048, 2048);
            float* xo  = (l == 4) ? Z : ((l & 1) ? X0 : X1);
            int    xol = (l == 4) ? 1024 : 512;
            lstm_gates<<<4096, 256, 0, stream>>>(G, c0 + (size_t)l * 1048576, xo, xol,
                                                 (l == 4) ? ts_o : nullptr);
        }

        // readout 1: K3 = 3*1024, N=1024
        pack_pair<<<(2048 * 256 + 1024 * 256 + 255) / 256, 256, 0, stream>>>(
            Z, 1024, 1024, nullptr, 0, 0, Ab, 2048,
            rW1, 1024, 1024, nullptr, 0, 0, Wb, 1024);
        gemm_mfma<2><<<dim3(16, 16), 256, 0, stream>>>(Ab, Wb, 3072, rb1, nullptr, G, 1024, 1024);

        // readout 2 (N=23): fused GEMV + dnn
        gemv_ro2<<<512, 256, 0, stream>>>(G, rW2, rb2, ssp, rng, raw_o, dnn_o);

        gampdt4_kernel<<<(NSTEPS * 2048 + 255) / 256, 256, 0, stream>>>(dnn_o, pop, AG4);
        ode_core<<<32, 64, 0, stream>>>(dnn_o, pop, ccn, mort, AG4, DET4, sol_o);
        ode_decay<<<256, 64, 0, stream>>>(dnn_o, ccn, mort, AG4, DET4, sol_o);
    } else {
        gemm_dual<1><<<dim3(4, 16), 256, 0, stream>>>(G, 512, mW2, 512, 512,
                                                      nullptr, 0, nullptr, 0, 0,
                                                      mb2, nullptr, Z + 512, 1024, 512);
        for (int l = 0; l < 5; ++l) {
            const float* A1 = (l == 0) ? x0p : ((l & 1) ? X1 : X0);
            int          K1 = (l == 0) ? 32 : 512;
            const float* W1 = (l == 0) ? Wp0 : (WihR + (size_t)(l - 1) * 1048576);
            gemm_dual<0><<<dim3(16, 16), 256, 0, stream>>>(
                A1, K1, W1, K1, K1,
                h0 + (size_t)l * 1048576, 512, Whh + (size_t)l * 1048576, 512, 512,
                bih + l * 2048, bhh + l * 2048, G, 2048, 2048);
            float* xo  = (l == 4) ? Z : ((l & 1) ? X0 : X1);
            int    xol = (l == 4) ? 1024 : 512;
            lstm_gates<<<4096, 256, 0, stream>>>(G, c0 + (size_t)l * 1048576, xo, xol,
                                                 (l == 4) ? ts_o : nullptr);
        }
        gemm_dual<2><<<dim3(8, 16), 256, 0, stream>>>(Z, 1024, rW1, 1024, 1024,
                                                      nullptr, 0, nullptr, 0, 0,
                                                      rb1, nullptr, G, 1024, 1024);
        gemm_dual<0><<<dim3(1, 16), 256, 0, stream>>>(G, 1024, rW2, 1024, 1024,
                                                      nullptr, 0, nullptr, 0, 0,
                                                      rb2, nullptr, raw_o, 23, 23);
        dnn_kernel<<<184, 256, 0, stream>>>(raw_o, ssp, rng, dnn_o);
        ode_kernel<<<32, 64, 0, stream>>>(dnn_o, pop, ccn, mort, sol_o);
    }
    (void)in_sizes; (void)n_in; (void)out_size;
}

// Round 9
// 748.693 us; speedup vs baseline: 2.8688x; 1.0614x over previous
//
#include <hip/hip_runtime.h>
#include <hip/hip_bf16.h>
#include <math.h>

// ---------------- problem constants ----------------
#define BATCH 2048
#define HID 512
#define TPTS 90
#define NSEG 89
#define NSUB 10
#define NSTEPS 890          // NSEG*NSUB global substeps

__device__ __constant__ const float kR_I  = 0.6931471805599453f / 5.0f;
__device__ __constant__ const float kR_D  = 0.6931471805599453f / 2.0f;
__device__ __constant__ const float kR_RI = 0.6931471805599453f / 10.0f;
__device__ __constant__ const float kR_RH = 0.6931471805599453f / 15.0f;
__device__ __constant__ const float kR_RV = 0.6931471805599453f / 10.0f;

typedef __attribute__((ext_vector_type(8))) short short8;
typedef __attribute__((ext_vector_type(4))) short short4v;
typedef __attribute__((ext_vector_type(4))) float float4v;

__device__ __forceinline__ float sigmoidf_(float x) { return 1.0f / (1.0f + expf(-x)); }

// ---------------- prep: pad K=30 operands to K=32, x = mi[:, :30]/pop ----------------
__global__ void prep_pad(const float* __restrict__ mi, const float* __restrict__ pop,
                         const float* __restrict__ Wih0, const float* __restrict__ mW1,
                         float* __restrict__ x0p, float* __restrict__ xmp,
                         float* __restrict__ Wp0, float* __restrict__ Wpm)
{
    int i = blockIdx.x * 256 + threadIdx.x;     // < 2048*32
    int r = i >> 5, c = i & 31;
    bool v = (c < 30);
    x0p[i] = v ? mi[r * 60 + c] / pop[r] : 0.0f;
    xmp[i] = v ? mi[r * 60 + 30 + c] : 0.0f;
    Wp0[i] = v ? Wih0[r * 30 + c] : 0.0f;
    if (r < 512) Wpm[i] = v ? mW1[r * 30 + c] : 0.0f;
}

// ---------------- hi/lo bf16 split + K-concat packing ----------------
// A-mode (wm=false): segments [hi | hi | lo];  W-mode (wm=true): [hi | lo | hi]
__device__ __forceinline__ void pack_quad(const float* __restrict__ s1, int ld1, int K1,
                                          const float* __restrict__ s2, int ld2, int K2,
                                          __hip_bfloat16* __restrict__ dst, int idx, bool wm)
{
    int Ks = K1 + K2, Kq = Ks >> 2;
    int r = idx / Kq, k4 = (idx - r * Kq) << 2;
    const float* srcp; int base, seg, kk;
    if (k4 < K1) { srcp = s1 + (size_t)r * ld1 + k4; base = 0; seg = K1; kk = k4; }
    else { kk = k4 - K1; srcp = s2 + (size_t)r * ld2 + kk; base = 3 * K1; seg = K2; }
    float4 x = *(const float4*)srcp;
    union { __hip_bfloat16 b[4]; short4v v; } H, L;
    H.b[0] = __float2bfloat16(x.x); H.b[1] = __float2bfloat16(x.y);
    H.b[2] = __float2bfloat16(x.z); H.b[3] = __float2bfloat16(x.w);
    L.b[0] = __float2bfloat16(x.x - __bfloat162float(H.b[0]));
    L.b[1] = __float2bfloat16(x.y - __bfloat162float(H.b[1]));
    L.b[2] = __float2bfloat16(x.z - __bfloat162float(H.b[2]));
    L.b[3] = __float2bfloat16(x.w - __bfloat162float(H.b[3]));
    __hip_bfloat16* d = dst + (size_t)r * (3 * Ks) + base;
    *(short4v*)(d + kk)           = H.v;
    *(short4v*)(d + seg + kk)     = wm ? L.v : H.v;
    *(short4v*)(d + 2 * seg + kk) = wm ? H.v : L.v;
}

// one launch packs both A (wm=false) and W (wm=true) operands of a layer
__global__ void pack_pair(const float* __restrict__ a1, int alda1, int aK1,
                          const float* __restrict__ a2, int alda2, int aK2,
                          __hip_bfloat16* __restrict__ da, int arows,
                          const float* __restrict__ w1, int wld1, int wK1,
                          const float* __restrict__ w2, int wld2, int wK2,
                          __hip_bfloat16* __restrict__ dw, int wrows)
{
    int aKq = (aK1 + aK2) >> 2, wKq = (wK1 + wK2) >> 2;
    int qa = arows * aKq;
    int idx = blockIdx.x * 256 + threadIdx.x;
    if (idx < qa) {
        pack_quad(a1, alda1, aK1, a2, alda2, aK2, da, idx, false);
    } else {
        idx -= qa;
        if (idx < wrows * wKq) pack_quad(w1, wld1, wK1, w2, wld2, wK2, dw, idx, true);
    }
}

// ---------------- bf16 MFMA GEMM-NT, 128x128 tile, register prefetch, split-K -------
// 256 thr = 4 waves, each wave a 64x64 quadrant via 4x4 mfma_f32_16x16x32_bf16.
// blockIdx.z selects the K-half: z=0 -> [0,kHalf) into Cp (+bias); z=1 ->
// [kHalf,K3) into Cp2 (no bias).  kHalf==0 means no split (full K into Cp).
// N multiple of 128, K3 multiple of 32.  ACT: 0=none, 1=relu, 2=tanh
template<int ACT>
__global__ __launch_bounds__(256, 2)
void gemm_mfma(const __hip_bfloat16* __restrict__ Ah,
               const __hip_bfloat16* __restrict__ Wh, int K3, int kHalf,
               const float* __restrict__ b1, const float* __restrict__ b2,
               float* __restrict__ Cp, float* __restrict__ Cp2, int ldc, int N)
{
    __shared__ __hip_bfloat16 As[128 * 32];
    __shared__ __hip_bfloat16 Ws[128 * 32];
    const int tid  = threadIdx.x;
    const int m0   = blockIdx.y * 128;
    const int n0   = blockIdx.x * 128;
    const int z    = blockIdx.z;
    const int k0   = z ? kHalf : 0;
    const int kLen = (kHalf == 0) ? K3 : (z ? (K3 - kHalf) : kHalf);
    float* C = z ? Cp2 : Cp;
    const int lane = tid & 63, wv = tid >> 6;
    const int mw   = (wv >> 1) * 64, nw = (wv & 1) * 64;
    const int l15  = lane & 15, quad = lane >> 4;
    const int sr   = tid >> 2;          // 0..63
    const int sc   = (tid & 3) * 8;     // {0,8,16,24}

    float4v acc[4][4];
    #pragma unroll
    for (int i = 0; i < 4; ++i)
        #pragma unroll
        for (int j = 0; j < 4; ++j)
            acc[i][j] = (float4v){0.0f, 0.0f, 0.0f, 0.0f};

    const __hip_bfloat16* pa0 = Ah + (size_t)(m0 + sr)      * K3 + k0 + sc;
    const __hip_bfloat16* pa1 = Ah + (size_t)(m0 + sr + 64) * K3 + k0 + sc;
    const __hip_bfloat16* pw0 = Wh + (size_t)(n0 + sr)      * K3 + k0 + sc;
    const __hip_bfloat16* pw1 = Wh + (size_t)(n0 + sr + 64) * K3 + k0 + sc;

    short8 a0 = *(const short8*)(pa0);
    short8 a1 = *(const short8*)(pa1);
    short8 w0 = *(const short8*)(pw0);
    short8 w1 = *(const short8*)(pw1);

    for (int kt = 0; kt < kLen; kt += 32) {
        __syncthreads();                 // previous iter's LDS reads done
        *(short8*)(As + sr * 32 + sc)        = a0;
        *(short8*)(As + (sr + 64) * 32 + sc) = a1;
        *(short8*)(Ws + sr * 32 + sc)        = w0;
        *(short8*)(Ws + (sr + 64) * 32 + sc) = w1;
        __syncthreads();

        // prefetch next k-tile into registers; overlaps ds_read + MFMA below
        int kn = kt + 32;
        if (kn < kLen) {
            a0 = *(const short8*)(pa0 + kn);
            a1 = *(const short8*)(pa1 + kn);
            w0 = *(const short8*)(pw0 + kn);
            w1 = *(const short8*)(pw1 + kn);
        }

        short8 af[4], bf[4];
        #pragma unroll
        for (int t = 0; t < 4; ++t) {
            af[t] = *(const short8*)(As + (mw + t * 16 + l15) * 32 + quad * 8);
            bf[t] = *(const short8*)(Ws + (nw + t * 16 + l15) * 32 + quad * 8);
        }
        #pragma unroll
        for (int i = 0; i < 4; ++i)
            #pragma unroll
            for (int j = 0; j < 4; ++j)
                acc[i][j] = __builtin_amdgcn_mfma_f32_16x16x32_bf16(af[i], bf[j], acc[i][j], 0, 0, 0);
    }

    // epilogue: C/D layout col = lane&15, row = quad*4 + reg
    #pragma unroll
    for (int j = 0; j < 4; ++j) {
        int col = n0 + nw + j * 16 + l15;
        float bias = z ? 0.0f : (b1[col] + (b2 ? b2[col] : 0.0f));
        #pragma unroll
        for (int i = 0; i < 4; ++i) {
            #pragma unroll
            for (int r = 0; r < 4; ++r) {
                int row = m0 + mw + i * 16 + quad * 4 + r;
                float v = acc[i][j][r] + bias;
                if (ACT == 1)      v = fmaxf(v, 0.0f);
                else if (ACT == 2) v = tanhf(v);
                C[(size_t)row * ldc + col] = v;
            }
        }
    }
}

// ---------------- fp32 tiled GEMM-NT (meta1 + fallback) ----------------
template<int ACT>
__global__ __launch_bounds__(256)
void gemm_dual(const float* __restrict__ A1, int lda1,
               const float* __restrict__ W1, int ldw1, int K1,
               const float* __restrict__ A2, int lda2,
               const float* __restrict__ W2, int ldw2, int K2,
               const float* __restrict__ b1p, const float* __restrict__ b2p,
               float* __restrict__ Cp, int ldc, int N)
{
    __shared__ float As[8][128];
    __shared__ float Ws[8][128];
    const int tid  = threadIdx.x;
    const int m0   = blockIdx.y * 128;
    const int n0   = blockIdx.x * 128;
    const int tm   = tid >> 4;
    const int tn   = tid & 15;
    const int lrow = tid >> 1;
    const int lkh  = (tid & 1) << 2;
    const int wrow = n0 + lrow;
    const int Ktot = K1 + K2;

    float acc[8][8];
    #pragma unroll
    for (int i = 0; i < 8; ++i)
        #pragma unroll
        for (int j = 0; j < 8; ++j) acc[i][j] = 0.0f;

    float4 av = *(const float4*)(A1 + (size_t)(m0 + lrow) * lda1 + lkh);
    float4 wv = make_float4(0.0f, 0.0f, 0.0f, 0.0f);
    if (wrow < N) wv = *(const float4*)(W1 + (size_t)wrow * ldw1 + lkh);

    for (int kt = 0; kt < Ktot; kt += 8) {
        __syncthreads();
        As[lkh + 0][lrow] = av.x; As[lkh + 1][lrow] = av.y;
        As[lkh + 2][lrow] = av.z; As[lkh + 3][lrow] = av.w;
        Ws[lkh + 0][lrow] = wv.x; Ws[lkh + 1][lrow] = wv.y;
        Ws[lkh + 2][lrow] = wv.z; Ws[lkh + 3][lrow] = wv.w;
        __syncthreads();

        int kn = kt + 8;
        float4 avn = make_float4(0.0f, 0.0f, 0.0f, 0.0f);
        float4 wvn = avn;
        if (kn < Ktot) {
            if (kn < K1) {
                avn = *(const float4*)(A1 + (size_t)(m0 + lrow) * lda1 + kn + lkh);
                if (wrow < N) wvn = *(const float4*)(W1 + (size_t)wrow * ldw1 + kn + lkh);
            } else {
                int k2 = kn - K1;
                avn = *(const float4*)(A2 + (size_t)(m0 + lrow) * lda2 + k2 + lkh);
                if (wrow < N) wvn = *(const float4*)(W2 + (size_t)wrow * ldw2 + k2 + lkh);
            }
        }

        #pragma unroll
        for (int kk = 0; kk < 8; ++kk) {
            float af[8], wf[8];
            #pragma unroll
            for (int i = 0; i < 4; ++i) {
                af[i]     = As[kk][tm * 8 + i];
                af[i + 4] = As[kk][tm * 8 + 4 + i];
                wf[i]     = Ws[kk][tn * 4 + i];
                wf[i + 4] = Ws[kk][64 + tn * 4 + i];
            }
            #pragma unroll
            for (int i = 0; i < 8; ++i)
                #pragma unroll
                for (int j = 0; j < 8; ++j)
                    acc[i][j] += af[i] * wf[j];
        }
        av = avn; wv = wvn;
    }

    #pragma unroll
    for (int j = 0; j < 8; ++j) {
        int col = n0 + ((j < 4) ? (tn * 4 + j) : (64 + tn * 4 + (j - 4)));
        if (col >= N) continue;
        float bias = b1p[col] + (b2p ? b2p[col] : 0.0f);
        #pragma unroll
        for (int i = 0; i < 8; ++i) {
            int rrow = m0 + tm * 8 + i;
            float v = acc[i][j] + bias;
            if (ACT == 1) v = fmaxf(v, 0.0f);
            else if (ACT == 2) v = tanhf(v);
            Cp[(size_t)rrow * ldc + col] = v;
        }
    }
}

// ---------------- fused ro2 GEMV + dnn: raw = G@rW2^T + rb2; dnn = sig(raw*ss)*rng --
__global__ __launch_bounds__(256)
void gemv_ro2(const float* __restrict__ A, const float* __restrict__ W,
              const float* __restrict__ b, const int* __restrict__ ssp,
              const float* __restrict__ rng, float* __restrict__ raw,
              float* __restrict__ dnn)
{
    int m    = blockIdx.x * 4 + (threadIdx.x >> 6);
    int lane = threadIdx.x & 63;
    const float* ar = A + (size_t)m * 1024 + lane * 4;
    float4 a0 = *(const float4*)(ar);
    float4 a1 = *(const float4*)(ar + 256);
    float4 a2 = *(const float4*)(ar + 512);
    float4 a3 = *(const float4*)(ar + 768);
    int v = *ssp;
    float ss = (v > 100000 || v < 0) ? __int_as_float(v) : (float)v;
    #pragma unroll 1
    for (int n = 0; n < 23; ++n) {
        const float* wr = W + (size_t)n * 1024 + lane * 4;
        float4 w0 = *(const float4*)(wr);
        float4 w1 = *(const float4*)(wr + 256);
        float4 w2 = *(const float4*)(wr + 512);
        float4 w3 = *(const float4*)(wr + 768);
        float s = a0.x * w0.x + a0.y * w0.y + a0.z * w0.z + a0.w * w0.w
                + a1.x * w1.x + a1.y * w1.y + a1.z * w1.z + a1.w * w1.w
                + a2.x * w2.x + a2.y * w2.y + a2.z * w2.z + a2.w * w2.w
                + a3.x * w3.x + a3.y * w3.y + a3.z * w3.z + a3.w * w3.w;
        #pragma unroll
        for (int o = 32; o > 0; o >>= 1) s += __shfl_xor(s, o, 64);
        if (lane == 0) {
            float r2 = s + b[n];
            raw[m * 23 + n] = r2;
            dnn[m * 23 + n] = sigmoidf_(r2 * ss) * rng[n];
        }
    }
}

// ---------------- LSTM gate nonlinearity (sums split-K partials) ----------------
__global__ void lstm_gates(const float* __restrict__ G0, const float* __restrict__ G1,
                           const float* __restrict__ c0l,
                           float* __restrict__ xout, int xld, float* __restrict__ ts)
{
    int i = blockIdx.x * 256 + threadIdx.x;     // < 2048*512
    int m = i >> 9, h = i & 511;
    const float* g = G0 + (size_t)m * 2048 + h;
    float gi = g[0], gf = g[512], gg = g[1024], go = g[1536];
    if (G1) {
        const float* g2 = G1 + (size_t)m * 2048 + h;
        gi += g2[0]; gf += g2[512]; gg += g2[1024]; go += g2[1536];
    }
    float c = sigmoidf_(gf) * c0l[i] + sigmoidf_(gi) * tanhf(gg);
    float x = sigmoidf_(go) * tanhf(c);
    xout[(size_t)m * xld + h] = x;
    if (ts) ts[i] = x;
}

// ---------------- dnn (fallback path only) ----------------
__global__ void dnn_kernel(const float* __restrict__ raw, const int* __restrict__ ssp,
                           const float* __restrict__ rng, float* __restrict__ dnn)
{
    int i = blockIdx.x * 256 + threadIdx.x;
    if (i >= 2048 * 23) return;
    int c = i % 23;
    int v = *ssp;
    float ss = (v > 100000 || v < 0) ? __int_as_float(v) : (float)v;
    dnn[i] = sigmoidf_(raw[i] * ss) * rng[c];
}

// ---------------- gam/pdt evaluation ----------------
__device__ __forceinline__ void gampdt_eval(float t, float alpha, float days, float rs20,
                                            float jump, float t_jump, float inv2s2,
                                            float pconst, float rdd20, float* ag, float* pd)
{
    float dtj = t - t_jump;
    float g = 0.6366197723675814f * atanf((days - t) * rs20) + 1.0f + jump * expf(-(dtj * dtj) * inv2s2);
    *ag = alpha * g;
    *pd = pconst * (atanf(-t * rdd20) + 1.5707963267948966f) + 0.001f;
}

// pack (ag_half*invN, pd_half, ag_end*invN, pd_end) per (substep k, chain e)
__global__ void gampdt4_kernel(const float* __restrict__ dnn, const float* __restrict__ pop,
                               float4* __restrict__ ag4)
{
    int idx = blockIdx.x * 256 + threadIdx.x;
    if (idx >= NSTEPS * 2048) return;
    int e = idx & 2047;
    int k = idx >> 11;
    int s = k / 10, j = k - s * 10;
    const float* p = dnn + e * 23 + 11;
    float alpha = p[0], days = p[1], r_s = p[2], p_dth = p[4], r_dthdecay = p[5];
    float jump = p[8], t_jump = p[9], stdn = p[10];
    float invN = 1.0f / pop[e];
    float rs20   = r_s * 0.05f;
    float rdd20  = r_dthdecay * 0.05f;
    float inv2s2 = 1.0f / (2.0f * stdn * stdn);
    float pconst = 0.6366197723675814f * (p_dth - 0.001f);
    float t = (float)s + (float)j * 0.1f;
    float agh, pdh, ag1, pd1;
    gampdt_eval(t + 0.05f, alpha, days, rs20, jump, t_jump, inv2s2, pconst, rdd20, &agh, &pdh);
    gampdt_eval(t + 0.1f,  alpha, days, rs20, jump, t_jump, inv2s2, pconst, rdd20, &ag1, &pd1);
    ag4[idx] = make_float4(agh * invN, pdh, ag1 * invN, pd1);
}

// ---------------- ODE pass 1: nonlinear core (S,E,I) + det stream + y11/y15 ----------
__global__ __launch_bounds__(64)
void ode_core(const float* __restrict__ dnn, const float* __restrict__ pop,
              const float* __restrict__ ccn, const float* __restrict__ mort,
              const float4* __restrict__ ag4, float4* __restrict__ det4,
              float* __restrict__ sol)
{
    int e = blockIdx.x * 64 + threadIdx.x;      // 0..2047
    const float* p = dnn + e * 23 + 11;
    float alpha = p[0], days = p[1], r_s = p[2], k1p = p[6], k2p = p[7];
    float jump = p[8], t_jump = p[9], stdn = p[10], p_dth = p[4], rdd = p[5];

    float N = pop[e];
    float invN = 1.0f / N;
    float PopI = ccn[e];
    float PopD = floorf(mort[e] * PopI);
    float R0v  = (PopI - PopD > 5.0f * PopD) ? 5.0f * PopD : 0.0f;
    float PopCI = PopI - PopD - R0v;
    float DP = PopCI / 0.2f;

    float y0 = N - DP * (k1p + k2p) - R0v / 0.2f - PopD / 0.2f;
    float y1 = DP * k1p;
    float y2 = DP * k2p;
    float y11 = PopCI * 0.15f;
    float y15 = PopI;

    float* sole = sol + (size_t)e * (TPTS * 16);
    sole[0] = y0; sole[1] = y1; sole[2] = y2; sole[11] = y11; sole[15] = y15;

    float rs20   = r_s * 0.05f;
    float rdd20  = rdd * 0.05f;
    float inv2s2 = 1.0f / (2.0f * stdn * stdn);
    float pconst = 0.6366197723675814f * (p_dth - 0.001f);
    float ag0, pd0;
    gampdt_eval(0.0f, alpha, days, rs20, jump, t_jump, inv2s2, pconst, rdd20, &ag0, &pd0);
    float agI = ag0 * invN;

    float4 cv[10];
    #pragma unroll
    for (int j = 0; j < 10; ++j) cv[j] = ag4[(size_t)j * 2048 + e];

    const float h6 = 0.016666668f;
    for (int s = 0; s < NSEG; ++s) {
        float Sdet = 0.0f;
        #pragma unroll
        for (int j = 0; j < 10; ++j) {
            float agh = cv[j].x, ag1 = cv[j].z;     // already * invN
            int kn = (s + 1) * 10 + j;
            if (kn >= NSTEPS) kn = NSTEPS - 1;
            cv[j] = ag4[(size_t)kn * 2048 + e];

            float det1 = kR_D * y2;
            float t1   = kR_I * y1;
            float inf  = agI * y0 * y2;
            float d1 = inf - t1, d2 = t1 - det1;
            float a0 = -inf, a1 = d1, a2 = d2;
            float z0 = y0 - 0.05f * inf, z1 = y1 + 0.05f * d1, z2 = y2 + 0.05f * d2;
            float det2 = kR_D * z2; t1 = kR_I * z1; inf = agh * z0 * z2;
            d1 = inf - t1; d2 = t1 - det2;
            a0 -= 2.0f * inf; a1 += 2.0f * d1; a2 += 2.0f * d2;
            z0 = y0 - 0.05f * inf; z1 = y1 + 0.05f * d1; z2 = y2 + 0.05f * d2;
            float det3 = kR_D * z2; t1 = kR_I * z1; inf = agh * z0 * z2;
            d1 = inf - t1; d2 = t1 - det3;
            a0 -= 2.0f * inf; a1 += 2.0f * d1; a2 += 2.0f * d2;
            z0 = y0 - 0.1f * inf; z1 = y1 + 0.1f * d1; z2 = y2 + 0.1f * d2;
            float det4v = kR_D * z2; t1 = kR_I * z1; inf = ag1 * z0 * z2;
            d1 = inf - t1; d2 = t1 - det4v;
            a0 -= inf; a1 += d1; a2 += d2;

            y0 += h6 * a0; y1 += h6 * a1; y2 += h6 * a2;
            float Wd = det1;
            Wd += 2.0f * det2; Wd += 2.0f * det3; Wd += det4v;
            Sdet += Wd;
            det4[(size_t)(s * 10 + j) * 2048 + e] = make_float4(det1, det2, det3, det4v);
            agI = ag1;
        }
        y11 += h6 * (0.03f * Sdet);
        y15 += h6 * (0.2f * Sdet);
        float* sp = sole + (size_t)(s + 1) * 16;
        sp[0] = y0; sp[1] = y1; sp[2] = y2; sp[11] = y11; sp[15] = y15;
    }
}

// ---------------- ODE pass 2: 8 linear decay states/chain + integrals ------------
__global__ __launch_bounds__(64)
void ode_decay(const float* __restrict__ dnn, const float* __restrict__ ccn,
               const float* __restrict__ mort, const float4* __restrict__ ag4,
               const float4* __restrict__ det4, float* __restrict__ sol)
{
    const int t  = blockIdx.x * 64 + threadIdx.x;   // 0..16383
    const int e  = t >> 3;
    const int g  = t & 7;
    const int lane = threadIdx.x & 63;
    const int base = lane & ~7;

    const float* p = dnn + e * 23 + 11;
    float r_dth = p[3], p_dth = p[4];

    float PopI = ccn[e];
    float PopD = floorf(mort[e] * PopI);
    float R0v  = (PopI - PopD > 5.0f * PopD) ? 5.0f * PopD : 0.0f;
    float PopCI = PopI - PopD - R0v;
    float DP = PopCI / 0.2f;
    float ompd = 1.0f - p_dth;

    float iy3  = (DP - PopCI) * ompd;
    float iy4  = PopCI * 0.15f * ompd;
    float iy5  = PopCI * 0.85f * ompd;
    float iy6  = (DP - PopCI) * p_dth;
    float iy7  = PopCI * 0.15f * p_dth;
    float iy8  = PopCI * 0.85f * p_dth;
    float iy12 = PopCI * 0.15f * 0.25f * ompd;
    float iy13 = PopCI * 0.15f * 0.25f * p_dth;

    float ha = (g == 0) ? iy3 : (g == 1) ? iy4 : (g == 2) ? iy5 : iy6;
    float hb = (g == 4) ? iy7 : (g == 5) ? iy8 : (g == 6) ? iy12 : iy13;
    float ys = (g < 4) ? ha : hb;
    float c1 = (g == 0) ? 0.8f : (g == 1) ? 0.03f : (g == 2) ? 0.17f : (g == 6) ? 0.0075f : 0.0f;
    float c2 = (g == 3) ? 0.8f : (g == 4) ? 0.03f : (g == 5) ? 0.17f : (g == 7) ? 0.0075f : 0.0f;
    float rr = (g == 0 || g == 2) ? kR_RI : (g == 1) ? kR_RH : (g == 6) ? kR_RV : r_dth;
    int own_idx = (g < 4) ? ((g < 2) ? (g == 0 ? 3 : 4) : (g == 2 ? 5 : 6))
                          : ((g < 6) ? (g == 4 ? 7 : 8) : (g == 6 ? 12 : 13));

    float y9  = R0v / 0.2f;
    float y10 = PopD / 0.2f;
    float y14 = PopD;

    float* sole = sol + (size_t)e * (TPTS * 16);
    sole[own_idx] = ys;
    if (g == 0) sole[9]  = y9;
    if (g == 1) sole[10] = y10;
    if (g == 2) sole[14] = y14;

    float pconst = 0.6366197723675814f * (p_dth - 0.001f);
    float pd0 = pconst * 1.5707963267948966f + 0.001f;
    float u0 = c1 * (1.0f - pd0) + c2 * pd0;

    float4 cvd[10], cva[10];
    #pragma unroll
    for (int j = 0; j < 10; ++j) {
        cvd[j] = det4[(size_t)j * 2048 + e];
        cva[j] = ag4[(size_t)j * 2048 + e];
    }

    const float h6 = 0.016666668f;
    for (int s = 0; s < NSEG; ++s) {
        float Sy = 0.0f;
        #pragma unroll
        for (int j = 0; j < 10; ++j) {
            float4 dd = cvd[j];
            float pdh = cva[j].y, pd1 = cva[j].w;
            int kn = (s + 1) * 10 + j;
            if (kn >= NSTEPS) kn = NSTEPS - 1;
            cvd[j] = det4[(size_t)kn * 2048 + e];
            cva[j] = ag4[(size_t)kn * 2048 + e];

            float uh = c1 * (1.0f - pdh) + c2 * pdh;
            float u1 = c1 * (1.0f - pd1) + c2 * pd1;
            float k1v = dd.x * u0 - rr * ys;
            float zs1 = ys + 0.05f * k1v;
            float k2v = dd.y * uh - rr * zs1;
            float zs2 = ys + 0.05f * k2v;
            float k3v = dd.z * uh - rr * zs2;
            float zs3 = ys + 0.1f * k3v;
            float k4v = dd.w * u1 - rr * zs3;
            float ka = k1v + 2.0f * (k2v + k3v) + k4v;
            Sy += ys + 2.0f * (zs1 + zs2) + zs3;
            ys += h6 * ka;
            u0 = u1;
        }
        float S0 = __shfl(Sy, base + 0, 64);
        float S1 = __shfl(Sy, base + 1, 64);
        float S2 = __shfl(Sy, base + 2, 64);
        float S3 = __shfl(Sy, base + 3, 64);
        float S4 = __shfl(Sy, base + 4, 64);
        float S5 = __shfl(Sy, base + 5, 64);
        y9  += h6 * (kR_RI * (S0 + S2) + kR_RH * S1);
        y10 += h6 * (r_dth * ((S3 + S4) + S5));
        y14 += h6 * (r_dth * (S4 + S5));

        float* sp = sole + (size_t)(s + 1) * 16;
        sp[own_idx] = ys;
        if (g == 0) sp[9]  = y9;
        if (g == 1) sp[10] = y10;
        if (g == 2) sp[14] = y14;
    }
}

// ---------------- monolithic ODE fallback (no precompute) ----------------
__device__ __forceinline__ void deriv16(const float* y, float ag, float pd,
                                        float invN, float r_dth, float* d)
{
    float inf = ag * y[0] * y[2] * invN;
    float det = kR_D * y[2];
    float t1  = kR_I * y[1];
    float omp = 1.0f - pd;
    float dq  = det * omp;
    float dp  = det * pd;
    float dq003 = dq * 0.03f;
    float dp003 = dp * 0.03f;
    d[0]  = -inf;
    d[1]  = inf - t1;
    d[2]  = t1 - det;
    d[3]  = dq * 0.8f  - kR_RI * y[3];
    d[4]  = dq003      - kR_RH * y[4];
    d[5]  = dq * 0.17f - kR_RI * y[5];
    d[6]  = dp * 0.8f  - r_dth * y[6];
    d[7]  = dp003      - r_dth * y[7];
    d[8]  = dp * 0.17f - r_dth * y[8];
    d[9]  = kR_RI * (y[3] + y[5]) + kR_RH * y[4];
    d[10] = r_dth * ((y[6] + y[7]) + y[8]);
    d[11] = det * 0.03f;
    d[12] = 0.25f * dq003 - kR_RV * y[12];
    d[13] = 0.25f * dp003 - r_dth * y[13];
    d[14] = r_dth * (y[7] + y[8]);
    d[15] = det * 0.2f;
}

__global__ __launch_bounds__(64)
void ode_kernel(const float* __restrict__ dnn, const float* __restrict__ pop,
                const float* __restrict__ ccn, const float* __restrict__ mort,
                float* __restrict__ sol)
{
    int e = blockIdx.x * 64 + threadIdx.x;
    const float* p = dnn + e * 23 + 11;
    float alpha = p[0], days = p[1], r_s = p[2], r_dth = p[3], p_dth = p[4];
    float r_dthdecay = p[5], k1p = p[6], k2p = p[7], jump = p[8], t_jump = p[9], stdn = p[10];

    float N = pop[e];
    float invN = 1.0f / N;
    float PopI = ccn[e];
    float PopD = floorf(mort[e] * PopI);
    float R0v  = (PopI - PopD > 5.0f * PopD) ? 5.0f * PopD : 0.0f;
    float PopCI = PopI - PopD - R0v;
    float DP = PopCI / 0.2f;

    float y[16];
    y[0]  = N - DP * (k1p + k2p) - R0v / 0.2f - PopD / 0.2f;
    y[1]  = DP * k1p;
    y[2]  = DP * k2p;
    y[3]  = (DP - PopCI) * (1.0f - p_dth);
    y[4]  = PopCI * 0.15f * (1.0f - p_dth);
    y[5]  = PopCI * 0.85f * (1.0f - p_dth);
    y[6]  = (DP - PopCI) * p_dth;
    y[7]  = PopCI * 0.15f * p_dth;
    y[8]  = PopCI * 0.85f * p_dth;
    y[9]  = R0v / 0.2f;
    y[10] = PopD / 0.2f;
    y[11] = PopCI * 0.15f;
    y[12] = PopCI * 0.15f * 0.25f * (1.0f - p_dth);
    y[13] = PopCI * 0.15f * 0.25f * p_dth;
    y[14] = PopD;
    y[15] = PopI;

    {
        float* sp = sol + (size_t)e * (TPTS * 16);
        #pragma unroll
        for (int i = 0; i < 16; ++i) sp[i] = y[i];
    }

    float rs20   = r_s * 0.05f;
    float rdd20  = r_dthdecay * 0.05f;
    float inv2s2 = 1.0f / (2.0f * stdn * stdn);
    float pconst = 0.6366197723675814f * (p_dth - 0.001f);

    float ag0, pd0;
    gampdt_eval(0.0f, alpha, days, rs20, jump, t_jump, inv2s2, pconst, rdd20, &ag0, &pd0);

    for (int s = 0; s < NSEG; ++s) {
        float t0 = (float)s;
        for (int j = 0; j < NSUB; ++j) {
            float agh, pdh, ag1, pd1;
            float t = t0 + (float)j * 0.1f;
            gampdt_eval(t + 0.05f, alpha, days, rs20, jump, t_jump, inv2s2, pconst, rdd20, &agh, &pdh);
            gampdt_eval(t + 0.1f,  alpha, days, rs20, jump, t_jump, inv2s2, pconst, rdd20, &ag1, &pd1);
            float d[16], acc[16], yt[16];
            deriv16(y, ag0, pd0, invN, r_dth, d);
            #pragma unroll
            for (int i = 0; i < 16; ++i) { acc[i] = d[i]; yt[i] = y[i] + 0.05f * d[i]; }
            deriv16(yt, agh, pdh, invN, r_dth, d);
            #pragma unroll
            for (int i = 0; i < 16; ++i) { acc[i] += 2.0f * d[i]; yt[i] = y[i] + 0.05f * d[i]; }
            deriv16(yt, agh, pdh, invN, r_dth, d);
            #pragma unroll
            for (int i = 0; i < 16; ++i) { acc[i] += 2.0f * d[i]; yt[i] = y[i] + 0.1f * d[i]; }
            deriv16(yt, ag1, pd1, invN, r_dth, d);
            #pragma unroll
            for (int i = 0; i < 16; ++i) y[i] += 0.016666668f * (acc[i] + d[i]);
            ag0 = ag1; pd0 = pd1;
        }
        float* sp = sol + (size_t)e * (TPTS * 16) + (size_t)(s + 1) * 16;
        #pragma unroll
        for (int i = 0; i < 16; ++i) sp[i] = y[i];
    }
}

// ---------------- host launch ----------------
extern "C" void kernel_launch(void* const* d_in, const int* in_sizes, int n_in,
                              void* d_out, int out_size, void* d_ws, size_t ws_size,
                              hipStream_t stream)
{
    const float* mi   = (const float*)d_in[0];
    const float* pop  = (const float*)d_in[1];
    const float* ccn  = (const float*)d_in[2];
    const float* mort = (const float*)d_in[3];
    const float* h0   = (const float*)d_in[4];
    const float* c0   = (const float*)d_in[5];
    const float* Wih0 = (const float*)d_in[6];
    const float* WihR = (const float*)d_in[7];
    const float* Whh  = (const float*)d_in[8];
    const float* bih  = (const float*)d_in[9];
    const float* bhh  = (const float*)d_in[10];
    const float* mW1  = (const float*)d_in[11];
    const float* mb1  = (const float*)d_in[12];
    const float* mW2  = (const float*)d_in[13];
    const float* mb2  = (const float*)d_in[14];
    const float* rW1  = (const float*)d_in[15];
    const float* rb1  = (const float*)d_in[16];
    const float* rW2  = (const float*)d_in[17];
    const float* rb2  = (const float*)d_in[18];
    const float* rng  = (const float*)d_in[19];
    const int*   ssp  = (const int*)d_in[20];

    float* out   = (float*)d_out;
    float* sol_o = out;                                   // 2048*90*16
    float* dnn_o = out + 2949120;                         // 2048*23
    float* ts_o  = out + 2949120 + 47104;                 // 2048*512
    float* raw_o = out + 2949120 + 47104 + 1048576;       // 2048*23

    float* ws  = (float*)d_ws;
    float* G   = ws;                    // 4,194,304 floats (NN scratch; DET4 aliases later)
    float* Z   = ws + 4194304;          // 2,097,152
    float* X0  = ws + 6291456;          // 1,048,576
    float* X1  = ws + 7340032;          // 1,048,576
    float* x0p = ws + 8388608;          // 65,536
    float* xmp = ws + 8454144;          // 65,536
    float* Wp0 = ws + 8519680;          // 65,536
    float* Wpm = ws + 8585216;          // 16,384   (end 8,601,600)
    __hip_bfloat16* Ab = (__hip_bfloat16*)(ws + 8601600);
    __hip_bfloat16* Wb = (__hip_bfloat16*)(ws + 8601600 + 3145728);
    float4* AG4  = (float4*)(ws + 8601600);          // aliases pack region (packs done first)
    float4* DET4 = (float4*)ws;                      // aliases G+Z+X0 (free after ro1/ro2)
    float*  G1   = ws + 15892480;                    // split-K partial C (4,194,304 fl)
    bool wsOK  = ws_size >= (size_t)15892480 * sizeof(float);
    bool wsOK2 = ws_size >= (size_t)(15892480 + 4194304) * sizeof(float);

    prep_pad<<<256, 256, 0, stream>>>(mi, pop, Wih0, mW1, x0p, xmp, Wp0, Wpm);

    gemm_dual<1><<<dim3(4, 16), 256, 0, stream>>>(xmp, 32, Wpm, 32, 32,
                                                  nullptr, 0, nullptr, 0, 0,
                                                  mb1, nullptr, G, 512, 512);

    if (wsOK) {
        // meta layer 2: K3 = 3*512, N=512 (no split)
        pack_pair<<<(2048 * 128 + 512 * 128 + 255) / 256, 256, 0, stream>>>(
            G, 512, 512, nullptr, 0, 0, Ab, 2048,
            mW2, 512, 512, nullptr, 0, 0, Wb, 512);
        gemm_mfma<1><<<dim3(4, 16, 1), 256, 0, stream>>>(Ab, Wb, 1536, 0, mb2, nullptr,
                                                         Z + 512, nullptr, 1024, 512);

        // 5-layer LSTM stack, split-K=2 when workspace allows
        for (int l = 0; l < 5; ++l) {
            const float* A1 = (l == 0) ? x0p : ((l & 1) ? X1 : X0);
            int          K1 = (l == 0) ? 32 : 512;
            const float* W1 = (l == 0) ? Wp0 : (WihR + (size_t)(l - 1) * 1048576);
            int Ks = K1 + 512, K3 = 3 * Ks, Kq = Ks >> 2;
            pack_pair<<<(2048 * Kq * 2 + 255) / 256, 256, 0, stream>>>(
                A1, K1, K1, h0 + (size_t)l * 1048576, 512, 512, Ab, 2048,
                W1, K1, K1, Whh + (size_t)l * 1048576, 512, 512, Wb, 2048);
            int kh = wsOK2 ? (((K3 / 2) + 31) / 32) * 32 : 0;
            gemm_mfma<0><<<dim3(16, 16, wsOK2 ? 2 : 1), 256, 0, stream>>>(
                Ab, Wb, K3, kh, bih + l * 2048, bhh + l * 2048, G, G1, 2048, 2048);
            float* xo  = (l == 4) ? Z : ((l & 1) ? X0 : X1);
            int    xol = (l == 4) ? 1024 : 512;
            lstm_gates<<<4096, 256, 0, stream>>>(G, wsOK2 ? G1 : nullptr,
                                                 c0 + (size_t)l * 1048576, xo, xol,
                                                 (l == 4) ? ts_o : nullptr);
        }

        // readout 1: K3 = 3*1024, N=1024 (no split)
        pack_pair<<<(2048 * 256 + 1024 * 256 + 255) / 256, 256, 0, stream>>>(
            Z, 1024, 1024, nullptr, 0, 0, Ab, 2048,
            rW1, 1024, 1024, nullptr, 0, 0, Wb, 1024);
        gemm_mfma<2><<<dim3(8, 16, 1), 256, 0, stream>>>(Ab, Wb, 3072, 0, rb1, nullptr,
                                                         G, nullptr, 1024, 1024);

        // readout 2 (N=23): fused GEMV + dnn
        gemv_ro2<<<512, 256, 0, stream>>>(G, rW2, rb2, ssp, rng, raw_o, dnn_o);

        gampdt4_kernel<<<(NSTEPS * 2048 + 255) / 256, 256, 0, stream>>>(dnn_o, pop, AG4);
        ode_core<<<32, 64, 0, stream>>>(dnn_o, pop, ccn, mort, AG4, DET4, sol_o);
        ode_decay<<<256, 64, 0, stream>>>(dnn_o, ccn, mort, AG4, DET4, sol_o);
    } else {
        gemm_dual<1><<<dim3(4, 16), 256, 0, stream>>>(G, 512, mW2, 512, 512,
                                                      nullptr, 0, nullptr, 0, 0,
                                                      mb2, nullptr, Z + 512, 1024, 512);
        for (int l = 0; l < 5; ++l) {
            const float* A1 = (l == 0) ? x0p : ((l & 1) ? X1 : X0);
            int          K1 = (l == 0) ? 32 : 512;
            const float* W1 = (l == 0) ? Wp0 : (WihR + (size_t)(l - 1) * 1048576);
            gemm_dual<0><<<dim3(16, 16), 256, 0, stream>>>(
                A1, K1, W1, K1, K1,
                h0 + (size_t)l * 1048576, 512, Whh + (size_t)l * 1048576, 512, 512,
                bih + l * 2048, bhh + l * 2048, G, 2048, 2048);
            float* xo  = (l == 4) ? Z : ((l & 1) ? X0 : X1);
            int    xol = (l == 4) ? 1024 : 512;
            lstm_gates<<<4096, 256, 0, stream>>>(G, nullptr, c0 + (size_t)l * 1048576, xo, xol,
                                                 (l == 4) ? ts_o : nullptr);
        }
        gemm_dual<2><<<dim3(8, 16), 256, 0, stream>>>(Z, 1024, rW1, 1024, 1024,
                                                      nullptr, 0, nullptr, 0, 0,
                                                      rb1, nullptr, G, 1024, 1024);
        gemm_dual<0><<<dim3(1, 16), 256, 0, stream>>>(G, 1024, rW2, 1024, 1024,
                                                      nullptr, 0, nullptr, 0, 0,
                                                      rb2, nullptr, raw_o, 23, 23);
        dnn_kernel<<<184, 256, 0, stream>>>(raw_o, ssp, rng, dnn_o);
        ode_kernel<<<32, 64, 0, stream>>>(dnn_o, pop, ccn, mort, sol_o);
    }
    (void)in_sizes; (void)n_in; (void)out_size;
}

// Round 10
// 724.119 us; speedup vs baseline: 2.9662x; 1.0339x over previous
//
#include <hip/hip_runtime.h>
#include <hip/hip_bf16.h>
#include <math.h>

// ---------------- problem constants ----------------
#define BATCH 2048
#define HID 512
#define TPTS 90
#define NSEG 89
#define NSUB 10
#define NSTEPS 890          // NSEG*NSUB global substeps

__device__ __constant__ const float kR_I  = 0.6931471805599453f / 5.0f;
__device__ __constant__ const float kR_D  = 0.6931471805599453f / 2.0f;
__device__ __constant__ const float kR_RI = 0.6931471805599453f / 10.0f;
__device__ __constant__ const float kR_RH = 0.6931471805599453f / 15.0f;
__device__ __constant__ const float kR_RV = 0.6931471805599453f / 10.0f;

typedef __attribute__((ext_vector_type(8))) short short8;
typedef __attribute__((ext_vector_type(4))) short short4v;
typedef __attribute__((ext_vector_type(4))) float float4v;

__device__ __forceinline__ float sigmoidf_(float x) { return 1.0f / (1.0f + expf(-x)); }

// ---------------- prep: pad K=30 operands to K=32, x = mi[:, :30]/pop ----------------
__global__ void prep_pad(const float* __restrict__ mi, const float* __restrict__ pop,
                         const float* __restrict__ Wih0, const float* __restrict__ mW1,
                         float* __restrict__ x0p, float* __restrict__ xmp,
                         float* __restrict__ Wp0, float* __restrict__ Wpm)
{
    int i = blockIdx.x * 256 + threadIdx.x;     // < 2048*32
    int r = i >> 5, c = i & 31;
    bool v = (c < 30);
    x0p[i] = v ? mi[r * 60 + c] / pop[r] : 0.0f;
    xmp[i] = v ? mi[r * 60 + 30 + c] : 0.0f;
    Wp0[i] = v ? Wih0[r * 30 + c] : 0.0f;
    if (r < 512) Wpm[i] = v ? mW1[r * 30 + c] : 0.0f;
}

// ---------------- hi/lo bf16 split + K-concat packing ----------------
// A-mode (wm=false): segments [hi | hi | lo];  W-mode (wm=true): [hi | lo | hi]
__device__ __forceinline__ void pack_quad(const float* __restrict__ s1, int ld1, int K1,
                                          const float* __restrict__ s2, int ld2, int K2,
                                          __hip_bfloat16* __restrict__ dst, int idx, bool wm)
{
    int Ks = K1 + K2, Kq = Ks >> 2;
    int r = idx / Kq, k4 = (idx - r * Kq) << 2;
    const float* srcp; int base, seg, kk;
    if (k4 < K1) { srcp = s1 + (size_t)r * ld1 + k4; base = 0; seg = K1; kk = k4; }
    else { kk = k4 - K1; srcp = s2 + (size_t)r * ld2 + kk; base = 3 * K1; seg = K2; }
    float4 x = *(const float4*)srcp;
    union { __hip_bfloat16 b[4]; short4v v; } H, L;
    H.b[0] = __float2bfloat16(x.x); H.b[1] = __float2bfloat16(x.y);
    H.b[2] = __float2bfloat16(x.z); H.b[3] = __float2bfloat16(x.w);
    L.b[0] = __float2bfloat16(x.x - __bfloat162float(H.b[0]));
    L.b[1] = __float2bfloat16(x.y - __bfloat162float(H.b[1]));
    L.b[2] = __float2bfloat16(x.z - __bfloat162float(H.b[2]));
    L.b[3] = __float2bfloat16(x.w - __bfloat162float(H.b[3]));
    __hip_bfloat16* d = dst + (size_t)r * (3 * Ks) + base;
    *(short4v*)(d + kk)           = H.v;
    *(short4v*)(d + seg + kk)     = wm ? L.v : H.v;
    *(short4v*)(d + 2 * seg + kk) = wm ? H.v : L.v;
}

// one launch packs both A (wm=false) and W (wm=true) operands of a layer
__global__ void pack_pair(const float* __restrict__ a1, int alda1, int aK1,
                          const float* __restrict__ a2, int alda2, int aK2,
                          __hip_bfloat16* __restrict__ da, int arows,
                          const float* __restrict__ w1, int wld1, int wK1,
                          const float* __restrict__ w2, int wld2, int wK2,
                          __hip_bfloat16* __restrict__ dw, int wrows)
{
    int aKq = (aK1 + aK2) >> 2, wKq = (wK1 + wK2) >> 2;
    int qa = arows * aKq;
    int idx = blockIdx.x * 256 + threadIdx.x;
    if (idx < qa) {
        pack_quad(a1, alda1, aK1, a2, alda2, aK2, da, idx, false);
    } else {
        idx -= qa;
        if (idx < wrows * wKq) pack_quad(w1, wld1, wK1, w2, wld2, wK2, dw, idx, true);
    }
}

// ---------------- bf16 MFMA GEMM-NT, 128x128 tile, register prefetch, split-K -------
// 256 thr = 4 waves, each wave a 64x64 quadrant via 4x4 mfma_f32_16x16x32_bf16.
// blockIdx.z selects the K-half: z=0 -> [0,kHalf) into Cp (+bias); z=1 ->
// [kHalf,K3) into Cp2 (no bias).  kHalf==0 means no split (full K into Cp).
// With split, ACT must be deferred to the consumer (use ACT=0).
template<int ACT>
__global__ __launch_bounds__(256, 2)
void gemm_mfma(const __hip_bfloat16* __restrict__ Ah,
               const __hip_bfloat16* __restrict__ Wh, int K3, int kHalf,
               const float* __restrict__ b1, const float* __restrict__ b2,
               float* __restrict__ Cp, float* __restrict__ Cp2, int ldc, int N)
{
    __shared__ __hip_bfloat16 As[128 * 32];
    __shared__ __hip_bfloat16 Ws[128 * 32];
    const int tid  = threadIdx.x;
    const int m0   = blockIdx.y * 128;
    const int n0   = blockIdx.x * 128;
    const int z    = blockIdx.z;
    const int k0   = z ? kHalf : 0;
    const int kLen = (kHalf == 0) ? K3 : (z ? (K3 - kHalf) : kHalf);
    float* C = z ? Cp2 : Cp;
    const int lane = tid & 63, wv = tid >> 6;
    const int mw   = (wv >> 1) * 64, nw = (wv & 1) * 64;
    const int l15  = lane & 15, quad = lane >> 4;
    const int sr   = tid >> 2;          // 0..63
    const int sc   = (tid & 3) * 8;     // {0,8,16,24}

    float4v acc[4][4];
    #pragma unroll
    for (int i = 0; i < 4; ++i)
        #pragma unroll
        for (int j = 0; j < 4; ++j)
            acc[i][j] = (float4v){0.0f, 0.0f, 0.0f, 0.0f};

    const __hip_bfloat16* pa0 = Ah + (size_t)(m0 + sr)      * K3 + k0 + sc;
    const __hip_bfloat16* pa1 = Ah + (size_t)(m0 + sr + 64) * K3 + k0 + sc;
    const __hip_bfloat16* pw0 = Wh + (size_t)(n0 + sr)      * K3 + k0 + sc;
    const __hip_bfloat16* pw1 = Wh + (size_t)(n0 + sr + 64) * K3 + k0 + sc;

    short8 a0 = *(const short8*)(pa0);
    short8 a1 = *(const short8*)(pa1);
    short8 w0 = *(const short8*)(pw0);
    short8 w1 = *(const short8*)(pw1);

    for (int kt = 0; kt < kLen; kt += 32) {
        __syncthreads();                 // previous iter's LDS reads done
        *(short8*)(As + sr * 32 + sc)        = a0;
        *(short8*)(As + (sr + 64) * 32 + sc) = a1;
        *(short8*)(Ws + sr * 32 + sc)        = w0;
        *(short8*)(Ws + (sr + 64) * 32 + sc) = w1;
        __syncthreads();

        // prefetch next k-tile into registers; overlaps ds_read + MFMA below
        int kn = kt + 32;
        if (kn < kLen) {
            a0 = *(const short8*)(pa0 + kn);
            a1 = *(const short8*)(pa1 + kn);
            w0 = *(const short8*)(pw0 + kn);
            w1 = *(const short8*)(pw1 + kn);
        }

        short8 af[4], bf[4];
        #pragma unroll
        for (int t = 0; t < 4; ++t) {
            af[t] = *(const short8*)(As + (mw + t * 16 + l15) * 32 + quad * 8);
            bf[t] = *(const short8*)(Ws + (nw + t * 16 + l15) * 32 + quad * 8);
        }
        #pragma unroll
        for (int i = 0; i < 4; ++i)
            #pragma unroll
            for (int j = 0; j < 4; ++j)
                acc[i][j] = __builtin_amdgcn_mfma_f32_16x16x32_bf16(af[i], bf[j], acc[i][j], 0, 0, 0);
    }

    // epilogue: C/D layout col = lane&15, row = quad*4 + reg
    #pragma unroll
    for (int j = 0; j < 4; ++j) {
        int col = n0 + nw + j * 16 + l15;
        float bias = z ? 0.0f : (b1[col] + (b2 ? b2[col] : 0.0f));
        #pragma unroll
        for (int i = 0; i < 4; ++i) {
            #pragma unroll
            for (int r = 0; r < 4; ++r) {
                int row = m0 + mw + i * 16 + quad * 4 + r;
                float v = acc[i][j][r] + bias;
                if (ACT == 1)      v = fmaxf(v, 0.0f);
                else if (ACT == 2) v = tanhf(v);
                C[(size_t)row * ldc + col] = v;
            }
        }
    }
}

// ---------------- fp32 tiled GEMM-NT (meta1 + fallback) ----------------
template<int ACT>
__global__ __launch_bounds__(256)
void gemm_dual(const float* __restrict__ A1, int lda1,
               const float* __restrict__ W1, int ldw1, int K1,
               const float* __restrict__ A2, int lda2,
               const float* __restrict__ W2, int ldw2, int K2,
               const float* __restrict__ b1p, const float* __restrict__ b2p,
               float* __restrict__ Cp, int ldc, int N)
{
    __shared__ float As[8][128];
    __shared__ float Ws[8][128];
    const int tid  = threadIdx.x;
    const int m0   = blockIdx.y * 128;
    const int n0   = blockIdx.x * 128;
    const int tm   = tid >> 4;
    const int tn   = tid & 15;
    const int lrow = tid >> 1;
    const int lkh  = (tid & 1) << 2;
    const int wrow = n0 + lrow;
    const int Ktot = K1 + K2;

    float acc[8][8];
    #pragma unroll
    for (int i = 0; i < 8; ++i)
        #pragma unroll
        for (int j = 0; j < 8; ++j) acc[i][j] = 0.0f;

    float4 av = *(const float4*)(A1 + (size_t)(m0 + lrow) * lda1 + lkh);
    float4 wv = make_float4(0.0f, 0.0f, 0.0f, 0.0f);
    if (wrow < N) wv = *(const float4*)(W1 + (size_t)wrow * ldw1 + lkh);

    for (int kt = 0; kt < Ktot; kt += 8) {
        __syncthreads();
        As[lkh + 0][lrow] = av.x; As[lkh + 1][lrow] = av.y;
        As[lkh + 2][lrow] = av.z; As[lkh + 3][lrow] = av.w;
        Ws[lkh + 0][lrow] = wv.x; Ws[lkh + 1][lrow] = wv.y;
        Ws[lkh + 2][lrow] = wv.z; Ws[lkh + 3][lrow] = wv.w;
        __syncthreads();

        int kn = kt + 8;
        float4 avn = make_float4(0.0f, 0.0f, 0.0f, 0.0f);
        float4 wvn = avn;
        if (kn < Ktot) {
            if (kn < K1) {
                avn = *(const float4*)(A1 + (size_t)(m0 + lrow) * lda1 + kn + lkh);
                if (wrow < N) wvn = *(const float4*)(W1 + (size_t)wrow * ldw1 + kn + lkh);
            } else {
                int k2 = kn - K1;
                avn = *(const float4*)(A2 + (size_t)(m0 + lrow) * lda2 + k2 + lkh);
                if (wrow < N) wvn = *(const float4*)(W2 + (size_t)wrow * ldw2 + k2 + lkh);
            }
        }

        #pragma unroll
        for (int kk = 0; kk < 8; ++kk) {
            float af[8], wf[8];
            #pragma unroll
            for (int i = 0; i < 4; ++i) {
                af[i]     = As[kk][tm * 8 + i];
                af[i + 4] = As[kk][tm * 8 + 4 + i];
                wf[i]     = Ws[kk][tn * 4 + i];
                wf[i + 4] = Ws[kk][64 + tn * 4 + i];
            }
            #pragma unroll
            for (int i = 0; i < 8; ++i)
                #pragma unroll
                for (int j = 0; j < 8; ++j)
                    acc[i][j] += af[i] * wf[j];
        }
        av = avn; wv = wvn;
    }

    #pragma unroll
    for (int j = 0; j < 8; ++j) {
        int col = n0 + ((j < 4) ? (tn * 4 + j) : (64 + tn * 4 + (j - 4)));
        if (col >= N) continue;
        float bias = b1p[col] + (b2p ? b2p[col] : 0.0f);
        #pragma unroll
        for (int i = 0; i < 8; ++i) {
            int rrow = m0 + tm * 8 + i;
            float v = acc[i][j] + bias;
            if (ACT == 1) v = fmaxf(v, 0.0f);
            else if (ACT == 2) v = tanhf(v);
            Cp[(size_t)rrow * ldc + col] = v;
        }
    }
}

// ---------------- fused ro2 GEMV + dnn ----------------
// If Ap != null: A holds a split-K partial; z = tanh(A + Ap) elementwise first.
__global__ __launch_bounds__(256)
void gemv_ro2(const float* __restrict__ A, const float* __restrict__ Ap,
              const float* __restrict__ W, const float* __restrict__ b,
              const int* __restrict__ ssp, const float* __restrict__ rng,
              float* __restrict__ raw, float* __restrict__ dnn)
{
    int m    = blockIdx.x * 4 + (threadIdx.x >> 6);
    int lane = threadIdx.x & 63;
    const float* ar = A + (size_t)m * 1024 + lane * 4;
    float4 a0 = *(const float4*)(ar);
    float4 a1 = *(const float4*)(ar + 256);
    float4 a2 = *(const float4*)(ar + 512);
    float4 a3 = *(const float4*)(ar + 768);
    if (Ap) {
        const float* pr = Ap + (size_t)m * 1024 + lane * 4;
        float4 p0 = *(const float4*)(pr);
        float4 p1 = *(const float4*)(pr + 256);
        float4 p2 = *(const float4*)(pr + 512);
        float4 p3 = *(const float4*)(pr + 768);
        a0.x = tanhf(a0.x + p0.x); a0.y = tanhf(a0.y + p0.y);
        a0.z = tanhf(a0.z + p0.z); a0.w = tanhf(a0.w + p0.w);
        a1.x = tanhf(a1.x + p1.x); a1.y = tanhf(a1.y + p1.y);
        a1.z = tanhf(a1.z + p1.z); a1.w = tanhf(a1.w + p1.w);
        a2.x = tanhf(a2.x + p2.x); a2.y = tanhf(a2.y + p2.y);
        a2.z = tanhf(a2.z + p2.z); a2.w = tanhf(a2.w + p2.w);
        a3.x = tanhf(a3.x + p3.x); a3.y = tanhf(a3.y + p3.y);
        a3.z = tanhf(a3.z + p3.z); a3.w = tanhf(a3.w + p3.w);
    }
    int v = *ssp;
    float ss = (v > 100000 || v < 0) ? __int_as_float(v) : (float)v;
    #pragma unroll 1
    for (int n = 0; n < 23; ++n) {
        const float* wr = W + (size_t)n * 1024 + lane * 4;
        float4 w0 = *(const float4*)(wr);
        float4 w1 = *(const float4*)(wr + 256);
        float4 w2 = *(const float4*)(wr + 512);
        float4 w3 = *(const float4*)(wr + 768);
        float s = a0.x * w0.x + a0.y * w0.y + a0.z * w0.z + a0.w * w0.w
                + a1.x * w1.x + a1.y * w1.y + a1.z * w1.z + a1.w * w1.w
                + a2.x * w2.x + a2.y * w2.y + a2.z * w2.z + a2.w * w2.w
                + a3.x * w3.x + a3.y * w3.y + a3.z * w3.z + a3.w * w3.w;
        #pragma unroll
        for (int o = 32; o > 0; o >>= 1) s += __shfl_xor(s, o, 64);
        if (lane == 0) {
            float r2 = s + b[n];
            raw[m * 23 + n] = r2;
            dnn[m * 23 + n] = sigmoidf_(r2 * ss) * rng[n];
        }
    }
}

// ---------------- LSTM gate nonlinearity (sums split-K partials) ----------------
__global__ void lstm_gates(const float* __restrict__ G0, const float* __restrict__ G1,
                           const float* __restrict__ c0l,
                           float* __restrict__ xout, int xld, float* __restrict__ ts)
{
    int i = blockIdx.x * 256 + threadIdx.x;     // < 2048*512
    int m = i >> 9, h = i & 511;
    const float* g = G0 + (size_t)m * 2048 + h;
    float gi = g[0], gf = g[512], gg = g[1024], go = g[1536];
    if (G1) {
        const float* g2 = G1 + (size_t)m * 2048 + h;
        gi += g2[0]; gf += g2[512]; gg += g2[1024]; go += g2[1536];
    }
    float c = sigmoidf_(gf) * c0l[i] + sigmoidf_(gi) * tanhf(gg);
    float x = sigmoidf_(go) * tanhf(c);
    xout[(size_t)m * xld + h] = x;
    if (ts) ts[i] = x;
}

// ---------------- dnn (fallback path only) ----------------
__global__ void dnn_kernel(const float* __restrict__ raw, const int* __restrict__ ssp,
                           const float* __restrict__ rng, float* __restrict__ dnn)
{
    int i = blockIdx.x * 256 + threadIdx.x;
    if (i >= 2048 * 23) return;
    int c = i % 23;
    int v = *ssp;
    float ss = (v > 100000 || v < 0) ? __int_as_float(v) : (float)v;
    dnn[i] = sigmoidf_(raw[i] * ss) * rng[c];
}

// ---------------- gam/pdt evaluation ----------------
__device__ __forceinline__ void gampdt_eval(float t, float alpha, float days, float rs20,
                                            float jump, float t_jump, float inv2s2,
                                            float pconst, float rdd20, float* ag, float* pd)
{
    float dtj = t - t_jump;
    float g = 0.6366197723675814f * atanf((days - t) * rs20) + 1.0f + jump * expf(-(dtj * dtj) * inv2s2);
    *ag = alpha * g;
    *pd = pconst * (atanf(-t * rdd20) + 1.5707963267948966f) + 0.001f;
}

// pack (ag_half*invN, pd_half, ag_end*invN, pd_end) per (substep k, chain e)
__global__ void gampdt4_kernel(const float* __restrict__ dnn, const float* __restrict__ pop,
                               float4* __restrict__ ag4)
{
    int idx = blockIdx.x * 256 + threadIdx.x;
    if (idx >= NSTEPS * 2048) return;
    int e = idx & 2047;
    int k = idx >> 11;
    int s = k / 10, j = k - s * 10;
    const float* p = dnn + e * 23 + 11;
    float alpha = p[0], days = p[1], r_s = p[2], p_dth = p[4], r_dthdecay = p[5];
    float jump = p[8], t_jump = p[9], stdn = p[10];
    float invN = 1.0f / pop[e];
    float rs20   = r_s * 0.05f;
    float rdd20  = r_dthdecay * 0.05f;
    float inv2s2 = 1.0f / (2.0f * stdn * stdn);
    float pconst = 0.6366197723675814f * (p_dth - 0.001f);
    float t = (float)s + (float)j * 0.1f;
    float agh, pdh, ag1, pd1;
    gampdt_eval(t + 0.05f, alpha, days, rs20, jump, t_jump, inv2s2, pconst, rdd20, &agh, &pdh);
    gampdt_eval(t + 0.1f,  alpha, days, rs20, jump, t_jump, inv2s2, pconst, rdd20, &ag1, &pd1);
    ag4[idx] = make_float4(agh * invN, pdh, ag1 * invN, pd1);
}

// ---------------- ODE pass 1: nonlinear core (S,E,I) + det stream + y11/y15 ----------
// det4 values for a whole segment are buffered in registers and stored at the
// segment boundary: the per-substep store's source registers are otherwise
// overwritten next substep, forcing an exposed s_waitcnt on the in-flight store.
__global__ __launch_bounds__(64)
void ode_core(const float* __restrict__ dnn, const float* __restrict__ pop,
              const float* __restrict__ ccn, const float* __restrict__ mort,
              const float4* __restrict__ ag4, float4* __restrict__ det4,
              float* __restrict__ sol)
{
    int e = blockIdx.x * 64 + threadIdx.x;      // 0..2047
    const float* p = dnn + e * 23 + 11;
    float alpha = p[0], days = p[1], r_s = p[2], k1p = p[6], k2p = p[7];
    float jump = p[8], t_jump = p[9], stdn = p[10], p_dth = p[4], rdd = p[5];

    float N = pop[e];
    float invN = 1.0f / N;
    float PopI = ccn[e];
    float PopD = floorf(mort[e] * PopI);
    float R0v  = (PopI - PopD > 5.0f * PopD) ? 5.0f * PopD : 0.0f;
    float PopCI = PopI - PopD - R0v;
    float DP = PopCI / 0.2f;

    float y0 = N - DP * (k1p + k2p) - R0v / 0.2f - PopD / 0.2f;
    float y1 = DP * k1p;
    float y2 = DP * k2p;
    float y11 = PopCI * 0.15f;
    float y15 = PopI;

    float* sole = sol + (size_t)e * (TPTS * 16);
    sole[0] = y0; sole[1] = y1; sole[2] = y2; sole[11] = y11; sole[15] = y15;

    float rs20   = r_s * 0.05f;
    float rdd20  = rdd * 0.05f;
    float inv2s2 = 1.0f / (2.0f * stdn * stdn);
    float pconst = 0.6366197723675814f * (p_dth - 0.001f);
    float ag0, pd0;
    gampdt_eval(0.0f, alpha, days, rs20, jump, t_jump, inv2s2, pconst, rdd20, &ag0, &pd0);
    float agI = ag0 * invN;

    float4 cv[10];
    #pragma unroll
    for (int j = 0; j < 10; ++j) cv[j] = ag4[(size_t)j * 2048 + e];

    const float h6 = 0.016666668f;
    for (int s = 0; s < NSEG; ++s) {
        float Sdet = 0.0f;
        float4 db[10];                          // segment det buffer (register ring)
        #pragma unroll
        for (int j = 0; j < 10; ++j) {
            float agh = cv[j].x, ag1 = cv[j].z;     // already * invN
            int kn = (s + 1) * 10 + j;
            if (kn >= NSTEPS) kn = NSTEPS - 1;
            cv[j] = ag4[(size_t)kn * 2048 + e];

            float det1 = kR_D * y2;
            float t1   = kR_I * y1;
            float inf  = agI * y0 * y2;
            float d1 = inf - t1, d2 = t1 - det1;
            float a0 = -inf, a1 = d1, a2 = d2;
            float z0 = y0 - 0.05f * inf, z1 = y1 + 0.05f * d1, z2 = y2 + 0.05f * d2;
            float det2 = kR_D * z2; t1 = kR_I * z1; inf = agh * z0 * z2;
            d1 = inf - t1; d2 = t1 - det2;
            a0 -= 2.0f * inf; a1 += 2.0f * d1; a2 += 2.0f * d2;
            z0 = y0 - 0.05f * inf; z1 = y1 + 0.05f * d1; z2 = y2 + 0.05f * d2;
            float det3 = kR_D * z2; t1 = kR_I * z1; inf = agh * z0 * z2;
            d1 = inf - t1; d2 = t1 - det3;
            a0 -= 2.0f * inf; a1 += 2.0f * d1; a2 += 2.0f * d2;
            z0 = y0 - 0.1f * inf; z1 = y1 + 0.1f * d1; z2 = y2 + 0.1f * d2;
            float det4v = kR_D * z2; t1 = kR_I * z1; inf = ag1 * z0 * z2;
            d1 = inf - t1; d2 = t1 - det4v;
            a0 -= inf; a1 += d1; a2 += d2;

            y0 += h6 * a0; y1 += h6 * a1; y2 += h6 * a2;
            float Wd = det1;
            Wd += 2.0f * det2; Wd += 2.0f * det3; Wd += det4v;
            Sdet += Wd;
            db[j] = make_float4(det1, det2, det3, det4v);
            agI = ag1;
        }
        // batched stores: 10 in flight, sources not reused until next segment
        #pragma unroll
        for (int j = 0; j < 10; ++j)
            det4[(size_t)(s * 10 + j) * 2048 + e] = db[j];
        y11 += h6 * (0.03f * Sdet);
        y15 += h6 * (0.2f * Sdet);
        float* sp = sole + (size_t)(s + 1) * 16;
        sp[0] = y0; sp[1] = y1; sp[2] = y2; sp[11] = y11; sp[15] = y15;
    }
}

// ---------------- ODE pass 2: 8 linear decay states/chain + integrals ------------
__global__ __launch_bounds__(64)
void ode_decay(const float* __restrict__ dnn, const float* __restrict__ ccn,
               const float* __restrict__ mort, const float4* __restrict__ ag4,
               const float4* __restrict__ det4, float* __restrict__ sol)
{
    const int t  = blockIdx.x * 64 + threadIdx.x;   // 0..16383
    const int e  = t >> 3;
    const int g  = t & 7;
    const int lane = threadIdx.x & 63;
    const int base = lane & ~7;

    const float* p = dnn + e * 23 + 11;
    float r_dth = p[3], p_dth = p[4];

    float PopI = ccn[e];
    float PopD = floorf(mort[e] * PopI);
    float R0v  = (PopI - PopD > 5.0f * PopD) ? 5.0f * PopD : 0.0f;
    float PopCI = PopI - PopD - R0v;
    float DP = PopCI / 0.2f;
    float ompd = 1.0f - p_dth;

    float iy3  = (DP - PopCI) * ompd;
    float iy4  = PopCI * 0.15f * ompd;
    float iy5  = PopCI * 0.85f * ompd;
    float iy6  = (DP - PopCI) * p_dth;
    float iy7  = PopCI * 0.15f * p_dth;
    float iy8  = PopCI * 0.85f * p_dth;
    float iy12 = PopCI * 0.15f * 0.25f * ompd;
    float iy13 = PopCI * 0.15f * 0.25f * p_dth;

    float ha = (g == 0) ? iy3 : (g == 1) ? iy4 : (g == 2) ? iy5 : iy6;
    float hb = (g == 4) ? iy7 : (g == 5) ? iy8 : (g == 6) ? iy12 : iy13;
    float ys = (g < 4) ? ha : hb;
    float c1 = (g == 0) ? 0.8f : (g == 1) ? 0.03f : (g == 2) ? 0.17f : (g == 6) ? 0.0075f : 0.0f;
    float c2 = (g == 3) ? 0.8f : (g == 4) ? 0.03f : (g == 5) ? 0.17f : (g == 7) ? 0.0075f : 0.0f;
    float rr = (g == 0 || g == 2) ? kR_RI : (g == 1) ? kR_RH : (g == 6) ? kR_RV : r_dth;
    int own_idx = (g < 4) ? ((g < 2) ? (g == 0 ? 3 : 4) : (g == 2 ? 5 : 6))
                          : ((g < 6) ? (g == 4 ? 7 : 8) : (g == 6 ? 12 : 13));

    float y9  = R0v / 0.2f;
    float y10 = PopD / 0.2f;
    float y14 = PopD;

    float* sole = sol + (size_t)e * (TPTS * 16);
    sole[own_idx] = ys;
    if (g == 0) sole[9]  = y9;
    if (g == 1) sole[10] = y10;
    if (g == 2) sole[14] = y14;

    float pconst = 0.6366197723675814f * (p_dth - 0.001f);
    float pd0 = pconst * 1.5707963267948966f + 0.001f;
    float u0 = c1 * (1.0f - pd0) + c2 * pd0;

    float4 cvd[10], cva[10];
    #pragma unroll
    for (int j = 0; j < 10; ++j) {
        cvd[j] = det4[(size_t)j * 2048 + e];
        cva[j] = ag4[(size_t)j * 2048 + e];
    }

    const float h6 = 0.016666668f;
    for (int s = 0; s < NSEG; ++s) {
        float Sy = 0.0f;
        #pragma unroll
        for (int j = 0; j < 10; ++j) {
            float4 dd = cvd[j];
            float pdh = cva[j].y, pd1 = cva[j].w;
            int kn = (s + 1) * 10 + j;
            if (kn >= NSTEPS) kn = NSTEPS - 1;
            cvd[j] = det4[(size_t)kn * 2048 + e];
            cva[j] = ag4[(size_t)kn * 2048 + e];

            float uh = c1 * (1.0f - pdh) + c2 * pdh;
            float u1 = c1 * (1.0f - pd1) + c2 * pd1;
            float k1v = dd.x * u0 - rr * ys;
            float zs1 = ys + 0.05f * k1v;
            float k2v = dd.y * uh - rr * zs1;
            float zs2 = ys + 0.05f * k2v;
            float k3v = dd.z * uh - rr * zs2;
            float zs3 = ys + 0.1f * k3v;
            float k4v = dd.w * u1 - rr * zs3;
            float ka = k1v + 2.0f * (k2v + k3v) + k4v;
            Sy += ys + 2.0f * (zs1 + zs2) + zs3;
            ys += h6 * ka;
            u0 = u1;
        }
        float S0 = __shfl(Sy, base + 0, 64);
        float S1 = __shfl(Sy, base + 1, 64);
        float S2 = __shfl(Sy, base + 2, 64);
        float S3 = __shfl(Sy, base + 3, 64);
        float S4 = __shfl(Sy, base + 4, 64);
        float S5 = __shfl(Sy, base + 5, 64);
        y9  += h6 * (kR_RI * (S0 + S2) + kR_RH * S1);
        y10 += h6 * (r_dth * ((S3 + S4) + S5));
        y14 += h6 * (r_dth * (S4 + S5));

        float* sp = sole + (size_t)(s + 1) * 16;
        sp[own_idx] = ys;
        if (g == 0) sp[9]  = y9;
        if (g == 1) sp[10] = y10;
        if (g == 2) sp[14] = y14;
    }
}

// ---------------- monolithic ODE fallback (no precompute) ----------------
__device__ __forceinline__ void deriv16(const float* y, float ag, float pd,
                                        float invN, float r_dth, float* d)
{
    float inf = ag * y[0] * y[2] * invN;
    float det = kR_D * y[2];
    float t1  = kR_I * y[1];
    float omp = 1.0f - pd;
    float dq  = det * omp;
    float dp  = det * pd;
    float dq003 = dq * 0.03f;
    float dp003 = dp * 0.03f;
    d[0]  = -inf;
    d[1]  = inf - t1;
    d[2]  = t1 - det;
    d[3]  = dq * 0.8f  - kR_RI * y[3];
    d[4]  = dq003      - kR_RH * y[4];
    d[5]  = dq * 0.17f - kR_RI * y[5];
    d[6]  = dp * 0.8f  - r_dth * y[6];
    d[7]  = dp003      - r_dth * y[7];
    d[8]  = dp * 0.17f - r_dth * y[8];
    d[9]  = kR_RI * (y[3] + y[5]) + kR_RH * y[4];
    d[10] = r_dth * ((y[6] + y[7]) + y[8]);
    d[11] = det * 0.03f;
    d[12] = 0.25f * dq003 - kR_RV * y[12];
    d[13] = 0.25f * dp003 - r_dth * y[13];
    d[14] = r_dth * (y[7] + y[8]);
    d[15] = det * 0.2f;
}

__global__ __launch_bounds__(64)
void ode_kernel(const float* __restrict__ dnn, const float* __restrict__ pop,
                const float* __restrict__ ccn, const float* __restrict__ mort,
                float* __restrict__ sol)
{
    int e = blockIdx.x * 64 + threadIdx.x;
    const float* p = dnn + e * 23 + 11;
    float alpha = p[0], days = p[1], r_s = p[2], r_dth = p[3], p_dth = p[4];
    float r_dthdecay = p[5], k1p = p[6], k2p = p[7], jump = p[8], t_jump = p[9], stdn = p[10];

    float N = pop[e];
    float invN = 1.0f / N;
    float PopI = ccn[e];
    float PopD = floorf(mort[e] * PopI);
    float R0v  = (PopI - PopD > 5.0f * PopD) ? 5.0f * PopD : 0.0f;
    float PopCI = PopI - PopD - R0v;
    float DP = PopCI / 0.2f;

    float y[16];
    y[0]  = N - DP * (k1p + k2p) - R0v / 0.2f - PopD / 0.2f;
    y[1]  = DP * k1p;
    y[2]  = DP * k2p;
    y[3]  = (DP - PopCI) * (1.0f - p_dth);
    y[4]  = PopCI * 0.15f * (1.0f - p_dth);
    y[5]  = PopCI * 0.85f * (1.0f - p_dth);
    y[6]  = (DP - PopCI) * p_dth;
    y[7]  = PopCI * 0.15f * p_dth;
    y[8]  = PopCI * 0.85f * p_dth;
    y[9]  = R0v / 0.2f;
    y[10] = PopD / 0.2f;
    y[11] = PopCI * 0.15f;
    y[12] = PopCI * 0.15f * 0.25f * (1.0f - p_dth);
    y[13] = PopCI * 0.15f * 0.25f * p_dth;
    y[14] = PopD;
    y[15] = PopI;

    {
        float* sp = sol + (size_t)e * (TPTS * 16);
        #pragma unroll
        for (int i = 0; i < 16; ++i) sp[i] = y[i];
    }

    float rs20   = r_s * 0.05f;
    float rdd20  = r_dthdecay * 0.05f;
    float inv2s2 = 1.0f / (2.0f * stdn * stdn);
    float pconst = 0.6366197723675814f * (p_dth - 0.001f);

    float ag0, pd0;
    gampdt_eval(0.0f, alpha, days, rs20, jump, t_jump, inv2s2, pconst, rdd20, &ag0, &pd0);

    for (int s = 0; s < NSEG; ++s) {
        float t0 = (float)s;
        for (int j = 0; j < NSUB; ++j) {
            float agh, pdh, ag1, pd1;
            float t = t0 + (float)j * 0.1f;
            gampdt_eval(t + 0.05f, alpha, days, rs20, jump, t_jump, inv2s2, pconst, rdd20, &agh, &pdh);
            gampdt_eval(t + 0.1f,  alpha, days, rs20, jump, t_jump, inv2s2, pconst, rdd20, &ag1, &pd1);
            float d[16], acc[16], yt[16];
            deriv16(y, ag0, pd0, invN, r_dth, d);
            #pragma unroll
            for (int i = 0; i < 16; ++i) { acc[i] = d[i]; yt[i] = y[i] + 0.05f * d[i]; }
            deriv16(yt, agh, pdh, invN, r_dth, d);
            #pragma unroll
            for (int i = 0; i < 16; ++i) { acc[i] += 2.0f * d[i]; yt[i] = y[i] + 0.05f * d[i]; }
            deriv16(yt, agh, pdh, invN, r_dth, d);
            #pragma unroll
            for (int i = 0; i < 16; ++i) { acc[i] += 2.0f * d[i]; yt[i] = y[i] + 0.1f * d[i]; }
            deriv16(yt, ag1, pd1, invN, r_dth, d);
            #pragma unroll
            for (int i = 0; i < 16; ++i) y[i] += 0.016666668f * (acc[i] + d[i]);
            ag0 = ag1; pd0 = pd1;
        }
        float* sp = sol + (size_t)e * (TPTS * 16) + (size_t)(s + 1) * 16;
        #pragma unroll
        for (int i = 0; i < 16; ++i) sp[i] = y[i];
    }
}

// ---------------- host launch ----------------
extern "C" void kernel_launch(void* const* d_in, const int* in_sizes, int n_in,
                              void* d_out, int out_size, void* d_ws, size_t ws_size,
                              hipStream_t stream)
{
    const float* mi   = (const float*)d_in[0];
    const float* pop  = (const float*)d_in[1];
    const float* ccn  = (const float*)d_in[2];
    const float* mort = (const float*)d_in[3];
    const float* h0   = (const float*)d_in[4];
    const float* c0   = (const float*)d_in[5];
    const float* Wih0 = (const float*)d_in[6];
    const float* WihR = (const float*)d_in[7];
    const float* Whh  = (const float*)d_in[8];
    const float* bih  = (const float*)d_in[9];
    const float* bhh  = (const float*)d_in[10];
    const float* mW1  = (const float*)d_in[11];
    const float* mb1  = (const float*)d_in[12];
    const float* mW2  = (const float*)d_in[13];
    const float* mb2  = (const float*)d_in[14];
    const float* rW1  = (const float*)d_in[15];
    const float* rb1  = (const float*)d_in[16];
    const float* rW2  = (const float*)d_in[17];
    const float* rb2  = (const float*)d_in[18];
    const float* rng  = (const float*)d_in[19];
    const int*   ssp  = (const int*)d_in[20];

    float* out   = (float*)d_out;
    float* sol_o = out;                                   // 2048*90*16
    float* dnn_o = out + 2949120;                         // 2048*23
    float* ts_o  = out + 2949120 + 47104;                 // 2048*512
    float* raw_o = out + 2949120 + 47104 + 1048576;       // 2048*23

    float* ws  = (float*)d_ws;
    float* G   = ws;                    // 4,194,304 floats (NN scratch; DET4 aliases later)
    float* Z   = ws + 4194304;          // 2,097,152
    float* X0  = ws + 6291456;          // 1,048,576
    float* X1  = ws + 7340032;          // 1,048,576
    float* x0p = ws + 8388608;          // 65,536
    float* xmp = ws + 8454144;          // 65,536
    float* Wp0 = ws + 8519680;          // 65,536
    float* Wpm = ws + 8585216;          // 16,384   (end 8,601,600)
    __hip_bfloat16* Ab = (__hip_bfloat16*)(ws + 8601600);
    __hip_bfloat16* Wb = (__hip_bfloat16*)(ws + 8601600 + 3145728);
    float4* AG4  = (float4*)(ws + 8601600);          // aliases pack region (packs done first)
    float4* DET4 = (float4*)ws;                      // aliases G+Z+X0 (free after ro1/ro2)
    float*  G1   = ws + 15892480;                    // split-K partial C (4,194,304 fl)
    bool wsOK  = ws_size >= (size_t)15892480 * sizeof(float);
    bool wsOK2 = ws_size >= (size_t)(15892480 + 4194304) * sizeof(float);

    prep_pad<<<256, 256, 0, stream>>>(mi, pop, Wih0, mW1, x0p, xmp, Wp0, Wpm);

    gemm_dual<1><<<dim3(4, 16), 256, 0, stream>>>(xmp, 32, Wpm, 32, 32,
                                                  nullptr, 0, nullptr, 0, 0,
                                                  mb1, nullptr, G, 512, 512);

    if (wsOK) {
        // meta layer 2: K3 = 3*512, N=512 (no split)
        pack_pair<<<(2048 * 128 + 512 * 128 + 255) / 256, 256, 0, stream>>>(
            G, 512, 512, nullptr, 0, 0, Ab, 2048,
            mW2, 512, 512, nullptr, 0, 0, Wb, 512);
        gemm_mfma<1><<<dim3(4, 16, 1), 256, 0, stream>>>(Ab, Wb, 1536, 0, mb2, nullptr,
                                                         Z + 512, nullptr, 1024, 512);

        // 5-layer LSTM stack, split-K=2 when workspace allows
        for (int l = 0; l < 5; ++l) {
            const float* A1 = (l == 0) ? x0p : ((l & 1) ? X1 : X0);
            int          K1 = (l == 0) ? 32 : 512;
            const float* W1 = (l == 0) ? Wp0 : (WihR + (size_t)(l - 1) * 1048576);
            int Ks = K1 + 512, K3 = 3 * Ks, Kq = Ks >> 2;
            pack_pair<<<(2048 * Kq * 2 + 255) / 256, 256, 0, stream>>>(
                A1, K1, K1, h0 + (size_t)l * 1048576, 512, 512, Ab, 2048,
                W1, K1, K1, Whh + (size_t)l * 1048576, 512, 512, Wb, 2048);
            int kh = wsOK2 ? (((K3 / 2) + 31) / 32) * 32 : 0;
            gemm_mfma<0><<<dim3(16, 16, wsOK2 ? 2 : 1), 256, 0, stream>>>(
                Ab, Wb, K3, kh, bih + l * 2048, bhh + l * 2048, G, G1, 2048, 2048);
            float* xo  = (l == 4) ? Z : ((l & 1) ? X0 : X1);
            int    xol = (l == 4) ? 1024 : 512;
            lstm_gates<<<4096, 256, 0, stream>>>(G, wsOK2 ? G1 : nullptr,
                                                 c0 + (size_t)l * 1048576, xo, xol,
                                                 (l == 4) ? ts_o : nullptr);
        }

        // readout 1: K3 = 3*1024, N=1024; split-K=2 with tanh deferred to gemv_ro2
        pack_pair<<<(2048 * 256 + 1024 * 256 + 255) / 256, 256, 0, stream>>>(
            Z, 1024, 1024, nullptr, 0, 0, Ab, 2048,
            rW1, 1024, 1024, nullptr, 0, 0, Wb, 1024);
        if (wsOK2) {
            gemm_mfma<0><<<dim3(8, 16, 2), 256, 0, stream>>>(Ab, Wb, 3072, 1536, rb1, nullptr,
                                                             G, G1, 1024, 1024);
            gemv_ro2<<<512, 256, 0, stream>>>(G, G1, rW2, rb2, ssp, rng, raw_o, dnn_o);
        } else {
            gemm_mfma<2><<<dim3(8, 16, 1), 256, 0, stream>>>(Ab, Wb, 3072, 0, rb1, nullptr,
                                                             G, nullptr, 1024, 1024);
            gemv_ro2<<<512, 256, 0, stream>>>(G, nullptr, rW2, rb2, ssp, rng, raw_o, dnn_o);
        }

        gampdt4_kernel<<<(NSTEPS * 2048 + 255) / 256, 256, 0, stream>>>(dnn_o, pop, AG4);
        ode_core<<<32, 64, 0, stream>>>(dnn_o, pop, ccn, mort, AG4, DET4, sol_o);
        ode_decay<<<256, 64, 0, stream>>>(dnn_o, ccn, mort, AG4, DET4, sol_o);
    } else {
        gemm_dual<1><<<dim3(4, 16), 256, 0, stream>>>(G, 512, mW2, 512, 512,
                                                      nullptr, 0, nullptr, 0, 0,
                                                      mb2, nullptr, Z + 512, 1024, 512);
        for (int l = 0; l < 5; ++l) {
            const float* A1 = (l == 0) ? x0p : ((l & 1) ? X1 : X0);
            int          K1 = (l == 0) ? 32 : 512;
            const float* W1 = (l == 0) ? Wp0 : (WihR + (size_t)(l - 1) * 1048576);
            gemm_dual<0><<<dim3(16, 16), 256, 0, stream>>>(
                A1, K1, W1, K1, K1,
                h0 + (size_t)l * 1048576, 512, Whh + (size_t)l * 1048576, 512, 512,
                bih + l * 2048, bhh + l * 2048, G, 2048, 2048);
            float* xo  = (l == 4) ? Z : ((l & 1) ? X0 : X1);
            int    xol = (l == 4) ? 1024 : 512;
            lstm_gates<<<4096, 256, 0, stream>>>(G, nullptr, c0 + (size_t)l * 1048576, xo, xol,
                                                 (l == 4) ? ts_o : nullptr);
        }
        gemm_dual<2><<<dim3(8, 16), 256, 0, stream>>>(Z, 1024, rW1, 1024, 1024,
                                                      nullptr, 0, nullptr, 0, 0,
                                                      rb1, nullptr, G, 1024, 1024);
        gemm_dual<0><<<dim3(1, 16), 256, 0, stream>>>(G, 1024, rW2, 1024, 1024,
                                                      nullptr, 0, nullptr, 0, 0,
                                                      rb2, nullptr, raw_o, 23, 23);
        dnn_kernel<<<184, 256, 0, stream>>>(raw_o, ssp, rng, dnn_o);
        ode_kernel<<<32, 64, 0, stream>>>(dnn_o, pop, ccn, mort, sol_o);
    }
    (void)in_sizes; (void)n_in; (void)out_size;
}